// Round 4
// baseline (947.413 us; speedup 1.0000x reference)
//
#include <hip/hip_runtime.h>
#include <cstdio>

#define Nn 50000
#define Ee 800000
#define Ff 512
#define Dd 256
#define Gg 8

typedef short short8 __attribute__((ext_vector_type(8)));
typedef unsigned short ushort8v __attribute__((ext_vector_type(8)));
typedef __bf16 bf16x8 __attribute__((ext_vector_type(8)));
typedef float f32x4 __attribute__((ext_vector_type(4)));

__device__ inline unsigned short f2bf(float f) {
  unsigned u = __float_as_uint(f);
  u += 0x7FFFu + ((u >> 16) & 1u);
  return (unsigned short)(u >> 16);
}
__device__ inline float bf2f(unsigned short h) {
  return __uint_as_float(((unsigned)h) << 16);
}

__device__ inline void gload16(const void* g, void* l) {
  __builtin_amdgcn_global_load_lds((const __attribute__((address_space(1))) void*)g,
                                   (__attribute__((address_space(3))) void*)l, 16, 0, 0);
}

// ---------------- CSR build ----------------

__global__ void hist_kernel(const int* __restrict__ dst, int* __restrict__ deg) {
  int i = blockIdx.x * blockDim.x + threadIdx.x;
  int stride = gridDim.x * blockDim.x;
  for (; i < Ee; i += stride) atomicAdd(&deg[dst[i]], 1);
}

__global__ __launch_bounds__(1024) void scan_kernel(const int* __restrict__ deg, int* __restrict__ off) {
  __shared__ int wsum[16];
  __shared__ int carry;
  int tid = threadIdx.x;
  int lane = tid & 63, w = tid >> 6;
  if (tid == 0) carry = 0;
  __syncthreads();
  for (int start = 0; start < Nn; start += 1024) {
    int i = start + tid;
    int v = (i < Nn) ? deg[i] : 0;
    int x = v;
#pragma unroll
    for (int o = 1; o < 64; o <<= 1) {
      int t = __shfl_up(x, o);
      if (lane >= o) x += t;
    }
    if (lane == 63) wsum[w] = x;
    __syncthreads();
    if (w == 0 && lane < 16) {
      int y = wsum[lane];
#pragma unroll
      for (int o = 1; o < 16; o <<= 1) {
        int t = __shfl_up(y, o);
        if (lane >= o) y += t;
      }
      wsum[lane] = y;
    }
    __syncthreads();
    int cb = carry;
    int incl = x + (w ? wsum[w - 1] : 0);
    if (i < Nn) off[i] = cb + incl - v;
    __syncthreads();
    if (tid == 1023) carry = cb + incl;
    __syncthreads();
  }
  if (tid == 0) off[Nn] = carry;
}

__global__ void scatter_kernel(const int* __restrict__ src, const int* __restrict__ dst,
                               const int* __restrict__ off, int* __restrict__ cur,
                               int* __restrict__ ssrc) {
  int i = blockIdx.x * blockDim.x + threadIdx.x;
  int stride = gridDim.x * blockDim.x;
  for (; i < Ee; i += stride) {
    int d = dst[i];
    int pos = off[d] + atomicAdd(&cur[d], 1);
    ssrc[pos] = src[i];
  }
}

// ---------------- conversions ----------------

// round fp32 [M][K] -> bf16 [M][K]
__global__ void round_kernel(const float* __restrict__ in, unsigned short* __restrict__ out,
                             int M, int K) {
  const int kg4 = K >> 2;
  int i = blockIdx.x * blockDim.x + threadIdx.x;
  const int total = M * kg4;
  const int stride = gridDim.x * blockDim.x;
  for (; i < total; i += stride) {
    const int row = i / kg4, kg = i - row * kg4;
    const float4 v = *(const float4*)(in + (size_t)row * K + kg * 4);
    ushort4 h;
    h.x = f2bf(v.x); h.y = f2bf(v.y); h.z = f2bf(v.z); h.w = f2bf(v.w);
    *(ushort4*)(out + (size_t)row * K + kg * 4) = h;
  }
}

// 4x W [K][256] fp32 -> B2 [1024][2K] bf16 (transposed): cols [0,K)=hi, [K,2K)=lo
__global__ void convw_kernel(const float* __restrict__ W0, const float* __restrict__ W1,
                             const float* __restrict__ W2, const float* __restrict__ W3,
                             unsigned short* __restrict__ B2, int K) {
  int i = blockIdx.x * blockDim.x + threadIdx.x;
  const int total = 1024 * K;
  const int stride = gridDim.x * blockDim.x;
  for (; i < total; i += stride) {
    const int n = i & 1023;
    const int k = i >> 10;
    const int z = n >> 8, c = n & 255;
    const float* W = z == 0 ? W0 : z == 1 ? W1 : z == 2 ? W2 : W3;
    const float v = W[(size_t)k * Dd + c];
    const unsigned short h = f2bf(v);
    const unsigned short l = f2bf(v - bf2f(h));
    unsigned short* row = B2 + (size_t)n * 2 * K;
    row[k] = h; row[K + k] = l;
  }
}

// ---------------- 2-term split-bf16 MFMA GEMM ----------------
// C = A_bf16 @ (B_hi + B_lo) + bias.  A [M][K] bf16, B2 [1024][2K] bf16.
// Tile: 256x128 per block (4 waves, each 128x64), BK=64.
// outputs: z=0 -> q fp32 [M][256]; z=1/2 -> kv bf16 [M][512] interleaved
// (channel c: K at (c>>2)*8+(c&3), V at +4); z=3 -> s fp32 [M][256]

__global__ __launch_bounds__(256)
void gemm_mfma(const unsigned short* __restrict__ A2, int M, int K,
               const unsigned short* __restrict__ B2,
               const float* __restrict__ b0, const float* __restrict__ b1,
               const float* __restrict__ b2, const float* __restrict__ b3,
               float* __restrict__ qout, unsigned short* __restrict__ kvout,
               float* __restrict__ sout) {
  __shared__ __align__(16) unsigned short As[256 * 64];   // 32 KB
  __shared__ __align__(16) unsigned short Bs[128 * 64];   // 16 KB
  const int tid = threadIdx.x;
  const int lane = tid & 63, w = tid >> 6;
  const int wr = w >> 1, wc = w & 1;
  // XCD swizzle: 1568 blocks = 8 xcd * 196; each XCD owns contiguous row range
  const int p = blockIdx.x;
  const int wg = (p & 7) * 196 + (p >> 3);
  const int bm = (wg >> 3) * 256;
  const int bn = (wg & 7) * 128;
  const int lda = K, ldb = 2 * K;
  const int nsA = K >> 6;
  const int nsteps = (2 * K) >> 6;
  const int srow = lane >> 3, sslot = lane & 7;
  const int fr = lane & 15, fq = lane >> 4;

  f32x4 acc[8][4] = {};

  for (int s = 0; s < nsteps; ++s) {
    const int ak = (s < nsA ? s : s - nsA) << 6;
    const int bk = s << 6;
    __syncthreads();
    // stage A 256x64 (32 chunks of 1KB), B 128x64 (16 chunks); row r's 16B slot
    // sslot holds global col-group sslot^(r&7)  (both-sides swizzle, rule 21)
#pragma unroll
    for (int h = 0; h < 8; ++h) {
      const int q = h * 4 + w;
      const int r = q * 8 + srow;
      const int g = sslot ^ (r & 7);
      int ga = bm + r; if (ga > M - 1) ga = M - 1;
      gload16(A2 + (size_t)ga * lda + ak + g * 8, (char*)As + q * 1024);
    }
#pragma unroll
    for (int h = 0; h < 4; ++h) {
      const int q = h * 4 + w;
      const int r = q * 8 + srow;
      const int g = sslot ^ (r & 7);
      gload16(B2 + (size_t)(bn + r) * ldb + bk + g * 8, (char*)Bs + q * 1024);
    }
    __syncthreads();
#pragma unroll
    for (int kh = 0; kh < 2; ++kh) {
      short8 av[8], bv[4];
#pragma unroll
      for (int i = 0; i < 8; ++i) {
        const int ra = wr * 128 + i * 16 + fr;
        av[i] = *(const short8*)((const char*)As + ra * 128 + (((kh * 4 + fq) ^ (ra & 7)) << 4));
      }
#pragma unroll
      for (int j = 0; j < 4; ++j) {
        const int rb = wc * 64 + j * 16 + fr;
        bv[j] = *(const short8*)((const char*)Bs + rb * 128 + (((kh * 4 + fq) ^ (rb & 7)) << 4));
      }
#pragma unroll
      for (int i = 0; i < 8; ++i)
#pragma unroll
        for (int j = 0; j < 4; ++j)
          acc[i][j] = __builtin_amdgcn_mfma_f32_16x16x32_bf16(
              __builtin_bit_cast(bf16x8, av[i]),
              __builtin_bit_cast(bf16x8, bv[j]), acc[i][j], 0, 0, 0);
    }
  }

  // epilogue: C/D layout col=lane&15, row=(lane>>4)*4+jj
#pragma unroll
  for (int i = 0; i < 8; ++i) {
    const int grow0 = bm + wr * 128 + i * 16 + fq * 4;
#pragma unroll
    for (int j = 0; j < 4; ++j) {
      const int nbase = bn + wc * 64 + j * 16;
      const int z = nbase >> 8;
      const int c = (nbase & 255) + fr;
      const float* bp = z == 0 ? b0 : z == 1 ? b1 : z == 2 ? b2 : b3;
      const float bias = bp[c];
#pragma unroll
      for (int jj = 0; jj < 4; ++jj) {
        const int grow = grow0 + jj;
        if (grow < M) {
          const float val = acc[i][j][jj] + bias;
          if (z == 0) {
            qout[(size_t)grow * Dd + c] = val;
          } else if (z == 3) {
            sout[(size_t)grow * Dd + c] = val;
          } else {
            const int idx = ((c >> 2) << 3) + (c & 3) + (z == 2 ? 4 : 0);
            kvout[(size_t)grow * 512 + idx] = f2bf(val);
          }
        }
      }
    }
  }
}

// ---------------- per-node attention (one wave per dst node, online softmax) ----------------
// kv: bf16 [Nn][512], lane's 16B slot = {K[4c..4c+3], V[4c..4c+3]}
// MODE 0: write relu(out) bf16 [Nn][256] (layer-2 A); MODE 1: fp32 [Nn][256]

template <int MODE>
__global__ __launch_bounds__(256)
void attn_kernel(const float* __restrict__ qbuf, const unsigned short* __restrict__ kvbuf,
                 const float* __restrict__ sbuf, const int* __restrict__ off,
                 const int* __restrict__ ssrc, float* __restrict__ hout,
                 unsigned short* __restrict__ hbout) {
  int gw = (int)((blockIdx.x * 256 + threadIdx.x) >> 6);
  if (gw >= Nn) return;
  int lane = threadIdx.x & 63;

  float4 q = *(const float4*)(qbuf + (size_t)gw * Dd + lane * 4);
  int e0 = off[gw], e1 = off[gw + 1];
  const float scale = 0.08838834764831845f;

  float m = -3.4e38f, d = 0.f;
  float ax = 0.f, ay = 0.f, az = 0.f, aw = 0.f;

  int e = e0;
  for (; e + 2 <= e1; e += 2) {
    int s0 = ssrc[e], s1 = ssrc[e + 1];
    ushort8v u0 = *(const ushort8v*)(kvbuf + (size_t)s0 * 512 + lane * 8);
    ushort8v u1 = *(const ushort8v*)(kvbuf + (size_t)s1 * 512 + lane * 8);
    float p0 = q.x * bf2f(u0[0]);  p0 = fmaf(q.y, bf2f(u0[1]), p0);
    p0 = fmaf(q.z, bf2f(u0[2]), p0); p0 = fmaf(q.w, bf2f(u0[3]), p0);
    float p1 = q.x * bf2f(u1[0]);  p1 = fmaf(q.y, bf2f(u1[1]), p1);
    p1 = fmaf(q.z, bf2f(u1[2]), p1); p1 = fmaf(q.w, bf2f(u1[3]), p1);
    p0 += __shfl_xor(p0, 16); p1 += __shfl_xor(p1, 16);
    p0 += __shfl_xor(p0, 8);  p1 += __shfl_xor(p1, 8);
    p0 += __shfl_xor(p0, 4);  p1 += __shfl_xor(p1, 4);
    p0 += __shfl_xor(p0, 2);  p1 += __shfl_xor(p1, 2);
    p0 += __shfl_xor(p0, 1);  p1 += __shfl_xor(p1, 1);
    float sc0 = p0 * scale, sc1 = p1 * scale;
    float nm = fmaxf(m, fmaxf(sc0, sc1));
    float f = __expf(m - nm);
    float w0 = __expf(sc0 - nm), w1 = __expf(sc1 - nm);
    d = d * f + w0 + w1;
    ax = ax * f + w0 * bf2f(u0[4]) + w1 * bf2f(u1[4]);
    ay = ay * f + w0 * bf2f(u0[5]) + w1 * bf2f(u1[5]);
    az = az * f + w0 * bf2f(u0[6]) + w1 * bf2f(u1[6]);
    aw = aw * f + w0 * bf2f(u0[7]) + w1 * bf2f(u1[7]);
    m = nm;
  }
  if (e < e1) {
    int s0 = ssrc[e];
    ushort8v u0 = *(const ushort8v*)(kvbuf + (size_t)s0 * 512 + lane * 8);
    float p0 = q.x * bf2f(u0[0]);  p0 = fmaf(q.y, bf2f(u0[1]), p0);
    p0 = fmaf(q.z, bf2f(u0[2]), p0); p0 = fmaf(q.w, bf2f(u0[3]), p0);
    p0 += __shfl_xor(p0, 16);
    p0 += __shfl_xor(p0, 8);
    p0 += __shfl_xor(p0, 4);
    p0 += __shfl_xor(p0, 2);
    p0 += __shfl_xor(p0, 1);
    float sc0 = p0 * scale;
    float nm = fmaxf(m, sc0);
    float f = __expf(m - nm);
    float w0 = __expf(sc0 - nm);
    d = d * f + w0;
    ax = ax * f + w0 * bf2f(u0[4]);
    ay = ay * f + w0 * bf2f(u0[5]);
    az = az * f + w0 * bf2f(u0[6]);
    aw = aw * f + w0 * bf2f(u0[7]);
    m = nm;
  }

  float inv = 1.f / (d + 1e-16f);
  float4 sk = *(const float4*)(sbuf + (size_t)gw * Dd + lane * 4);
  float4 o;
  o.x = fmaxf(ax * inv + sk.x, 0.f);
  o.y = fmaxf(ay * inv + sk.y, 0.f);
  o.z = fmaxf(az * inv + sk.z, 0.f);
  o.w = fmaxf(aw * inv + sk.w, 0.f);
  if (MODE == 0) {
    ushort4 hh;
    hh.x = f2bf(o.x); hh.y = f2bf(o.y); hh.z = f2bf(o.z); hh.w = f2bf(o.w);
    *(ushort4*)(hbout + (size_t)gw * Dd + lane * 4) = hh;
  } else {
    *(float4*)(hout + (size_t)gw * Dd + lane * 4) = o;
  }
}

// ---------------- pooling + fc ----------------

__global__ __launch_bounds__(256)
void pool_kernel(const float* __restrict__ h, const int* __restrict__ batch,
                 float* __restrict__ pooled) {
  int c = threadIdx.x;
  int n0 = blockIdx.x * 128;
  int n1 = min(n0 + 128, Nn);
  int curg = batch[n0];
  float mx = 0.f;
  for (int n = n0; n < n1; ++n) {
    int g = batch[n];
    if (g != curg) {
      atomicMax((int*)(pooled + curg * Dd + c), __float_as_int(mx));
      mx = 0.f;
      curg = g;
    }
    mx = fmaxf(mx, h[(size_t)n * Dd + c]);
  }
  atomicMax((int*)(pooled + curg * Dd + c), __float_as_int(mx));
}

__global__ __launch_bounds__(512)
void fc_kernel(const float* __restrict__ pooled,
               const float* __restrict__ wf1, const float* __restrict__ bf1,
               const float* __restrict__ wf2, const float* __restrict__ bf2,
               float* __restrict__ outp) {
  __shared__ float t[Gg][64];
  int tid = threadIdx.x;
  int g = tid >> 6, j = tid & 63;
  float acc = bf1[j];
  for (int c = 0; c < Dd; ++c) acc = fmaf(pooled[g * Dd + c], wf1[c * 64 + j], acc);
  t[g][j] = acc;
  __syncthreads();
  if (tid < Gg * 4) {
    int gg = tid >> 2, cc = tid & 3;
    float a2 = bf2[cc];
    for (int j2 = 0; j2 < 64; ++j2) a2 = fmaf(t[gg][j2], wf2[j2 * 4 + cc], a2);
    outp[gg * 4 + cc] = a2;
  }
}

// ---------------- host ----------------

extern "C" void kernel_launch(void* const* d_in, const int* in_sizes, int n_in,
                              void* d_out, int out_size, void* d_ws, size_t ws_size,
                              hipStream_t stream) {
  const float* x   = (const float*)d_in[0];
  const int* ei    = (const int*)d_in[1];
  const int* srcE  = ei;
  const int* dstE  = ei + Ee;
  const int* batch = (const int*)d_in[2];
  const float* wq1 = (const float*)d_in[3];  const float* bq1 = (const float*)d_in[4];
  const float* wk1 = (const float*)d_in[5];  const float* bk1 = (const float*)d_in[6];
  const float* wv1 = (const float*)d_in[7];  const float* bv1 = (const float*)d_in[8];
  const float* ws1 = (const float*)d_in[9];  const float* bs1 = (const float*)d_in[10];
  const float* wq2 = (const float*)d_in[11]; const float* bq2 = (const float*)d_in[12];
  const float* wk2 = (const float*)d_in[13]; const float* bk2 = (const float*)d_in[14];
  const float* wv2 = (const float*)d_in[15]; const float* bv2 = (const float*)d_in[16];
  const float* ws2 = (const float*)d_in[17]; const float* bs2 = (const float*)d_in[18];
  const float* wf1 = (const float*)d_in[19]; const float* bf1 = (const float*)d_in[20];
  const float* wf2 = (const float*)d_in[21]; const float* bf2 = (const float*)d_in[22];
  float* outp = (float*)d_out;
  char* ws = (char*)d_ws;

  auto al256 = [](size_t v) { return (v + 255) & ~(size_t)255; };
  size_t o_deg  = 0;
  size_t o_cur  = o_deg + (size_t)Nn * 4;
  size_t o_pool = o_cur + (size_t)Nn * 4;
  size_t zbytes = o_pool + (size_t)Gg * Dd * 4;
  size_t o_off  = al256(zbytes);
  size_t o_ssrc = al256(o_off + (size_t)(Nn + 1) * 4);
  size_t o_q    = al256(o_ssrc + (size_t)Ee * 4);
  size_t o_kv   = al256(o_q + (size_t)Nn * Dd * 4);
  size_t o_s    = al256(o_kv + (size_t)Nn * 512 * 2);
  size_t o_b21  = al256(o_s + (size_t)Nn * Dd * 4);
  size_t o_b22  = al256(o_b21 + (size_t)1024 * 2 * Ff * 2);
  size_t o_a    = al256(o_b22 + (size_t)1024 * 2 * Dd * 2);   // x bf16 [Nn][512] / h bf16 [Nn][256] overlay
  size_t o_h2   = al256(o_a + (size_t)Nn * Ff * 2);
  size_t total  = o_h2 + (size_t)Nn * Dd * 4;
  if (ws_size < total) {
    fprintf(stderr, "kernel_launch: ws too small: %zu < %zu\n", ws_size, total);
    return;
  }

  int*   deg    = (int*)(ws + o_deg);
  int*   cur    = (int*)(ws + o_cur);
  float* pooled = (float*)(ws + o_pool);
  int*   off    = (int*)(ws + o_off);
  int*   ssrc   = (int*)(ws + o_ssrc);
  float* qb     = (float*)(ws + o_q);
  unsigned short* kvb = (unsigned short*)(ws + o_kv);
  float* sb     = (float*)(ws + o_s);
  unsigned short* b21 = (unsigned short*)(ws + o_b21);
  unsigned short* b22 = (unsigned short*)(ws + o_b22);
  unsigned short* a2  = (unsigned short*)(ws + o_a);    // [Nn][512] bf16
  unsigned short* h2b = (unsigned short*)(ws + o_a);    // [Nn][256] bf16 (overlays a2)
  float* h2     = (float*)(ws + o_h2);                  // [Nn][256] fp32

  hipMemsetAsync(ws, 0, zbytes, stream);
  hist_kernel<<<1024, 256, 0, stream>>>(dstE, deg);
  scan_kernel<<<1, 1024, 0, stream>>>(deg, off);
  scatter_kernel<<<1024, 256, 0, stream>>>(srcE, dstE, off, cur, ssrc);

  convw_kernel<<<1024, 256, 0, stream>>>(wq1, wk1, wv1, ws1, b21, Ff);
  convw_kernel<<<1024, 256, 0, stream>>>(wq2, wk2, wv2, ws2, b22, Dd);
  round_kernel<<<4096, 256, 0, stream>>>(x, a2, Nn, Ff);

  gemm_mfma<<<1568, 256, 0, stream>>>(a2, Nn, Ff, b21, bq1, bk1, bv1, bs1, qb, kvb, sb);
  attn_kernel<0><<<(Nn + 3) / 4, 256, 0, stream>>>(qb, kvb, sb, off, ssrc, nullptr, h2b);
  gemm_mfma<<<1568, 256, 0, stream>>>(h2b, Nn, Dd, b22, bq2, bk2, bv2, bs2, qb, kvb, sb);
  attn_kernel<1><<<(Nn + 3) / 4, 256, 0, stream>>>(qb, kvb, sb, off, ssrc, h2, nullptr);

  pool_kernel<<<(Nn + 127) / 128, 256, 0, stream>>>(h2, batch, pooled);
  fc_kernel<<<1, 512, 0, stream>>>(pooled, wf1, bf1, wf2, bf2, outp);
}

// Round 5
// 740.458 us; speedup vs baseline: 1.2795x; 1.2795x over previous
//
#include <hip/hip_runtime.h>
#include <cstdio>

#define Nn 50000
#define Ee 800000
#define Ff 512
#define Dd 256
#define Gg 8

typedef short short8 __attribute__((ext_vector_type(8)));
typedef unsigned short ushort8v __attribute__((ext_vector_type(8)));
typedef __bf16 bf16x8 __attribute__((ext_vector_type(8)));
typedef float f32x4 __attribute__((ext_vector_type(4)));

__device__ inline unsigned short f2bf(float f) {
  unsigned u = __float_as_uint(f);
  u += 0x7FFFu + ((u >> 16) & 1u);
  return (unsigned short)(u >> 16);
}
__device__ inline float bf2f(unsigned short h) {
  return __uint_as_float(((unsigned)h) << 16);
}

__device__ inline void gload16(const void* g, void* l) {
  __builtin_amdgcn_global_load_lds((const __attribute__((address_space(1))) void*)g,
                                   (__attribute__((address_space(3))) void*)l, 16, 0, 0);
}

// ---------------- CSR build ----------------

__global__ void hist_kernel(const int* __restrict__ dst, int* __restrict__ deg) {
  int i = blockIdx.x * blockDim.x + threadIdx.x;
  int stride = gridDim.x * blockDim.x;
  for (; i < Ee; i += stride) atomicAdd(&deg[dst[i]], 1);
}

__global__ __launch_bounds__(1024) void scan_kernel(const int* __restrict__ deg, int* __restrict__ off) {
  __shared__ int wsum[16];
  __shared__ int carry;
  int tid = threadIdx.x;
  int lane = tid & 63, w = tid >> 6;
  if (tid == 0) carry = 0;
  __syncthreads();
  for (int start = 0; start < Nn; start += 1024) {
    int i = start + tid;
    int v = (i < Nn) ? deg[i] : 0;
    int x = v;
#pragma unroll
    for (int o = 1; o < 64; o <<= 1) {
      int t = __shfl_up(x, o);
      if (lane >= o) x += t;
    }
    if (lane == 63) wsum[w] = x;
    __syncthreads();
    if (w == 0 && lane < 16) {
      int y = wsum[lane];
#pragma unroll
      for (int o = 1; o < 16; o <<= 1) {
        int t = __shfl_up(y, o);
        if (lane >= o) y += t;
      }
      wsum[lane] = y;
    }
    __syncthreads();
    int cb = carry;
    int incl = x + (w ? wsum[w - 1] : 0);
    if (i < Nn) off[i] = cb + incl - v;
    __syncthreads();
    if (tid == 1023) carry = cb + incl;
    __syncthreads();
  }
  if (tid == 0) off[Nn] = carry;
}

__global__ void scatter_kernel(const int* __restrict__ src, const int* __restrict__ dst,
                               const int* __restrict__ off, int* __restrict__ cur,
                               int* __restrict__ ssrc) {
  int i = blockIdx.x * blockDim.x + threadIdx.x;
  int stride = gridDim.x * blockDim.x;
  for (; i < Ee; i += stride) {
    int d = dst[i];
    int pos = off[d] + atomicAdd(&cur[d], 1);
    ssrc[pos] = src[i];
  }
}

// ---------------- conversions ----------------

// round fp32 [M][K] -> bf16 [M][K]
__global__ void round_kernel(const float* __restrict__ in, unsigned short* __restrict__ out,
                             int M, int K) {
  const int kg4 = K >> 2;
  int i = blockIdx.x * blockDim.x + threadIdx.x;
  const int total = M * kg4;
  const int stride = gridDim.x * blockDim.x;
  for (; i < total; i += stride) {
    const int row = i / kg4, kg = i - row * kg4;
    const float4 v = *(const float4*)(in + (size_t)row * K + kg * 4);
    ushort4 h;
    h.x = f2bf(v.x); h.y = f2bf(v.y); h.z = f2bf(v.z); h.w = f2bf(v.w);
    *(ushort4*)(out + (size_t)row * K + kg * 4) = h;
  }
}

// 4x W [K][256] fp32 -> B2 [1024][2K] bf16 (transposed): cols [0,K)=hi, [K,2K)=lo
__global__ void convw_kernel(const float* __restrict__ W0, const float* __restrict__ W1,
                             const float* __restrict__ W2, const float* __restrict__ W3,
                             unsigned short* __restrict__ B2, int K) {
  int i = blockIdx.x * blockDim.x + threadIdx.x;
  const int total = 1024 * K;
  const int stride = gridDim.x * blockDim.x;
  for (; i < total; i += stride) {
    const int n = i & 1023;
    const int k = i >> 10;
    const int z = n >> 8, c = n & 255;
    const float* W = z == 0 ? W0 : z == 1 ? W1 : z == 2 ? W2 : W3;
    const float v = W[(size_t)k * Dd + c];
    const unsigned short h = f2bf(v);
    const unsigned short l = f2bf(v - bf2f(h));
    unsigned short* row = B2 + (size_t)n * 2 * K;
    row[k] = h; row[K + k] = l;
  }
}

// ---------------- 2-term split-bf16 MFMA GEMM (round-3 128x128 structure) ----------------
// C = A_bf16 @ (B_hi + B_lo) + bias.  A [M][K] bf16, B2 [1024][2K] bf16.
// outputs: z=0 -> q fp32 [M][256]; z=1/2 -> kv bf16 [M][512] interleaved
// (channel c: K at (c>>2)*8+(c&3), V at +4); z=3 -> s fp32 [M][256]

__global__ __launch_bounds__(256)
void gemm_mfma(const unsigned short* __restrict__ A2, int M, int K,
               const unsigned short* __restrict__ B2,
               const float* __restrict__ b0, const float* __restrict__ b1,
               const float* __restrict__ b2, const float* __restrict__ b3,
               float* __restrict__ qout, unsigned short* __restrict__ kvout,
               float* __restrict__ sout) {
  __shared__ __align__(16) unsigned short As[128 * 64];
  __shared__ __align__(16) unsigned short Bs[128 * 64];
  const int tid = threadIdx.x;
  const int lane = tid & 63, w = tid >> 6;
  const int wr = w >> 1, wc = w & 1;
  // XCD-aware swizzle: 3136 blocks; xcd p&7 owns 49 contiguous row-tiles,
  // its 8 column-groups of a row-tile adjacent in time -> A panel L2-resident
  const int p = blockIdx.x;
  const int xcd = p & 7;
  const int i2 = p >> 3;
  const int bm = (xcd * 49 + (i2 >> 3)) * 128;
  const int bn = (i2 & 7) * 128;
  const int lda = K, ldb = 2 * K;
  const int nsA = K >> 6;
  const int nsteps = (2 * K) >> 6;
  const int srow = lane >> 3, sslot = lane & 7;
  const int fr = lane & 15, fq = lane >> 4;

  f32x4 acc[4][4] = {};

  for (int s = 0; s < nsteps; ++s) {
    const int ak = (s < nsA ? s : s - nsA) << 6;
    const int bk = s << 6;
    __syncthreads();
#pragma unroll
    for (int h = 0; h < 4; ++h) {
      const int q = h * 4 + w;
      const int r = q * 8 + srow;
      const int g = sslot ^ (r & 7);
      int ga = bm + r; if (ga > M - 1) ga = M - 1;
      gload16(A2 + (size_t)ga * lda + ak + g * 8, (char*)As + q * 1024);
      const int gb = bn + r;
      gload16(B2 + (size_t)gb * ldb + bk + g * 8, (char*)Bs + q * 1024);
    }
    __syncthreads();
    short8 av[2][4], bv[2][4];
#pragma unroll
    for (int kh = 0; kh < 2; ++kh)
#pragma unroll
      for (int i = 0; i < 4; ++i) {
        const int ra = wr * 64 + i * 16 + fr;
        av[kh][i] = *(const short8*)((const char*)As + ra * 128 + (((kh * 4 + fq) ^ (ra & 7)) << 4));
        const int rb = wc * 64 + i * 16 + fr;
        bv[kh][i] = *(const short8*)((const char*)Bs + rb * 128 + (((kh * 4 + fq) ^ (rb & 7)) << 4));
      }
#pragma unroll
    for (int kh = 0; kh < 2; ++kh)
#pragma unroll
      for (int mi = 0; mi < 4; ++mi)
#pragma unroll
        for (int ni = 0; ni < 4; ++ni)
          acc[mi][ni] = __builtin_amdgcn_mfma_f32_16x16x32_bf16(
              __builtin_bit_cast(bf16x8, av[kh][mi]),
              __builtin_bit_cast(bf16x8, bv[kh][ni]), acc[mi][ni], 0, 0, 0);
  }

#pragma unroll
  for (int mi = 0; mi < 4; ++mi) {
    const int grow0 = bm + wr * 64 + mi * 16 + fq * 4;
#pragma unroll
    for (int ni = 0; ni < 4; ++ni) {
      const int nbase = bn + wc * 64 + ni * 16;
      const int z = nbase >> 8;
      const int c = (nbase & 255) + fr;
      const float* bp = z == 0 ? b0 : z == 1 ? b1 : z == 2 ? b2 : b3;
      const float bias = bp[c];
#pragma unroll
      for (int j = 0; j < 4; ++j) {
        const int grow = grow0 + j;
        if (grow < M) {
          const float val = acc[mi][ni][j] + bias;
          if (z == 0) {
            qout[(size_t)grow * Dd + c] = val;
          } else if (z == 3) {
            sout[(size_t)grow * Dd + c] = val;
          } else {
            const int idx = ((c >> 2) << 3) + (c & 3) + (z == 2 ? 4 : 0);
            kvout[(size_t)grow * 512 + idx] = f2bf(val);
          }
        }
      }
    }
  }
}

// ---------------- per-node attention (one wave per dst node, online softmax) ----------------
// kv: bf16 [Nn][512], lane's 16B slot = {K[4c..4c+3], V[4c..4c+3]}
// 4-edge unroll for load MLP. MODE 0: write relu(out) bf16 [Nn][256]; MODE 1: fp32.

template <int MODE>
__global__ __launch_bounds__(256)
void attn_kernel(const float* __restrict__ qbuf, const unsigned short* __restrict__ kvbuf,
                 const float* __restrict__ sbuf, const int* __restrict__ off,
                 const int* __restrict__ ssrc, float* __restrict__ hout,
                 unsigned short* __restrict__ hbout) {
  int gw = (int)((blockIdx.x * 256 + threadIdx.x) >> 6);
  if (gw >= Nn) return;
  int lane = threadIdx.x & 63;

  float4 q = *(const float4*)(qbuf + (size_t)gw * Dd + lane * 4);
  int e0 = off[gw], e1 = off[gw + 1];
  const float scale = 0.08838834764831845f;

  float m = -3.4e38f, d = 0.f;
  float ax = 0.f, ay = 0.f, az = 0.f, aw = 0.f;

  int e = e0;
  for (; e + 4 <= e1; e += 4) {
    int s0 = ssrc[e], s1 = ssrc[e + 1], s2 = ssrc[e + 2], s3 = ssrc[e + 3];
    ushort8v u0 = *(const ushort8v*)(kvbuf + (size_t)s0 * 512 + lane * 8);
    ushort8v u1 = *(const ushort8v*)(kvbuf + (size_t)s1 * 512 + lane * 8);
    ushort8v u2 = *(const ushort8v*)(kvbuf + (size_t)s2 * 512 + lane * 8);
    ushort8v u3 = *(const ushort8v*)(kvbuf + (size_t)s3 * 512 + lane * 8);
    float p0 = q.x * bf2f(u0[0]); p0 = fmaf(q.y, bf2f(u0[1]), p0);
    p0 = fmaf(q.z, bf2f(u0[2]), p0); p0 = fmaf(q.w, bf2f(u0[3]), p0);
    float p1 = q.x * bf2f(u1[0]); p1 = fmaf(q.y, bf2f(u1[1]), p1);
    p1 = fmaf(q.z, bf2f(u1[2]), p1); p1 = fmaf(q.w, bf2f(u1[3]), p1);
    float p2 = q.x * bf2f(u2[0]); p2 = fmaf(q.y, bf2f(u2[1]), p2);
    p2 = fmaf(q.z, bf2f(u2[2]), p2); p2 = fmaf(q.w, bf2f(u2[3]), p2);
    float p3 = q.x * bf2f(u3[0]); p3 = fmaf(q.y, bf2f(u3[1]), p3);
    p3 = fmaf(q.z, bf2f(u3[2]), p3); p3 = fmaf(q.w, bf2f(u3[3]), p3);
#pragma unroll
    for (int o = 16; o >= 1; o >>= 1) {
      p0 += __shfl_xor(p0, o); p1 += __shfl_xor(p1, o);
      p2 += __shfl_xor(p2, o); p3 += __shfl_xor(p3, o);
    }
    float sc0 = p0 * scale, sc1 = p1 * scale, sc2 = p2 * scale, sc3 = p3 * scale;
    float nm = fmaxf(fmaxf(m, fmaxf(sc0, sc1)), fmaxf(sc2, sc3));
    float f = __expf(m - nm);
    float w0 = __expf(sc0 - nm), w1 = __expf(sc1 - nm);
    float w2 = __expf(sc2 - nm), w3 = __expf(sc3 - nm);
    d = d * f + w0 + w1 + w2 + w3;
    ax = ax * f + w0 * bf2f(u0[4]) + w1 * bf2f(u1[4]) + w2 * bf2f(u2[4]) + w3 * bf2f(u3[4]);
    ay = ay * f + w0 * bf2f(u0[5]) + w1 * bf2f(u1[5]) + w2 * bf2f(u2[5]) + w3 * bf2f(u3[5]);
    az = az * f + w0 * bf2f(u0[6]) + w1 * bf2f(u1[6]) + w2 * bf2f(u2[6]) + w3 * bf2f(u3[6]);
    aw = aw * f + w0 * bf2f(u0[7]) + w1 * bf2f(u1[7]) + w2 * bf2f(u2[7]) + w3 * bf2f(u3[7]);
    m = nm;
  }
  for (; e < e1; ++e) {
    int s0 = ssrc[e];
    ushort8v u0 = *(const ushort8v*)(kvbuf + (size_t)s0 * 512 + lane * 8);
    float p0 = q.x * bf2f(u0[0]); p0 = fmaf(q.y, bf2f(u0[1]), p0);
    p0 = fmaf(q.z, bf2f(u0[2]), p0); p0 = fmaf(q.w, bf2f(u0[3]), p0);
#pragma unroll
    for (int o = 16; o >= 1; o >>= 1) p0 += __shfl_xor(p0, o);
    float sc0 = p0 * scale;
    float nm = fmaxf(m, sc0);
    float f = __expf(m - nm);
    float w0 = __expf(sc0 - nm);
    d = d * f + w0;
    ax = ax * f + w0 * bf2f(u0[4]);
    ay = ay * f + w0 * bf2f(u0[5]);
    az = az * f + w0 * bf2f(u0[6]);
    aw = aw * f + w0 * bf2f(u0[7]);
    m = nm;
  }

  float inv = 1.f / (d + 1e-16f);
  float4 sk = *(const float4*)(sbuf + (size_t)gw * Dd + lane * 4);
  float4 o;
  o.x = fmaxf(ax * inv + sk.x, 0.f);
  o.y = fmaxf(ay * inv + sk.y, 0.f);
  o.z = fmaxf(az * inv + sk.z, 0.f);
  o.w = fmaxf(aw * inv + sk.w, 0.f);
  if (MODE == 0) {
    ushort4 hh;
    hh.x = f2bf(o.x); hh.y = f2bf(o.y); hh.z = f2bf(o.z); hh.w = f2bf(o.w);
    *(ushort4*)(hbout + (size_t)gw * Dd + lane * 4) = hh;
  } else {
    *(float4*)(hout + (size_t)gw * Dd + lane * 4) = o;
  }
}

// ---------------- pooling + fc ----------------

__global__ __launch_bounds__(256)
void pool_kernel(const float* __restrict__ h, const int* __restrict__ batch,
                 float* __restrict__ pooled) {
  int c = threadIdx.x;
  int n0 = blockIdx.x * 128;
  int n1 = min(n0 + 128, Nn);
  int curg = batch[n0];
  float mx = 0.f;
  for (int n = n0; n < n1; ++n) {
    int g = batch[n];
    if (g != curg) {
      atomicMax((int*)(pooled + curg * Dd + c), __float_as_int(mx));
      mx = 0.f;
      curg = g;
    }
    mx = fmaxf(mx, h[(size_t)n * Dd + c]);
  }
  atomicMax((int*)(pooled + curg * Dd + c), __float_as_int(mx));
}

__global__ __launch_bounds__(512)
void fc_kernel(const float* __restrict__ pooled,
               const float* __restrict__ wf1, const float* __restrict__ bf1,
               const float* __restrict__ wf2, const float* __restrict__ bf2,
               float* __restrict__ outp) {
  __shared__ float t[Gg][64];
  int tid = threadIdx.x;
  int g = tid >> 6, j = tid & 63;
  float acc = bf1[j];
  for (int c = 0; c < Dd; ++c) acc = fmaf(pooled[g * Dd + c], wf1[c * 64 + j], acc);
  t[g][j] = acc;
  __syncthreads();
  if (tid < Gg * 4) {
    int gg = tid >> 2, cc = tid & 3;
    float a2 = bf2[cc];
    for (int j2 = 0; j2 < 64; ++j2) a2 = fmaf(t[gg][j2], wf2[j2 * 4 + cc], a2);
    outp[gg * 4 + cc] = a2;
  }
}

// ---------------- host ----------------

extern "C" void kernel_launch(void* const* d_in, const int* in_sizes, int n_in,
                              void* d_out, int out_size, void* d_ws, size_t ws_size,
                              hipStream_t stream) {
  const float* x   = (const float*)d_in[0];
  const int* ei    = (const int*)d_in[1];
  const int* srcE  = ei;
  const int* dstE  = ei + Ee;
  const int* batch = (const int*)d_in[2];
  const float* wq1 = (const float*)d_in[3];  const float* bq1 = (const float*)d_in[4];
  const float* wk1 = (const float*)d_in[5];  const float* bk1 = (const float*)d_in[6];
  const float* wv1 = (const float*)d_in[7];  const float* bv1 = (const float*)d_in[8];
  const float* ws1 = (const float*)d_in[9];  const float* bs1 = (const float*)d_in[10];
  const float* wq2 = (const float*)d_in[11]; const float* bq2 = (const float*)d_in[12];
  const float* wk2 = (const float*)d_in[13]; const float* bk2 = (const float*)d_in[14];
  const float* wv2 = (const float*)d_in[15]; const float* bv2 = (const float*)d_in[16];
  const float* ws2 = (const float*)d_in[17]; const float* bs2 = (const float*)d_in[18];
  const float* wf1 = (const float*)d_in[19]; const float* bf1 = (const float*)d_in[20];
  const float* wf2 = (const float*)d_in[21]; const float* bf2 = (const float*)d_in[22];
  float* outp = (float*)d_out;
  char* ws = (char*)d_ws;

  auto al256 = [](size_t v) { return (v + 255) & ~(size_t)255; };
  size_t o_deg  = 0;
  size_t o_cur  = o_deg + (size_t)Nn * 4;
  size_t o_pool = o_cur + (size_t)Nn * 4;
  size_t zbytes = o_pool + (size_t)Gg * Dd * 4;
  size_t o_off  = al256(zbytes);
  size_t o_ssrc = al256(o_off + (size_t)(Nn + 1) * 4);
  size_t o_q    = al256(o_ssrc + (size_t)Ee * 4);
  size_t o_kv   = al256(o_q + (size_t)Nn * Dd * 4);
  size_t o_s    = al256(o_kv + (size_t)Nn * 512 * 2);
  size_t o_b21  = al256(o_s + (size_t)Nn * Dd * 4);
  size_t o_b22  = al256(o_b21 + (size_t)1024 * 2 * Ff * 2);
  size_t o_a    = al256(o_b22 + (size_t)1024 * 2 * Dd * 2);   // x bf16 [Nn][512] / h bf16 [Nn][256] overlay
  size_t o_h2   = al256(o_a + (size_t)Nn * Ff * 2);
  size_t total  = o_h2 + (size_t)Nn * Dd * 4;
  if (ws_size < total) {
    fprintf(stderr, "kernel_launch: ws too small: %zu < %zu\n", ws_size, total);
    return;
  }

  int*   deg    = (int*)(ws + o_deg);
  int*   cur    = (int*)(ws + o_cur);
  float* pooled = (float*)(ws + o_pool);
  int*   off    = (int*)(ws + o_off);
  int*   ssrc   = (int*)(ws + o_ssrc);
  float* qb     = (float*)(ws + o_q);
  unsigned short* kvb = (unsigned short*)(ws + o_kv);
  float* sb     = (float*)(ws + o_s);
  unsigned short* b21 = (unsigned short*)(ws + o_b21);
  unsigned short* b22 = (unsigned short*)(ws + o_b22);
  unsigned short* a2  = (unsigned short*)(ws + o_a);    // [Nn][512] bf16
  unsigned short* h2b = (unsigned short*)(ws + o_a);    // [Nn][256] bf16 (overlays a2)
  float* h2     = (float*)(ws + o_h2);                  // [Nn][256] fp32

  hipMemsetAsync(ws, 0, zbytes, stream);
  hist_kernel<<<1024, 256, 0, stream>>>(dstE, deg);
  scan_kernel<<<1, 1024, 0, stream>>>(deg, off);
  scatter_kernel<<<1024, 256, 0, stream>>>(srcE, dstE, off, cur, ssrc);

  convw_kernel<<<1024, 256, 0, stream>>>(wq1, wk1, wv1, ws1, b21, Ff);
  convw_kernel<<<1024, 256, 0, stream>>>(wq2, wk2, wv2, ws2, b22, Dd);
  round_kernel<<<4096, 256, 0, stream>>>(x, a2, Nn, Ff);

  gemm_mfma<<<3136, 256, 0, stream>>>(a2, Nn, Ff, b21, bq1, bk1, bv1, bs1, qb, kvb, sb);
  attn_kernel<0><<<(Nn + 3) / 4, 256, 0, stream>>>(qb, kvb, sb, off, ssrc, nullptr, h2b);
  gemm_mfma<<<3136, 256, 0, stream>>>(h2b, Nn, Dd, b22, bq2, bk2, bv2, bs2, qb, kvb, sb);
  attn_kernel<1><<<(Nn + 3) / 4, 256, 0, stream>>>(qb, kvb, sb, off, ssrc, h2, nullptr);

  pool_kernel<<<(Nn + 127) / 128, 256, 0, stream>>>(h2, batch, pooled);
  fc_kernel<<<1, 512, 0, stream>>>(pooled, wf1, bf1, wf2, bf2, outp);
}

// Round 6
// 732.838 us; speedup vs baseline: 1.2928x; 1.0104x over previous
//
#include <hip/hip_runtime.h>
#include <cstdio>

#define Nn 50000
#define Ee 800000
#define Ff 512
#define Dd 256
#define Gg 8

typedef short short8 __attribute__((ext_vector_type(8)));
typedef unsigned short ushort8v __attribute__((ext_vector_type(8)));
typedef __bf16 bf16x8 __attribute__((ext_vector_type(8)));
typedef float f32x4 __attribute__((ext_vector_type(4)));

__device__ inline unsigned short f2bf(float f) {
  unsigned u = __float_as_uint(f);
  u += 0x7FFFu + ((u >> 16) & 1u);
  return (unsigned short)(u >> 16);
}
__device__ inline float bf2f(unsigned short h) {
  return __uint_as_float(((unsigned)h) << 16);
}

__device__ inline void gload16(const void* g, void* l) {
  __builtin_amdgcn_global_load_lds((const __attribute__((address_space(1))) void*)g,
                                   (__attribute__((address_space(3))) void*)l, 16, 0, 0);
}

// ---------------- CSR build ----------------

__global__ void hist_kernel(const int* __restrict__ dst, int* __restrict__ deg) {
  int i = blockIdx.x * blockDim.x + threadIdx.x;
  int stride = gridDim.x * blockDim.x;
  for (; i < Ee; i += stride) atomicAdd(&deg[dst[i]], 1);
}

__global__ __launch_bounds__(1024) void scan_kernel(const int* __restrict__ deg, int* __restrict__ off) {
  __shared__ int wsum[16];
  __shared__ int carry;
  int tid = threadIdx.x;
  int lane = tid & 63, w = tid >> 6;
  if (tid == 0) carry = 0;
  __syncthreads();
  for (int start = 0; start < Nn; start += 1024) {
    int i = start + tid;
    int v = (i < Nn) ? deg[i] : 0;
    int x = v;
#pragma unroll
    for (int o = 1; o < 64; o <<= 1) {
      int t = __shfl_up(x, o);
      if (lane >= o) x += t;
    }
    if (lane == 63) wsum[w] = x;
    __syncthreads();
    if (w == 0 && lane < 16) {
      int y = wsum[lane];
#pragma unroll
      for (int o = 1; o < 16; o <<= 1) {
        int t = __shfl_up(y, o);
        if (lane >= o) y += t;
      }
      wsum[lane] = y;
    }
    __syncthreads();
    int cb = carry;
    int incl = x + (w ? wsum[w - 1] : 0);
    if (i < Nn) off[i] = cb + incl - v;
    __syncthreads();
    if (tid == 1023) carry = cb + incl;
    __syncthreads();
  }
  if (tid == 0) off[Nn] = carry;
}

__global__ void scatter_kernel(const int* __restrict__ src, const int* __restrict__ dst,
                               const int* __restrict__ off, int* __restrict__ cur,
                               int* __restrict__ ssrc) {
  int i = blockIdx.x * blockDim.x + threadIdx.x;
  int stride = gridDim.x * blockDim.x;
  for (; i < Ee; i += stride) {
    int d = dst[i];
    int pos = off[d] + atomicAdd(&cur[d], 1);
    ssrc[pos] = src[i];
  }
}

// ---------------- conversions ----------------

// round fp32 [M][K] -> bf16 [M][K]
__global__ void round_kernel(const float* __restrict__ in, unsigned short* __restrict__ out,
                             int M, int K) {
  const int kg4 = K >> 2;
  int i = blockIdx.x * blockDim.x + threadIdx.x;
  const int total = M * kg4;
  const int stride = gridDim.x * blockDim.x;
  for (; i < total; i += stride) {
    const int row = i / kg4, kg = i - row * kg4;
    const float4 v = *(const float4*)(in + (size_t)row * K + kg * 4);
    ushort4 h;
    h.x = f2bf(v.x); h.y = f2bf(v.y); h.z = f2bf(v.z); h.w = f2bf(v.w);
    *(ushort4*)(out + (size_t)row * K + kg * 4) = h;
  }
}

// 4x W [K][256] fp32 -> B2 [1024][2K] bf16 (transposed): cols [0,K)=hi, [K,2K)=lo
__global__ void convw_kernel(const float* __restrict__ W0, const float* __restrict__ W1,
                             const float* __restrict__ W2, const float* __restrict__ W3,
                             unsigned short* __restrict__ B2, int K) {
  int i = blockIdx.x * blockDim.x + threadIdx.x;
  const int total = 1024 * K;
  const int stride = gridDim.x * blockDim.x;
  for (; i < total; i += stride) {
    const int n = i & 1023;
    const int k = i >> 10;
    const int z = n >> 8, c = n & 255;
    const float* W = z == 0 ? W0 : z == 1 ? W1 : z == 2 ? W2 : W3;
    const float v = W[(size_t)k * Dd + c];
    const unsigned short h = f2bf(v);
    const unsigned short l = f2bf(v - bf2f(h));
    unsigned short* row = B2 + (size_t)n * 2 * K;
    row[k] = h; row[K + k] = l;
  }
}

// ---------------- 2-term split-bf16 MFMA GEMM (128x128 tile, 2-barrier loop) ----------------
// C = A_bf16 @ (B_hi + B_lo) + bias.  A [M][K] bf16, B2 [1024][2K] bf16.
// z = col-block/2: q(0)/s(3) use both hi+lo B terms; k(1)/v(2) use hi only
// (their outputs are stored bf16 anyway -> lo term below storage noise).
// outputs: z=0 -> q fp32 [M][256]; z=1/2 -> kv bf16 [M][512] interleaved
// (channel c: K at (c>>2)*8+(c&3), V at +4); z=3 -> s fp32 [M][256]

__global__ __launch_bounds__(256)
void gemm_mfma(const unsigned short* __restrict__ A2, int M, int K,
               const unsigned short* __restrict__ B2,
               const float* __restrict__ b0, const float* __restrict__ b1,
               const float* __restrict__ b2, const float* __restrict__ b3,
               float* __restrict__ qout, unsigned short* __restrict__ kvout,
               float* __restrict__ sout) {
  __shared__ __align__(16) unsigned short As[128 * 64];
  __shared__ __align__(16) unsigned short Bs[128 * 64];
  const int tid = threadIdx.x;
  const int lane = tid & 63, w = tid >> 6;
  const int wr = w >> 1, wc = w & 1;
  // XCD-aware swizzle: 3136 blocks; xcd p&7 owns 49 contiguous row-tiles,
  // its 8 column-groups of a row-tile adjacent in time -> A panel L2-resident
  const int p = blockIdx.x;
  const int xcd = p & 7;
  const int i2 = p >> 3;
  const int bm = (xcd * 49 + (i2 >> 3)) * 128;
  const int bn = (i2 & 7) * 128;
  const int zblk = (i2 & 7) >> 1;            // which output this block computes
  const int lda = K, ldb = 2 * K;
  const int nsA = K >> 6;
  const int nsteps = (zblk == 1 || zblk == 2) ? nsA : (2 * nsA);
  const int srow = lane >> 3, sslot = lane & 7;
  const int fr = lane & 15, fq = lane >> 4;

  f32x4 acc[4][4] = {};

  for (int s = 0; s < nsteps; ++s) {
    const int ak = (s < nsA ? s : s - nsA) << 6;
    const int bk = s << 6;
    __syncthreads();
#pragma unroll
    for (int h = 0; h < 4; ++h) {
      const int q = h * 4 + w;
      const int r = q * 8 + srow;
      const int g = sslot ^ (r & 7);
      int ga = bm + r; if (ga > M - 1) ga = M - 1;
      gload16(A2 + (size_t)ga * lda + ak + g * 8, (char*)As + q * 1024);
      const int gb = bn + r;
      gload16(B2 + (size_t)gb * ldb + bk + g * 8, (char*)Bs + q * 1024);
    }
    __syncthreads();
    short8 av[2][4], bv[2][4];
#pragma unroll
    for (int kh = 0; kh < 2; ++kh)
#pragma unroll
      for (int i = 0; i < 4; ++i) {
        const int ra = wr * 64 + i * 16 + fr;
        av[kh][i] = *(const short8*)((const char*)As + ra * 128 + (((kh * 4 + fq) ^ (ra & 7)) << 4));
        const int rb = wc * 64 + i * 16 + fr;
        bv[kh][i] = *(const short8*)((const char*)Bs + rb * 128 + (((kh * 4 + fq) ^ (rb & 7)) << 4));
      }
#pragma unroll
    for (int kh = 0; kh < 2; ++kh)
#pragma unroll
      for (int mi = 0; mi < 4; ++mi)
#pragma unroll
        for (int ni = 0; ni < 4; ++ni)
          acc[mi][ni] = __builtin_amdgcn_mfma_f32_16x16x32_bf16(
              __builtin_bit_cast(bf16x8, av[kh][mi]),
              __builtin_bit_cast(bf16x8, bv[kh][ni]), acc[mi][ni], 0, 0, 0);
  }

#pragma unroll
  for (int mi = 0; mi < 4; ++mi) {
    const int grow0 = bm + wr * 64 + mi * 16 + fq * 4;
#pragma unroll
    for (int ni = 0; ni < 4; ++ni) {
      const int nbase = bn + wc * 64 + ni * 16;
      const int z = nbase >> 8;
      const int c = (nbase & 255) + fr;
      const float* bp = z == 0 ? b0 : z == 1 ? b1 : z == 2 ? b2 : b3;
      const float bias = bp[c];
#pragma unroll
      for (int j = 0; j < 4; ++j) {
        const int grow = grow0 + j;
        if (grow < M) {
          const float val = acc[mi][ni][j] + bias;
          if (z == 0) {
            qout[(size_t)grow * Dd + c] = val;
          } else if (z == 3) {
            sout[(size_t)grow * Dd + c] = val;
          } else {
            const int idx = ((c >> 2) << 3) + (c & 3) + (z == 2 ? 4 : 0);
            kvout[(size_t)grow * 512 + idx] = f2bf(val);
          }
        }
      }
    }
  }
}

// ---------------- per-node attention (one wave per dst node, online softmax) ----------------
// kv: bf16 [Nn][512], lane's 16B slot = {K[4c..4c+3], V[4c..4c+3]}
// masked 8-edge unroll: 8 gathers in flight, invalid slots -> weight 0.
// MODE 0: write relu(out) bf16 [Nn][256]; MODE 1: fp32.

template <int MODE>
__global__ __launch_bounds__(256)
void attn_kernel(const float* __restrict__ qbuf, const unsigned short* __restrict__ kvbuf,
                 const float* __restrict__ sbuf, const int* __restrict__ off,
                 const int* __restrict__ ssrc, float* __restrict__ hout,
                 unsigned short* __restrict__ hbout) {
  int gw = (int)((blockIdx.x * 256 + threadIdx.x) >> 6);
  if (gw >= Nn) return;
  int lane = threadIdx.x & 63;

  float4 q = *(const float4*)(qbuf + (size_t)gw * Dd + lane * 4);
  int e0 = off[gw], e1 = off[gw + 1];
  const float scale = 0.08838834764831845f;

  float m = -3.4e38f, d = 0.f;
  float ax = 0.f, ay = 0.f, az = 0.f, aw = 0.f;

  for (int e = e0; e < e1; e += 8) {
    int sx[8];
#pragma unroll
    for (int t = 0; t < 8; ++t) {
      const int ee = e + t;
      sx[t] = ssrc[ee < e1 ? ee : e1 - 1];
    }
    ushort8v u[8];
#pragma unroll
    for (int t = 0; t < 8; ++t)
      u[t] = *(const ushort8v*)(kvbuf + (size_t)sx[t] * 512 + lane * 8);
    float p[8];
#pragma unroll
    for (int t = 0; t < 8; ++t) {
      float pp = q.x * bf2f(u[t][0]);
      pp = fmaf(q.y, bf2f(u[t][1]), pp);
      pp = fmaf(q.z, bf2f(u[t][2]), pp);
      pp = fmaf(q.w, bf2f(u[t][3]), pp);
      p[t] = pp;
    }
#pragma unroll
    for (int o = 16; o >= 1; o >>= 1)
#pragma unroll
      for (int t = 0; t < 8; ++t) p[t] += __shfl_xor(p[t], o);
    float sc[8];
#pragma unroll
    for (int t = 0; t < 8; ++t)
      sc[t] = (e + t < e1) ? p[t] * scale : -3.0e38f;
    float mx = m;
#pragma unroll
    for (int t = 0; t < 8; ++t) mx = fmaxf(mx, sc[t]);
    const float f = __expf(m - mx);
    float wsum = 0.f, vx = 0.f, vy = 0.f, vz = 0.f, vw = 0.f;
#pragma unroll
    for (int t = 0; t < 8; ++t) {
      const float wt = __expf(sc[t] - mx);
      wsum += wt;
      vx = fmaf(wt, bf2f(u[t][4]), vx);
      vy = fmaf(wt, bf2f(u[t][5]), vy);
      vz = fmaf(wt, bf2f(u[t][6]), vz);
      vw = fmaf(wt, bf2f(u[t][7]), vw);
    }
    d = d * f + wsum;
    ax = ax * f + vx;
    ay = ay * f + vy;
    az = az * f + vz;
    aw = aw * f + vw;
    m = mx;
  }

  float inv = 1.f / (d + 1e-16f);
  float4 sk = *(const float4*)(sbuf + (size_t)gw * Dd + lane * 4);
  float4 o;
  o.x = fmaxf(ax * inv + sk.x, 0.f);
  o.y = fmaxf(ay * inv + sk.y, 0.f);
  o.z = fmaxf(az * inv + sk.z, 0.f);
  o.w = fmaxf(aw * inv + sk.w, 0.f);
  if (MODE == 0) {
    ushort4 hh;
    hh.x = f2bf(o.x); hh.y = f2bf(o.y); hh.z = f2bf(o.z); hh.w = f2bf(o.w);
    *(ushort4*)(hbout + (size_t)gw * Dd + lane * 4) = hh;
  } else {
    *(float4*)(hout + (size_t)gw * Dd + lane * 4) = o;
  }
}

// ---------------- pooling + fc ----------------

__global__ __launch_bounds__(256)
void pool_kernel(const float* __restrict__ h, const int* __restrict__ batch,
                 float* __restrict__ pooled) {
  int c = threadIdx.x;
  int n0 = blockIdx.x * 128;
  int n1 = min(n0 + 128, Nn);
  int curg = batch[n0];
  float mx = 0.f;
  for (int n = n0; n < n1; ++n) {
    int g = batch[n];
    if (g != curg) {
      atomicMax((int*)(pooled + curg * Dd + c), __float_as_int(mx));
      mx = 0.f;
      curg = g;
    }
    mx = fmaxf(mx, h[(size_t)n * Dd + c]);
  }
  atomicMax((int*)(pooled + curg * Dd + c), __float_as_int(mx));
}

__global__ __launch_bounds__(512)
void fc_kernel(const float* __restrict__ pooled,
               const float* __restrict__ wf1, const float* __restrict__ bf1,
               const float* __restrict__ wf2, const float* __restrict__ bf2,
               float* __restrict__ outp) {
  __shared__ float t[Gg][64];
  int tid = threadIdx.x;
  int g = tid >> 6, j = tid & 63;
  float acc = bf1[j];
  for (int c = 0; c < Dd; ++c) acc = fmaf(pooled[g * Dd + c], wf1[c * 64 + j], acc);
  t[g][j] = acc;
  __syncthreads();
  if (tid < Gg * 4) {
    int gg = tid >> 2, cc = tid & 3;
    float a2 = bf2[cc];
    for (int j2 = 0; j2 < 64; ++j2) a2 = fmaf(t[gg][j2], wf2[j2 * 4 + cc], a2);
    outp[gg * 4 + cc] = a2;
  }
}

// ---------------- host ----------------

extern "C" void kernel_launch(void* const* d_in, const int* in_sizes, int n_in,
                              void* d_out, int out_size, void* d_ws, size_t ws_size,
                              hipStream_t stream) {
  const float* x   = (const float*)d_in[0];
  const int* ei    = (const int*)d_in[1];
  const int* srcE  = ei;
  const int* dstE  = ei + Ee;
  const int* batch = (const int*)d_in[2];
  const float* wq1 = (const float*)d_in[3];  const float* bq1 = (const float*)d_in[4];
  const float* wk1 = (const float*)d_in[5];  const float* bk1 = (const float*)d_in[6];
  const float* wv1 = (const float*)d_in[7];  const float* bv1 = (const float*)d_in[8];
  const float* ws1 = (const float*)d_in[9];  const float* bs1 = (const float*)d_in[10];
  const float* wq2 = (const float*)d_in[11]; const float* bq2 = (const float*)d_in[12];
  const float* wk2 = (const float*)d_in[13]; const float* bk2 = (const float*)d_in[14];
  const float* wv2 = (const float*)d_in[15]; const float* bv2 = (const float*)d_in[16];
  const float* ws2 = (const float*)d_in[17]; const float* bs2 = (const float*)d_in[18];
  const float* wf1 = (const float*)d_in[19]; const float* bf1 = (const float*)d_in[20];
  const float* wf2 = (const float*)d_in[21]; const float* bf2 = (const float*)d_in[22];
  float* outp = (float*)d_out;
  char* ws = (char*)d_ws;

  auto al256 = [](size_t v) { return (v + 255) & ~(size_t)255; };
  size_t o_deg  = 0;
  size_t o_cur  = o_deg + (size_t)Nn * 4;
  size_t o_pool = o_cur + (size_t)Nn * 4;
  size_t zbytes = o_pool + (size_t)Gg * Dd * 4;
  size_t o_off  = al256(zbytes);
  size_t o_ssrc = al256(o_off + (size_t)(Nn + 1) * 4);
  size_t o_q    = al256(o_ssrc + (size_t)Ee * 4);
  size_t o_kv   = al256(o_q + (size_t)Nn * Dd * 4);
  size_t o_s    = al256(o_kv + (size_t)Nn * 512 * 2);
  size_t o_b21  = al256(o_s + (size_t)Nn * Dd * 4);
  size_t o_b22  = al256(o_b21 + (size_t)1024 * 2 * Ff * 2);
  size_t o_a    = al256(o_b22 + (size_t)1024 * 2 * Dd * 2);   // x bf16 [Nn][512] / h bf16 [Nn][256] overlay
  size_t o_h2   = al256(o_a + (size_t)Nn * Ff * 2);
  size_t total  = o_h2 + (size_t)Nn * Dd * 4;
  if (ws_size < total) {
    fprintf(stderr, "kernel_launch: ws too small: %zu < %zu\n", ws_size, total);
    return;
  }

  int*   deg    = (int*)(ws + o_deg);
  int*   cur    = (int*)(ws + o_cur);
  float* pooled = (float*)(ws + o_pool);
  int*   off    = (int*)(ws + o_off);
  int*   ssrc   = (int*)(ws + o_ssrc);
  float* qb     = (float*)(ws + o_q);
  unsigned short* kvb = (unsigned short*)(ws + o_kv);
  float* sb     = (float*)(ws + o_s);
  unsigned short* b21 = (unsigned short*)(ws + o_b21);
  unsigned short* b22 = (unsigned short*)(ws + o_b22);
  unsigned short* a2  = (unsigned short*)(ws + o_a);    // [Nn][512] bf16
  unsigned short* h2b = (unsigned short*)(ws + o_a);    // [Nn][256] bf16 (overlays a2)
  float* h2     = (float*)(ws + o_h2);                  // [Nn][256] fp32

  hipMemsetAsync(ws, 0, zbytes, stream);
  hist_kernel<<<1024, 256, 0, stream>>>(dstE, deg);
  scan_kernel<<<1, 1024, 0, stream>>>(deg, off);
  scatter_kernel<<<1024, 256, 0, stream>>>(srcE, dstE, off, cur, ssrc);

  convw_kernel<<<1024, 256, 0, stream>>>(wq1, wk1, wv1, ws1, b21, Ff);
  convw_kernel<<<1024, 256, 0, stream>>>(wq2, wk2, wv2, ws2, b22, Dd);
  round_kernel<<<4096, 256, 0, stream>>>(x, a2, Nn, Ff);

  gemm_mfma<<<3136, 256, 0, stream>>>(a2, Nn, Ff, b21, bq1, bk1, bv1, bs1, qb, kvb, sb);
  attn_kernel<0><<<(Nn + 3) / 4, 256, 0, stream>>>(qb, kvb, sb, off, ssrc, nullptr, h2b);
  gemm_mfma<<<3136, 256, 0, stream>>>(h2b, Nn, Dd, b22, bq2, bk2, bv2, bs2, qb, kvb, sb);
  attn_kernel<1><<<(Nn + 3) / 4, 256, 0, stream>>>(qb, kvb, sb, off, ssrc, h2, nullptr);

  pool_kernel<<<(Nn + 127) / 128, 256, 0, stream>>>(h2, batch, pooled);
  fc_kernel<<<1, 512, 0, stream>>>(pooled, wf1, bf1, wf2, bf2, outp);
}

// Round 7
// 711.065 us; speedup vs baseline: 1.3324x; 1.0306x over previous
//
#include <hip/hip_runtime.h>
#include <cstdio>

#define Nn 50000
#define Ee 800000
#define Ff 512
#define Dd 256
#define Gg 8

typedef short short8 __attribute__((ext_vector_type(8)));
typedef unsigned short ushort8v __attribute__((ext_vector_type(8)));
typedef __bf16 bf16x8 __attribute__((ext_vector_type(8)));
typedef float f32x4 __attribute__((ext_vector_type(4)));

__device__ inline unsigned short f2bf(float f) {
  unsigned u = __float_as_uint(f);
  u += 0x7FFFu + ((u >> 16) & 1u);
  return (unsigned short)(u >> 16);
}
__device__ inline float bf2f(unsigned short h) {
  return __uint_as_float(((unsigned)h) << 16);
}

__device__ inline void gload16(const void* g, void* l) {
  __builtin_amdgcn_global_load_lds((const __attribute__((address_space(1))) void*)g,
                                   (__attribute__((address_space(3))) void*)l, 16, 0, 0);
}

// ---------------- CSR build ----------------

__global__ void hist_kernel(const int* __restrict__ dst, int* __restrict__ deg) {
  int i = blockIdx.x * blockDim.x + threadIdx.x;
  int stride = gridDim.x * blockDim.x;
  for (; i < Ee; i += stride) atomicAdd(&deg[dst[i]], 1);
}

__global__ __launch_bounds__(1024) void scan_kernel(const int* __restrict__ deg, int* __restrict__ off) {
  __shared__ int wsum[16];
  __shared__ int carry;
  int tid = threadIdx.x;
  int lane = tid & 63, w = tid >> 6;
  if (tid == 0) carry = 0;
  __syncthreads();
  for (int start = 0; start < Nn; start += 1024) {
    int i = start + tid;
    int v = (i < Nn) ? deg[i] : 0;
    int x = v;
#pragma unroll
    for (int o = 1; o < 64; o <<= 1) {
      int t = __shfl_up(x, o);
      if (lane >= o) x += t;
    }
    if (lane == 63) wsum[w] = x;
    __syncthreads();
    if (w == 0 && lane < 16) {
      int y = wsum[lane];
#pragma unroll
      for (int o = 1; o < 16; o <<= 1) {
        int t = __shfl_up(y, o);
        if (lane >= o) y += t;
      }
      wsum[lane] = y;
    }
    __syncthreads();
    int cb = carry;
    int incl = x + (w ? wsum[w - 1] : 0);
    if (i < Nn) off[i] = cb + incl - v;
    __syncthreads();
    if (tid == 1023) carry = cb + incl;
    __syncthreads();
  }
  if (tid == 0) off[Nn] = carry;
}

__global__ void scatter_kernel(const int* __restrict__ src, const int* __restrict__ dst,
                               const int* __restrict__ off, int* __restrict__ cur,
                               int* __restrict__ ssrc) {
  int i = blockIdx.x * blockDim.x + threadIdx.x;
  int stride = gridDim.x * blockDim.x;
  for (; i < Ee; i += stride) {
    int d = dst[i];
    int pos = off[d] + atomicAdd(&cur[d], 1);
    ssrc[pos] = src[i];
  }
}

// ---------------- conversions ----------------

// round fp32 [M][K] -> bf16 [M][K]
__global__ void round_kernel(const float* __restrict__ in, unsigned short* __restrict__ out,
                             int M, int K) {
  const int kg4 = K >> 2;
  int i = blockIdx.x * blockDim.x + threadIdx.x;
  const int total = M * kg4;
  const int stride = gridDim.x * blockDim.x;
  for (; i < total; i += stride) {
    const int row = i / kg4, kg = i - row * kg4;
    const float4 v = *(const float4*)(in + (size_t)row * K + kg * 4);
    ushort4 h;
    h.x = f2bf(v.x); h.y = f2bf(v.y); h.z = f2bf(v.z); h.w = f2bf(v.w);
    *(ushort4*)(out + (size_t)row * K + kg * 4) = h;
  }
}

// W's -> Bqs [512][2K] (q rows 0-255, s rows 256-511; cols hi|lo)
//        Bkv [512][K]  (k rows 0-255, v rows 256-511; hi only)
__global__ void convw_kernel(const float* __restrict__ W0, const float* __restrict__ W1,
                             const float* __restrict__ W2, const float* __restrict__ W3,
                             unsigned short* __restrict__ Bqs, unsigned short* __restrict__ Bkv,
                             int K) {
  int i = blockIdx.x * blockDim.x + threadIdx.x;
  const int total = 1024 * K;
  const int stride = gridDim.x * blockDim.x;
  for (; i < total; i += stride) {
    const int n = i & 1023;
    const int k = i >> 10;
    const int z = n >> 8, c = n & 255;
    const float* W = z == 0 ? W0 : z == 1 ? W1 : z == 2 ? W2 : W3;
    const float v = W[(size_t)k * Dd + c];
    const unsigned short h = f2bf(v);
    if (z == 0 || z == 3) {
      const unsigned short l = f2bf(v - bf2f(h));
      unsigned short* row = Bqs + (size_t)((z == 3 ? 256 : 0) + c) * 2 * K;
      row[k] = h; row[K + k] = l;
    } else {
      Bkv[(size_t)((z == 2 ? 256 : 0) + c) * K + k] = h;
    }
  }
}

// ---------------- MFMA GEMM kernels (128x128 tile, r5 structure) ----------------
// grid 1568 = 8 xcd * 49 row-tiles * 4 col-groups

// q/s: C = A_bf16 @ (B_hi + B_lo) + bias, fp32 out
__global__ __launch_bounds__(256)
void gemm_qs(const unsigned short* __restrict__ A2, int M, int K,
             const unsigned short* __restrict__ Bqs,
             const float* __restrict__ bq, const float* __restrict__ bs,
             float* __restrict__ qout, float* __restrict__ sout) {
  __shared__ __align__(16) unsigned short As[128 * 64];
  __shared__ __align__(16) unsigned short Bs[128 * 64];
  const int tid = threadIdx.x;
  const int lane = tid & 63, w = tid >> 6;
  const int wr = w >> 1, wc = w & 1;
  const int p = blockIdx.x;
  const int xcd = p & 7;
  const int i2 = p >> 3;
  const int bm = (xcd * 49 + (i2 >> 2)) * 128;
  const int bn = (i2 & 3) * 128;
  const int lda = K, ldb = 2 * K;
  const int nsA = K >> 6;
  const int nsteps = 2 * nsA;
  const int srow = lane >> 3, sslot = lane & 7;
  const int fr = lane & 15, fq = lane >> 4;

  f32x4 acc[4][4] = {};

  for (int s = 0; s < nsteps; ++s) {
    const int ak = (s < nsA ? s : s - nsA) << 6;
    const int bk = s << 6;
    __syncthreads();
#pragma unroll
    for (int h = 0; h < 4; ++h) {
      const int q = h * 4 + w;
      const int r = q * 8 + srow;
      const int g = sslot ^ (r & 7);
      int ga = bm + r; if (ga > M - 1) ga = M - 1;
      gload16(A2 + (size_t)ga * lda + ak + g * 8, (char*)As + q * 1024);
      const int gb = bn + r;
      gload16(Bqs + (size_t)gb * ldb + bk + g * 8, (char*)Bs + q * 1024);
    }
    __syncthreads();
    short8 av[2][4], bv[2][4];
#pragma unroll
    for (int kh = 0; kh < 2; ++kh)
#pragma unroll
      for (int i = 0; i < 4; ++i) {
        const int ra = wr * 64 + i * 16 + fr;
        av[kh][i] = *(const short8*)((const char*)As + ra * 128 + (((kh * 4 + fq) ^ (ra & 7)) << 4));
        const int rb = wc * 64 + i * 16 + fr;
        bv[kh][i] = *(const short8*)((const char*)Bs + rb * 128 + (((kh * 4 + fq) ^ (rb & 7)) << 4));
      }
#pragma unroll
    for (int kh = 0; kh < 2; ++kh)
#pragma unroll
      for (int mi = 0; mi < 4; ++mi)
#pragma unroll
        for (int ni = 0; ni < 4; ++ni)
          acc[mi][ni] = __builtin_amdgcn_mfma_f32_16x16x32_bf16(
              __builtin_bit_cast(bf16x8, av[kh][mi]),
              __builtin_bit_cast(bf16x8, bv[kh][ni]), acc[mi][ni], 0, 0, 0);
  }

#pragma unroll
  for (int mi = 0; mi < 4; ++mi) {
    const int grow0 = bm + wr * 64 + mi * 16 + fq * 4;
#pragma unroll
    for (int ni = 0; ni < 4; ++ni) {
      const int nbase = bn + wc * 64 + ni * 16;
      const int isS = nbase >> 8;
      const int c = (nbase & 255) + fr;
      const float bias = (isS ? bs : bq)[c];
      float* out = isS ? sout : qout;
#pragma unroll
      for (int j = 0; j < 4; ++j) {
        const int grow = grow0 + j;
        if (grow < M) out[(size_t)grow * Dd + c] = acc[mi][ni][j] + bias;
      }
    }
  }
}

// k/v: C = A_bf16 @ B_hi + bias, interleaved bf16 out
// (channel c: K at (c>>2)*8+(c&3), V at +4)
__global__ __launch_bounds__(256)
void gemm_kv(const unsigned short* __restrict__ A2, int M, int K,
             const unsigned short* __restrict__ Bkv,
             const float* __restrict__ bk_, const float* __restrict__ bv_,
             unsigned short* __restrict__ kvout) {
  __shared__ __align__(16) unsigned short As[128 * 64];
  __shared__ __align__(16) unsigned short Bs[128 * 64];
  const int tid = threadIdx.x;
  const int lane = tid & 63, w = tid >> 6;
  const int wr = w >> 1, wc = w & 1;
  const int p = blockIdx.x;
  const int xcd = p & 7;
  const int i2 = p >> 3;
  const int bm = (xcd * 49 + (i2 >> 2)) * 128;
  const int bn = (i2 & 3) * 128;
  const int lda = K, ldb = K;
  const int nsteps = K >> 6;
  const int srow = lane >> 3, sslot = lane & 7;
  const int fr = lane & 15, fq = lane >> 4;

  f32x4 acc[4][4] = {};

  for (int s = 0; s < nsteps; ++s) {
    const int kk = s << 6;
    __syncthreads();
#pragma unroll
    for (int h = 0; h < 4; ++h) {
      const int q = h * 4 + w;
      const int r = q * 8 + srow;
      const int g = sslot ^ (r & 7);
      int ga = bm + r; if (ga > M - 1) ga = M - 1;
      gload16(A2 + (size_t)ga * lda + kk + g * 8, (char*)As + q * 1024);
      const int gb = bn + r;
      gload16(Bkv + (size_t)gb * ldb + kk + g * 8, (char*)Bs + q * 1024);
    }
    __syncthreads();
    short8 av[2][4], bv[2][4];
#pragma unroll
    for (int kh = 0; kh < 2; ++kh)
#pragma unroll
      for (int i = 0; i < 4; ++i) {
        const int ra = wr * 64 + i * 16 + fr;
        av[kh][i] = *(const short8*)((const char*)As + ra * 128 + (((kh * 4 + fq) ^ (ra & 7)) << 4));
        const int rb = wc * 64 + i * 16 + fr;
        bv[kh][i] = *(const short8*)((const char*)Bs + rb * 128 + (((kh * 4 + fq) ^ (rb & 7)) << 4));
      }
#pragma unroll
    for (int kh = 0; kh < 2; ++kh)
#pragma unroll
      for (int mi = 0; mi < 4; ++mi)
#pragma unroll
        for (int ni = 0; ni < 4; ++ni)
          acc[mi][ni] = __builtin_amdgcn_mfma_f32_16x16x32_bf16(
              __builtin_bit_cast(bf16x8, av[kh][mi]),
              __builtin_bit_cast(bf16x8, bv[kh][ni]), acc[mi][ni], 0, 0, 0);
  }

#pragma unroll
  for (int mi = 0; mi < 4; ++mi) {
    const int grow0 = bm + wr * 64 + mi * 16 + fq * 4;
#pragma unroll
    for (int ni = 0; ni < 4; ++ni) {
      const int nbase = bn + wc * 64 + ni * 16;
      const int isV = nbase >> 8;
      const int c = (nbase & 255) + fr;
      const float bias = (isV ? bv_ : bk_)[c];
      const int idx = ((c >> 2) << 3) + (c & 3) + (isV ? 4 : 0);
#pragma unroll
      for (int j = 0; j < 4; ++j) {
        const int grow = grow0 + j;
        if (grow < M) kvout[(size_t)grow * 512 + idx] = f2bf(acc[mi][ni][j] + bias);
      }
    }
  }
}

// ---------------- per-node attention (one wave per dst node, online softmax) ----------------
// kv: bf16 [Nn][512], lane's 16B slot = {K[4c..4c+3], V[4c..4c+3]}
// masked 8-edge unroll: 8 gathers in flight, invalid slots -> weight 0.
// MODE 0: write relu(out) bf16 [Nn][256]; MODE 1: fp32.

template <int MODE>
__global__ __launch_bounds__(256)
void attn_kernel(const float* __restrict__ qbuf, const unsigned short* __restrict__ kvbuf,
                 const float* __restrict__ sbuf, const int* __restrict__ off,
                 const int* __restrict__ ssrc, float* __restrict__ hout,
                 unsigned short* __restrict__ hbout) {
  int gw = (int)((blockIdx.x * 256 + threadIdx.x) >> 6);
  if (gw >= Nn) return;
  int lane = threadIdx.x & 63;

  float4 q = *(const float4*)(qbuf + (size_t)gw * Dd + lane * 4);
  int e0 = off[gw], e1 = off[gw + 1];
  const float scale = 0.08838834764831845f;

  float m = -3.4e38f, d = 0.f;
  float ax = 0.f, ay = 0.f, az = 0.f, aw = 0.f;

  for (int e = e0; e < e1; e += 8) {
    int sx[8];
#pragma unroll
    for (int t = 0; t < 8; ++t) {
      const int ee = e + t;
      sx[t] = ssrc[ee < e1 ? ee : e1 - 1];
    }
    ushort8v u[8];
#pragma unroll
    for (int t = 0; t < 8; ++t)
      u[t] = *(const ushort8v*)(kvbuf + (size_t)sx[t] * 512 + lane * 8);
    float p[8];
#pragma unroll
    for (int t = 0; t < 8; ++t) {
      float pp = q.x * bf2f(u[t][0]);
      pp = fmaf(q.y, bf2f(u[t][1]), pp);
      pp = fmaf(q.z, bf2f(u[t][2]), pp);
      pp = fmaf(q.w, bf2f(u[t][3]), pp);
      p[t] = pp;
    }
#pragma unroll
    for (int o = 16; o >= 1; o >>= 1)
#pragma unroll
      for (int t = 0; t < 8; ++t) p[t] += __shfl_xor(p[t], o);
    float sc[8];
#pragma unroll
    for (int t = 0; t < 8; ++t)
      sc[t] = (e + t < e1) ? p[t] * scale : -3.0e38f;
    float mx = m;
#pragma unroll
    for (int t = 0; t < 8; ++t) mx = fmaxf(mx, sc[t]);
    const float f = __expf(m - mx);
    float wsum = 0.f, vx = 0.f, vy = 0.f, vz = 0.f, vw = 0.f;
#pragma unroll
    for (int t = 0; t < 8; ++t) {
      const float wt = __expf(sc[t] - mx);
      wsum += wt;
      vx = fmaf(wt, bf2f(u[t][4]), vx);
      vy = fmaf(wt, bf2f(u[t][5]), vy);
      vz = fmaf(wt, bf2f(u[t][6]), vz);
      vw = fmaf(wt, bf2f(u[t][7]), vw);
    }
    d = d * f + wsum;
    ax = ax * f + vx;
    ay = ay * f + vy;
    az = az * f + vz;
    aw = aw * f + vw;
    m = mx;
  }

  float inv = 1.f / (d + 1e-16f);
  float4 sk = *(const float4*)(sbuf + (size_t)gw * Dd + lane * 4);
  float4 o;
  o.x = fmaxf(ax * inv + sk.x, 0.f);
  o.y = fmaxf(ay * inv + sk.y, 0.f);
  o.z = fmaxf(az * inv + sk.z, 0.f);
  o.w = fmaxf(aw * inv + sk.w, 0.f);
  if (MODE == 0) {
    ushort4 hh;
    hh.x = f2bf(o.x); hh.y = f2bf(o.y); hh.z = f2bf(o.z); hh.w = f2bf(o.w);
    *(ushort4*)(hbout + (size_t)gw * Dd + lane * 4) = hh;
  } else {
    *(float4*)(hout + (size_t)gw * Dd + lane * 4) = o;
  }
}

// ---------------- pooling + fc ----------------

__global__ __launch_bounds__(256)
void pool_kernel(const float* __restrict__ h, const int* __restrict__ batch,
                 float* __restrict__ pooled) {
  int c = threadIdx.x;
  int n0 = blockIdx.x * 128;
  int n1 = min(n0 + 128, Nn);
  int curg = batch[n0];
  float mx = 0.f;
  for (int n = n0; n < n1; ++n) {
    int g = batch[n];
    if (g != curg) {
      atomicMax((int*)(pooled + curg * Dd + c), __float_as_int(mx));
      mx = 0.f;
      curg = g;
    }
    mx = fmaxf(mx, h[(size_t)n * Dd + c]);
  }
  atomicMax((int*)(pooled + curg * Dd + c), __float_as_int(mx));
}

__global__ __launch_bounds__(512)
void fc_kernel(const float* __restrict__ pooled,
               const float* __restrict__ wf1, const float* __restrict__ bf1,
               const float* __restrict__ wf2, const float* __restrict__ bf2,
               float* __restrict__ outp) {
  __shared__ float t[Gg][64];
  int tid = threadIdx.x;
  int g = tid >> 6, j = tid & 63;
  float acc = bf1[j];
  for (int c = 0; c < Dd; ++c) acc = fmaf(pooled[g * Dd + c], wf1[c * 64 + j], acc);
  t[g][j] = acc;
  __syncthreads();
  if (tid < Gg * 4) {
    int gg = tid >> 2, cc = tid & 3;
    float a2 = bf2[cc];
    for (int j2 = 0; j2 < 64; ++j2) a2 = fmaf(t[gg][j2], wf2[j2 * 4 + cc], a2);
    outp[gg * 4 + cc] = a2;
  }
}

// ---------------- host ----------------

extern "C" void kernel_launch(void* const* d_in, const int* in_sizes, int n_in,
                              void* d_out, int out_size, void* d_ws, size_t ws_size,
                              hipStream_t stream) {
  const float* x   = (const float*)d_in[0];
  const int* ei    = (const int*)d_in[1];
  const int* srcE  = ei;
  const int* dstE  = ei + Ee;
  const int* batch = (const int*)d_in[2];
  const float* wq1 = (const float*)d_in[3];  const float* bq1 = (const float*)d_in[4];
  const float* wk1 = (const float*)d_in[5];  const float* bk1 = (const float*)d_in[6];
  const float* wv1 = (const float*)d_in[7];  const float* bv1 = (const float*)d_in[8];
  const float* ws1 = (const float*)d_in[9];  const float* bs1 = (const float*)d_in[10];
  const float* wq2 = (const float*)d_in[11]; const float* bq2 = (const float*)d_in[12];
  const float* wk2 = (const float*)d_in[13]; const float* bk2 = (const float*)d_in[14];
  const float* wv2 = (const float*)d_in[15]; const float* bv2 = (const float*)d_in[16];
  const float* ws2 = (const float*)d_in[17]; const float* bs2 = (const float*)d_in[18];
  const float* wf1 = (const float*)d_in[19]; const float* bf1 = (const float*)d_in[20];
  const float* wf2 = (const float*)d_in[21]; const float* bf2 = (const float*)d_in[22];
  float* outp = (float*)d_out;
  char* ws = (char*)d_ws;

  auto al256 = [](size_t v) { return (v + 255) & ~(size_t)255; };
  size_t o_deg  = 0;
  size_t o_cur  = o_deg + (size_t)Nn * 4;
  size_t o_pool = o_cur + (size_t)Nn * 4;
  size_t zbytes = o_pool + (size_t)Gg * Dd * 4;
  size_t o_off  = al256(zbytes);
  size_t o_ssrc = al256(o_off + (size_t)(Nn + 1) * 4);
  size_t o_q    = al256(o_ssrc + (size_t)Ee * 4);
  size_t o_kv   = al256(o_q + (size_t)Nn * Dd * 4);
  size_t o_s    = al256(o_kv + (size_t)Nn * 512 * 2);
  size_t o_bqs1 = al256(o_s + (size_t)Nn * Dd * 4);
  size_t o_bkv1 = al256(o_bqs1 + (size_t)512 * 2 * Ff * 2);
  size_t o_bqs2 = al256(o_bkv1 + (size_t)512 * Ff * 2);
  size_t o_bkv2 = al256(o_bqs2 + (size_t)512 * 2 * Dd * 2);
  size_t o_a    = al256(o_bkv2 + (size_t)512 * Dd * 2);   // x bf16 [Nn][512] / h bf16 [Nn][256] overlay
  size_t o_h2   = al256(o_a + (size_t)Nn * Ff * 2);
  size_t total  = o_h2 + (size_t)Nn * Dd * 4;
  if (ws_size < total) {
    fprintf(stderr, "kernel_launch: ws too small: %zu < %zu\n", ws_size, total);
    return;
  }

  int*   deg    = (int*)(ws + o_deg);
  int*   cur    = (int*)(ws + o_cur);
  float* pooled = (float*)(ws + o_pool);
  int*   off    = (int*)(ws + o_off);
  int*   ssrc   = (int*)(ws + o_ssrc);
  float* qb     = (float*)(ws + o_q);
  unsigned short* kvb = (unsigned short*)(ws + o_kv);
  float* sb     = (float*)(ws + o_s);
  unsigned short* bqs1 = (unsigned short*)(ws + o_bqs1);
  unsigned short* bkv1 = (unsigned short*)(ws + o_bkv1);
  unsigned short* bqs2 = (unsigned short*)(ws + o_bqs2);
  unsigned short* bkv2 = (unsigned short*)(ws + o_bkv2);
  unsigned short* a2  = (unsigned short*)(ws + o_a);    // [Nn][512] bf16
  unsigned short* h2b = (unsigned short*)(ws + o_a);    // [Nn][256] bf16 (overlays a2)
  float* h2     = (float*)(ws + o_h2);                  // [Nn][256] fp32

  hipMemsetAsync(ws, 0, zbytes, stream);
  hist_kernel<<<1024, 256, 0, stream>>>(dstE, deg);
  scan_kernel<<<1, 1024, 0, stream>>>(deg, off);
  scatter_kernel<<<1024, 256, 0, stream>>>(srcE, dstE, off, cur, ssrc);

  convw_kernel<<<1024, 256, 0, stream>>>(wq1, wk1, wv1, ws1, bqs1, bkv1, Ff);
  convw_kernel<<<1024, 256, 0, stream>>>(wq2, wk2, wv2, ws2, bqs2, bkv2, Dd);
  round_kernel<<<4096, 256, 0, stream>>>(x, a2, Nn, Ff);

  gemm_qs<<<1568, 256, 0, stream>>>(a2, Nn, Ff, bqs1, bq1, bs1, qb, sb);
  gemm_kv<<<1568, 256, 0, stream>>>(a2, Nn, Ff, bkv1, bk1, bv1, kvb);
  attn_kernel<0><<<(Nn + 3) / 4, 256, 0, stream>>>(qb, kvb, sb, off, ssrc, nullptr, h2b);
  gemm_qs<<<1568, 256, 0, stream>>>(h2b, Nn, Dd, bqs2, bq2, bs2, qb, sb);
  gemm_kv<<<1568, 256, 0, stream>>>(h2b, Nn, Dd, bkv2, bk2, bv2, kvb);
  attn_kernel<1><<<(Nn + 3) / 4, 256, 0, stream>>>(qb, kvb, sb, off, ssrc, h2, nullptr);

  pool_kernel<<<(Nn + 127) / 128, 256, 0, stream>>>(h2, batch, pooled);
  fc_kernel<<<1, 512, 0, stream>>>(pooled, wf1, bf1, wf2, bf2, outp);
}

// Round 8
// 642.130 us; speedup vs baseline: 1.4754x; 1.1074x over previous
//
#include <hip/hip_runtime.h>
#include <cstdio>

#define Nn 50000
#define Ee 800000
#define Ff 512
#define Dd 256
#define Gg 8

typedef short short8 __attribute__((ext_vector_type(8)));
typedef __bf16 bf16x8 __attribute__((ext_vector_type(8)));
typedef float f32x4 __attribute__((ext_vector_type(4)));
typedef _Float16 half2v __attribute__((ext_vector_type(2)));

#if defined(__has_builtin)
#if __has_builtin(__builtin_amdgcn_fdot2)
#define HAS_FDOT2 1
#endif
#endif

__device__ inline unsigned short f2bf(float f) {
  unsigned u = __float_as_uint(f);
  u += 0x7FFFu + ((u >> 16) & 1u);
  return (unsigned short)(u >> 16);
}
__device__ inline float bf2f(unsigned short h) {
  return __uint_as_float(((unsigned)h) << 16);
}

__device__ inline void gload16(const void* g, void* l) {
  __builtin_amdgcn_global_load_lds((const __attribute__((address_space(1))) void*)g,
                                   (__attribute__((address_space(3))) void*)l, 16, 0, 0);
}

// ---------------- CSR build ----------------

__global__ void hist_kernel(const int* __restrict__ dst, int* __restrict__ deg) {
  int i = blockIdx.x * blockDim.x + threadIdx.x;
  int stride = gridDim.x * blockDim.x;
  for (; i < Ee; i += stride) atomicAdd(&deg[dst[i]], 1);
}

__global__ __launch_bounds__(1024) void scan_kernel(const int* __restrict__ deg, int* __restrict__ off) {
  __shared__ int wsum[16];
  __shared__ int carry;
  int tid = threadIdx.x;
  int lane = tid & 63, w = tid >> 6;
  if (tid == 0) carry = 0;
  __syncthreads();
  for (int start = 0; start < Nn; start += 1024) {
    int i = start + tid;
    int v = (i < Nn) ? deg[i] : 0;
    int x = v;
#pragma unroll
    for (int o = 1; o < 64; o <<= 1) {
      int t = __shfl_up(x, o);
      if (lane >= o) x += t;
    }
    if (lane == 63) wsum[w] = x;
    __syncthreads();
    if (w == 0 && lane < 16) {
      int y = wsum[lane];
#pragma unroll
      for (int o = 1; o < 16; o <<= 1) {
        int t = __shfl_up(y, o);
        if (lane >= o) y += t;
      }
      wsum[lane] = y;
    }
    __syncthreads();
    int cb = carry;
    int incl = x + (w ? wsum[w - 1] : 0);
    if (i < Nn) off[i] = cb + incl - v;
    __syncthreads();
    if (tid == 1023) carry = cb + incl;
    __syncthreads();
  }
  if (tid == 0) off[Nn] = carry;
}

__global__ void scatter_kernel(const int* __restrict__ src, const int* __restrict__ dst,
                               const int* __restrict__ off, int* __restrict__ cur,
                               int* __restrict__ ssrc) {
  int i = blockIdx.x * blockDim.x + threadIdx.x;
  int stride = gridDim.x * blockDim.x;
  for (; i < Ee; i += stride) {
    int d = dst[i];
    int pos = off[d] + atomicAdd(&cur[d], 1);
    ssrc[pos] = src[i];
  }
}

// ---------------- conversions ----------------

// round fp32 [M][K] -> bf16 [M][K]
__global__ void round_kernel(const float* __restrict__ in, unsigned short* __restrict__ out,
                             int M, int K) {
  const int kg4 = K >> 2;
  int i = blockIdx.x * blockDim.x + threadIdx.x;
  const int total = M * kg4;
  const int stride = gridDim.x * blockDim.x;
  for (; i < total; i += stride) {
    const int row = i / kg4, kg = i - row * kg4;
    const float4 v = *(const float4*)(in + (size_t)row * K + kg * 4);
    ushort4 h;
    h.x = f2bf(v.x); h.y = f2bf(v.y); h.z = f2bf(v.z); h.w = f2bf(v.w);
    *(ushort4*)(out + (size_t)row * K + kg * 4) = h;
  }
}

// 4x W [K][256] fp32 -> B [1024][K] bf16 hi-only, transposed; row n = z*256+c
__global__ void convw_kernel(const float* __restrict__ W0, const float* __restrict__ W1,
                             const float* __restrict__ W2, const float* __restrict__ W3,
                             unsigned short* __restrict__ B, int K) {
  int i = blockIdx.x * blockDim.x + threadIdx.x;
  const int total = 1024 * K;
  const int stride = gridDim.x * blockDim.x;
  for (; i < total; i += stride) {
    const int n = i & 1023;
    const int k = i >> 10;
    const int z = n >> 8, c = n & 255;
    const float* W = z == 0 ? W0 : z == 1 ? W1 : z == 2 ? W2 : W3;
    B[(size_t)n * K + k] = f2bf(W[(size_t)k * Dd + c]);
  }
}

// ---------------- 1-term bf16 MFMA GEMM (128x128 tile, 2-barrier loop) ----------------
// C = A_bf16 @ B_hi + bias.  A [M][K] bf16, B [1024][K] bf16.
// outputs: z=0 -> q fp16 [M][256]; z=1/2 -> kv fp16 [M][512] interleaved
// (channel c: K at (c>>2)*8+(c&3), V at +4); z=3 -> s fp32 [M][256]

__global__ __launch_bounds__(256)
void gemm_mfma(const unsigned short* __restrict__ A2, int M, int K,
               const unsigned short* __restrict__ B,
               const float* __restrict__ b0, const float* __restrict__ b1,
               const float* __restrict__ b2, const float* __restrict__ b3,
               _Float16* __restrict__ qout, _Float16* __restrict__ kvout,
               float* __restrict__ sout) {
  __shared__ __align__(16) unsigned short As[128 * 64];
  __shared__ __align__(16) unsigned short Bs[128 * 64];
  const int tid = threadIdx.x;
  const int lane = tid & 63, w = tid >> 6;
  const int wr = w >> 1, wc = w & 1;
  // XCD-aware swizzle: 3136 blocks; xcd p&7 owns 49 contiguous row-tiles,
  // its 8 column-groups of a row-tile adjacent in time -> A panel L2-resident
  const int p = blockIdx.x;
  const int xcd = p & 7;
  const int i2 = p >> 3;
  const int bm = (xcd * 49 + (i2 >> 3)) * 128;
  const int bn = (i2 & 7) * 128;
  const int lda = K, ldb = K;
  const int nsteps = K >> 6;
  const int srow = lane >> 3, sslot = lane & 7;
  const int fr = lane & 15, fq = lane >> 4;

  f32x4 acc[4][4] = {};

  for (int s = 0; s < nsteps; ++s) {
    const int kk = s << 6;
    __syncthreads();
#pragma unroll
    for (int h = 0; h < 4; ++h) {
      const int q = h * 4 + w;
      const int r = q * 8 + srow;
      const int g = sslot ^ (r & 7);
      int ga = bm + r; if (ga > M - 1) ga = M - 1;
      gload16(A2 + (size_t)ga * lda + kk + g * 8, (char*)As + q * 1024);
      const int gb = bn + r;
      gload16(B + (size_t)gb * ldb + kk + g * 8, (char*)Bs + q * 1024);
    }
    __syncthreads();
    short8 av[2][4], bv[2][4];
#pragma unroll
    for (int kh = 0; kh < 2; ++kh)
#pragma unroll
      for (int i = 0; i < 4; ++i) {
        const int ra = wr * 64 + i * 16 + fr;
        av[kh][i] = *(const short8*)((const char*)As + ra * 128 + (((kh * 4 + fq) ^ (ra & 7)) << 4));
        const int rb = wc * 64 + i * 16 + fr;
        bv[kh][i] = *(const short8*)((const char*)Bs + rb * 128 + (((kh * 4 + fq) ^ (rb & 7)) << 4));
      }
#pragma unroll
    for (int kh = 0; kh < 2; ++kh)
#pragma unroll
      for (int mi = 0; mi < 4; ++mi)
#pragma unroll
        for (int ni = 0; ni < 4; ++ni)
          acc[mi][ni] = __builtin_amdgcn_mfma_f32_16x16x32_bf16(
              __builtin_bit_cast(bf16x8, av[kh][mi]),
              __builtin_bit_cast(bf16x8, bv[kh][ni]), acc[mi][ni], 0, 0, 0);
  }

#pragma unroll
  for (int mi = 0; mi < 4; ++mi) {
    const int grow0 = bm + wr * 64 + mi * 16 + fq * 4;
#pragma unroll
    for (int ni = 0; ni < 4; ++ni) {
      const int nbase = bn + wc * 64 + ni * 16;
      const int z = nbase >> 8;
      const int c = (nbase & 255) + fr;
      const float* bp = z == 0 ? b0 : z == 1 ? b1 : z == 2 ? b2 : b3;
      const float bias = bp[c];
#pragma unroll
      for (int j = 0; j < 4; ++j) {
        const int grow = grow0 + j;
        if (grow < M) {
          const float val = acc[mi][ni][j] + bias;
          if (z == 0) {
            qout[(size_t)grow * Dd + c] = (_Float16)val;
          } else if (z == 3) {
            sout[(size_t)grow * Dd + c] = val;
          } else {
            const int idx = ((c >> 2) << 3) + (c & 3) + (z == 2 ? 4 : 0);
            kvout[(size_t)grow * 512 + idx] = (_Float16)val;
          }
        }
      }
    }
  }
}

// ---------------- per-node attention (one wave per dst node, online softmax) ----------------
// q: fp16 [Nn][256]; kv: fp16 [Nn][512], lane's 16B slot = {K[4c..4c+3], V[4c..4c+3]}
// masked 8-edge unroll; dot via v_dot2_f32_f16.
// MODE 0: write relu(out) bf16 [Nn][256]; MODE 1: fp32.

__device__ inline float hdot4(half2v a01, half2v a23, half2v b01, half2v b23) {
#ifdef HAS_FDOT2
  return __builtin_amdgcn_fdot2(a01, b01, __builtin_amdgcn_fdot2(a23, b23, 0.f, false), false);
#else
  float r = (float)a01[0] * (float)b01[0];
  r = fmaf((float)a01[1], (float)b01[1], r);
  r = fmaf((float)a23[0], (float)b23[0], r);
  r = fmaf((float)a23[1], (float)b23[1], r);
  return r;
#endif
}

template <int MODE>
__global__ __launch_bounds__(256)
void attn_kernel(const _Float16* __restrict__ qbuf, const _Float16* __restrict__ kvbuf,
                 const float* __restrict__ sbuf, const int* __restrict__ off,
                 const int* __restrict__ ssrc, float* __restrict__ hout,
                 unsigned short* __restrict__ hbout) {
  int gw = (int)((blockIdx.x * 256 + threadIdx.x) >> 6);
  if (gw >= Nn) return;
  int lane = threadIdx.x & 63;

  const uint2 qv = *(const uint2*)(qbuf + (size_t)gw * Dd + lane * 4);
  const half2v q01 = __builtin_bit_cast(half2v, qv.x);
  const half2v q23 = __builtin_bit_cast(half2v, qv.y);
  int e0 = off[gw], e1 = off[gw + 1];
  const float scale = 0.08838834764831845f;

  float m = -3.4e38f, d = 0.f;
  float ax = 0.f, ay = 0.f, az = 0.f, aw = 0.f;

  for (int e = e0; e < e1; e += 8) {
    int sx[8];
#pragma unroll
    for (int t = 0; t < 8; ++t) {
      const int ee = e + t;
      sx[t] = ssrc[ee < e1 ? ee : e1 - 1];
    }
    uint4 u[8];
#pragma unroll
    for (int t = 0; t < 8; ++t)
      u[t] = *(const uint4*)(kvbuf + (size_t)sx[t] * 512 + lane * 8);
    float p[8];
#pragma unroll
    for (int t = 0; t < 8; ++t)
      p[t] = hdot4(q01, q23, __builtin_bit_cast(half2v, u[t].x),
                   __builtin_bit_cast(half2v, u[t].y));
#pragma unroll
    for (int o = 16; o >= 1; o >>= 1)
#pragma unroll
      for (int t = 0; t < 8; ++t) p[t] += __shfl_xor(p[t], o);
    float sc[8];
#pragma unroll
    for (int t = 0; t < 8; ++t)
      sc[t] = (e + t < e1) ? p[t] * scale : -3.0e38f;
    float mx = m;
#pragma unroll
    for (int t = 0; t < 8; ++t) mx = fmaxf(mx, sc[t]);
    const float f = __expf(m - mx);
    float wsum = 0.f, vx = 0.f, vy = 0.f, vz = 0.f, vw = 0.f;
#pragma unroll
    for (int t = 0; t < 8; ++t) {
      const float wt = __expf(sc[t] - mx);
      const half2v v01 = __builtin_bit_cast(half2v, u[t].z);
      const half2v v23 = __builtin_bit_cast(half2v, u[t].w);
      wsum += wt;
      vx = fmaf(wt, (float)v01[0], vx);
      vy = fmaf(wt, (float)v01[1], vy);
      vz = fmaf(wt, (float)v23[0], vz);
      vw = fmaf(wt, (float)v23[1], vw);
    }
    d = d * f + wsum;
    ax = ax * f + vx;
    ay = ay * f + vy;
    az = az * f + vz;
    aw = aw * f + vw;
    m = mx;
  }

  float inv = 1.f / (d + 1e-16f);
  float4 sk = *(const float4*)(sbuf + (size_t)gw * Dd + lane * 4);
  float4 o;
  o.x = fmaxf(ax * inv + sk.x, 0.f);
  o.y = fmaxf(ay * inv + sk.y, 0.f);
  o.z = fmaxf(az * inv + sk.z, 0.f);
  o.w = fmaxf(aw * inv + sk.w, 0.f);
  if (MODE == 0) {
    ushort4 hh;
    hh.x = f2bf(o.x); hh.y = f2bf(o.y); hh.z = f2bf(o.z); hh.w = f2bf(o.w);
    *(ushort4*)(hbout + (size_t)gw * Dd + lane * 4) = hh;
  } else {
    *(float4*)(hout + (size_t)gw * Dd + lane * 4) = o;
  }
}

// ---------------- pooling + fc ----------------

__global__ __launch_bounds__(256)
void pool_kernel(const float* __restrict__ h, const int* __restrict__ batch,
                 float* __restrict__ pooled) {
  int c = threadIdx.x;
  int n0 = blockIdx.x * 128;
  int n1 = min(n0 + 128, Nn);
  int curg = batch[n0];
  float mx = 0.f;
  for (int n = n0; n < n1; ++n) {
    int g = batch[n];
    if (g != curg) {
      atomicMax((int*)(pooled + curg * Dd + c), __float_as_int(mx));
      mx = 0.f;
      curg = g;
    }
    mx = fmaxf(mx, h[(size_t)n * Dd + c]);
  }
  atomicMax((int*)(pooled + curg * Dd + c), __float_as_int(mx));
}

__global__ __launch_bounds__(512)
void fc_kernel(const float* __restrict__ pooled,
               const float* __restrict__ wf1, const float* __restrict__ bf1,
               const float* __restrict__ wf2, const float* __restrict__ bf2,
               float* __restrict__ outp) {
  __shared__ float t[Gg][64];
  int tid = threadIdx.x;
  int g = tid >> 6, j = tid & 63;
  float acc = bf1[j];
  for (int c = 0; c < Dd; ++c) acc = fmaf(pooled[g * Dd + c], wf1[c * 64 + j], acc);
  t[g][j] = acc;
  __syncthreads();
  if (tid < Gg * 4) {
    int gg = tid >> 2, cc = tid & 3;
    float a2 = bf2[cc];
    for (int j2 = 0; j2 < 64; ++j2) a2 = fmaf(t[gg][j2], wf2[j2 * 4 + cc], a2);
    outp[gg * 4 + cc] = a2;
  }
}

// ---------------- host ----------------

extern "C" void kernel_launch(void* const* d_in, const int* in_sizes, int n_in,
                              void* d_out, int out_size, void* d_ws, size_t ws_size,
                              hipStream_t stream) {
  const float* x   = (const float*)d_in[0];
  const int* ei    = (const int*)d_in[1];
  const int* srcE  = ei;
  const int* dstE  = ei + Ee;
  const int* batch = (const int*)d_in[2];
  const float* wq1 = (const float*)d_in[3];  const float* bq1 = (const float*)d_in[4];
  const float* wk1 = (const float*)d_in[5];  const float* bk1 = (const float*)d_in[6];
  const float* wv1 = (const float*)d_in[7];  const float* bv1 = (const float*)d_in[8];
  const float* ws1 = (const float*)d_in[9];  const float* bs1 = (const float*)d_in[10];
  const float* wq2 = (const float*)d_in[11]; const float* bq2 = (const float*)d_in[12];
  const float* wk2 = (const float*)d_in[13]; const float* bk2 = (const float*)d_in[14];
  const float* wv2 = (const float*)d_in[15]; const float* bv2 = (const float*)d_in[16];
  const float* ws2 = (const float*)d_in[17]; const float* bs2 = (const float*)d_in[18];
  const float* wf1 = (const float*)d_in[19]; const float* bf1 = (const float*)d_in[20];
  const float* wf2 = (const float*)d_in[21]; const float* bf2 = (const float*)d_in[22];
  float* outp = (float*)d_out;
  char* ws = (char*)d_ws;

  auto al256 = [](size_t v) { return (v + 255) & ~(size_t)255; };
  size_t o_deg  = 0;
  size_t o_cur  = o_deg + (size_t)Nn * 4;
  size_t o_pool = o_cur + (size_t)Nn * 4;
  size_t zbytes = o_pool + (size_t)Gg * Dd * 4;
  size_t o_off  = al256(zbytes);
  size_t o_ssrc = al256(o_off + (size_t)(Nn + 1) * 4);
  size_t o_q    = al256(o_ssrc + (size_t)Ee * 4);                 // fp16 [Nn][256]
  size_t o_kv   = al256(o_q + (size_t)Nn * Dd * 2);               // fp16 [Nn][512]
  size_t o_s    = al256(o_kv + (size_t)Nn * 512 * 2);             // fp32 [Nn][256]
  size_t o_b1   = al256(o_s + (size_t)Nn * Dd * 4);               // bf16 [1024][512]
  size_t o_b2   = al256(o_b1 + (size_t)1024 * Ff * 2);            // bf16 [1024][256]
  size_t o_a    = al256(o_b2 + (size_t)1024 * Dd * 2);            // bf16 [Nn][512] / h bf16 [Nn][256] overlay
  size_t o_h2   = al256(o_a + (size_t)Nn * Ff * 2);
  size_t total  = o_h2 + (size_t)Nn * Dd * 4;
  if (ws_size < total) {
    fprintf(stderr, "kernel_launch: ws too small: %zu < %zu\n", ws_size, total);
    return;
  }

  int*   deg    = (int*)(ws + o_deg);
  int*   cur    = (int*)(ws + o_cur);
  float* pooled = (float*)(ws + o_pool);
  int*   off    = (int*)(ws + o_off);
  int*   ssrc   = (int*)(ws + o_ssrc);
  _Float16* qb  = (_Float16*)(ws + o_q);
  _Float16* kvb = (_Float16*)(ws + o_kv);
  float* sb     = (float*)(ws + o_s);
  unsigned short* b1 = (unsigned short*)(ws + o_b1);
  unsigned short* b2 = (unsigned short*)(ws + o_b2);
  unsigned short* a2  = (unsigned short*)(ws + o_a);    // [Nn][512] bf16
  unsigned short* h2b = (unsigned short*)(ws + o_a);    // [Nn][256] bf16 (overlays a2)
  float* h2     = (float*)(ws + o_h2);                  // [Nn][256] fp32

  hipMemsetAsync(ws, 0, zbytes, stream);
  hist_kernel<<<1024, 256, 0, stream>>>(dstE, deg);
  scan_kernel<<<1, 1024, 0, stream>>>(deg, off);
  scatter_kernel<<<1024, 256, 0, stream>>>(srcE, dstE, off, cur, ssrc);

  convw_kernel<<<1024, 256, 0, stream>>>(wq1, wk1, wv1, ws1, b1, Ff);
  convw_kernel<<<1024, 256, 0, stream>>>(wq2, wk2, wv2, ws2, b2, Dd);
  round_kernel<<<4096, 256, 0, stream>>>(x, a2, Nn, Ff);

  gemm_mfma<<<3136, 256, 0, stream>>>(a2, Nn, Ff, b1, bq1, bk1, bv1, bs1, qb, kvb, sb);
  attn_kernel<0><<<(Nn + 3) / 4, 256, 0, stream>>>(qb, kvb, sb, off, ssrc, nullptr, h2b);
  gemm_mfma<<<3136, 256, 0, stream>>>(h2b, Nn, Dd, b2, bq2, bk2, bv2, bs2, qb, kvb, sb);
  attn_kernel<1><<<(Nn + 3) / 4, 256, 0, stream>>>(qb, kvb, sb, off, ssrc, h2, nullptr);

  pool_kernel<<<(Nn + 127) / 128, 256, 0, stream>>>(h2, batch, pooled);
  fc_kernel<<<1, 512, 0, stream>>>(pooled, wf1, bf1, wf2, bf2, outp);
}

// Round 9
// 607.438 us; speedup vs baseline: 1.5597x; 1.0571x over previous
//
#include <hip/hip_runtime.h>
#include <cstdio>

#define Nn 50000
#define Ee 800000
#define Ff 512
#define Dd 256
#define Gg 8
#define SCANB 49   // ceil(Nn/1024)

typedef short short8 __attribute__((ext_vector_type(8)));
typedef __bf16 bf16x8 __attribute__((ext_vector_type(8)));
typedef float f32x4 __attribute__((ext_vector_type(4)));
typedef _Float16 half2v __attribute__((ext_vector_type(2)));

#if defined(__has_builtin)
#if __has_builtin(__builtin_amdgcn_fdot2)
#define HAS_FDOT2 1
#endif
#endif

__device__ inline unsigned short f2bf(float f) {
  unsigned u = __float_as_uint(f);
  u += 0x7FFFu + ((u >> 16) & 1u);
  return (unsigned short)(u >> 16);
}
__device__ inline float bf2f(unsigned short h) {
  return __uint_as_float(((unsigned)h) << 16);
}

__device__ inline void gload16(const void* g, void* l) {
  __builtin_amdgcn_global_load_lds((const __attribute__((address_space(1))) void*)g,
                                   (__attribute__((address_space(3))) void*)l, 16, 0, 0);
}

// ---------------- CSR build ----------------

__global__ void hist_kernel(const int* __restrict__ dst, int* __restrict__ deg) {
  int i = blockIdx.x * blockDim.x + threadIdx.x;
  int stride = gridDim.x * blockDim.x;
  for (; i < Ee; i += stride) atomicAdd(&deg[dst[i]], 1);
}

// multi-block exclusive scan: scan1 (local) -> scan2 (block sums) -> scan3 (add)
__global__ __launch_bounds__(1024) void scan1_kernel(const int* __restrict__ deg,
                                                     int* __restrict__ off,
                                                     int* __restrict__ bsum) {
  __shared__ int wsum[16];
  int tid = threadIdx.x, lane = tid & 63, w = tid >> 6;
  int i = blockIdx.x * 1024 + tid;
  int v = (i < Nn) ? deg[i] : 0;
  int x = v;
#pragma unroll
  for (int o = 1; o < 64; o <<= 1) {
    int t = __shfl_up(x, o);
    if (lane >= o) x += t;
  }
  if (lane == 63) wsum[w] = x;
  __syncthreads();
  if (w == 0 && lane < 16) {
    int y = wsum[lane];
#pragma unroll
    for (int o = 1; o < 16; o <<= 1) {
      int t = __shfl_up(y, o);
      if (lane >= o) y += t;
    }
    wsum[lane] = y;
  }
  __syncthreads();
  int incl = x + (w ? wsum[w - 1] : 0);
  if (i < Nn) off[i] = incl - v;
  if (tid == 1023) bsum[blockIdx.x] = incl;
}

__global__ void scan2_kernel(const int* __restrict__ bsum, int* __restrict__ boff,
                             int* __restrict__ offN) {
  int lane = threadIdx.x;  // 64 threads
  int v = (lane < SCANB) ? bsum[lane] : 0;
  int x = v;
#pragma unroll
  for (int o = 1; o < 64; o <<= 1) {
    int t = __shfl_up(x, o);
    if (lane >= o) x += t;
  }
  if (lane < SCANB) boff[lane] = x - v;
  if (lane == 63) *offN = x;
}

__global__ void scan3_kernel(int* __restrict__ off, const int* __restrict__ boff) {
  int i = blockIdx.x * 256 + threadIdx.x;
  if (i < Nn) off[i] += boff[i >> 10];
}

__global__ void scatter_kernel(const int* __restrict__ src, const int* __restrict__ dst,
                               const int* __restrict__ off, int* __restrict__ cur,
                               int* __restrict__ ssrc) {
  int i = blockIdx.x * blockDim.x + threadIdx.x;
  int stride = gridDim.x * blockDim.x;
  for (; i < Ee; i += stride) {
    int d = dst[i];
    int pos = off[d] + atomicAdd(&cur[d], 1);
    ssrc[pos] = src[i];
  }
}

// ---------------- conversions ----------------

__global__ void round_kernel(const float* __restrict__ in, unsigned short* __restrict__ out,
                             int M, int K) {
  const int kg4 = K >> 2;
  int i = blockIdx.x * blockDim.x + threadIdx.x;
  const int total = M * kg4;
  const int stride = gridDim.x * blockDim.x;
  for (; i < total; i += stride) {
    const int row = i / kg4, kg = i - row * kg4;
    const float4 v = *(const float4*)(in + (size_t)row * K + kg * 4);
    ushort4 h;
    h.x = f2bf(v.x); h.y = f2bf(v.y); h.z = f2bf(v.z); h.w = f2bf(v.w);
    *(ushort4*)(out + (size_t)row * K + kg * 4) = h;
  }
}

// 4x W [K][256] fp32 -> B [1024][K] bf16 hi-only, transposed; row n = z*256+c
__global__ void convw_kernel(const float* __restrict__ W0, const float* __restrict__ W1,
                             const float* __restrict__ W2, const float* __restrict__ W3,
                             unsigned short* __restrict__ B, int K) {
  int i = blockIdx.x * blockDim.x + threadIdx.x;
  const int total = 1024 * K;
  const int stride = gridDim.x * blockDim.x;
  for (; i < total; i += stride) {
    const int n = i & 1023;
    const int k = i >> 10;
    const int z = n >> 8, c = n & 255;
    const float* W = z == 0 ? W0 : z == 1 ? W1 : z == 2 ? W2 : W3;
    B[(size_t)n * K + k] = f2bf(W[(size_t)k * Dd + c]);
  }
}

// ---------------- 1-term bf16 MFMA GEMM (128x128 tile, 2-barrier loop) ----------------
// C = A_bf16 @ B_hi + bias.  A [M][K] bf16, B [1024][K] bf16.
// outputs: z=0 -> q fp16 [M][256]; z=1/2 -> kv fp16 [M][512] interleaved
// (channel c: K at (c>>2)*8+(c&3), V at +4); z=3 -> s fp32 [M][256]

__global__ __launch_bounds__(256)
void gemm_mfma(const unsigned short* __restrict__ A2, int M, int K,
               const unsigned short* __restrict__ B,
               const float* __restrict__ b0, const float* __restrict__ b1,
               const float* __restrict__ b2, const float* __restrict__ b3,
               _Float16* __restrict__ qout, _Float16* __restrict__ kvout,
               float* __restrict__ sout) {
  __shared__ __align__(16) unsigned short As[128 * 64];
  __shared__ __align__(16) unsigned short Bs[128 * 64];
  const int tid = threadIdx.x;
  const int lane = tid & 63, w = tid >> 6;
  const int wr = w >> 1, wc = w & 1;
  const int p = blockIdx.x;
  const int xcd = p & 7;
  const int i2 = p >> 3;
  const int bm = (xcd * 49 + (i2 >> 3)) * 128;
  const int bn = (i2 & 7) * 128;
  const int lda = K, ldb = K;
  const int nsteps = K >> 6;
  const int srow = lane >> 3, sslot = lane & 7;
  const int fr = lane & 15, fq = lane >> 4;

  f32x4 acc[4][4] = {};

  for (int s = 0; s < nsteps; ++s) {
    const int kk = s << 6;
    __syncthreads();
#pragma unroll
    for (int h = 0; h < 4; ++h) {
      const int q = h * 4 + w;
      const int r = q * 8 + srow;
      const int g = sslot ^ (r & 7);
      int ga = bm + r; if (ga > M - 1) ga = M - 1;
      gload16(A2 + (size_t)ga * lda + kk + g * 8, (char*)As + q * 1024);
      const int gb = bn + r;
      gload16(B + (size_t)gb * ldb + kk + g * 8, (char*)Bs + q * 1024);
    }
    __syncthreads();
    short8 av[2][4], bv[2][4];
#pragma unroll
    for (int kh = 0; kh < 2; ++kh)
#pragma unroll
      for (int i = 0; i < 4; ++i) {
        const int ra = wr * 64 + i * 16 + fr;
        av[kh][i] = *(const short8*)((const char*)As + ra * 128 + (((kh * 4 + fq) ^ (ra & 7)) << 4));
        const int rb = wc * 64 + i * 16 + fr;
        bv[kh][i] = *(const short8*)((const char*)Bs + rb * 128 + (((kh * 4 + fq) ^ (rb & 7)) << 4));
      }
#pragma unroll
    for (int kh = 0; kh < 2; ++kh)
#pragma unroll
      for (int mi = 0; mi < 4; ++mi)
#pragma unroll
        for (int ni = 0; ni < 4; ++ni)
          acc[mi][ni] = __builtin_amdgcn_mfma_f32_16x16x32_bf16(
              __builtin_bit_cast(bf16x8, av[kh][mi]),
              __builtin_bit_cast(bf16x8, bv[kh][ni]), acc[mi][ni], 0, 0, 0);
  }

#pragma unroll
  for (int mi = 0; mi < 4; ++mi) {
    const int grow0 = bm + wr * 64 + mi * 16 + fq * 4;
#pragma unroll
    for (int ni = 0; ni < 4; ++ni) {
      const int nbase = bn + wc * 64 + ni * 16;
      const int z = nbase >> 8;
      const int c = (nbase & 255) + fr;
      const float* bp = z == 0 ? b0 : z == 1 ? b1 : z == 2 ? b2 : b3;
      const float bias = bp[c];
#pragma unroll
      for (int j = 0; j < 4; ++j) {
        const int grow = grow0 + j;
        if (grow < M) {
          const float val = acc[mi][ni][j] + bias;
          if (z == 0) {
            qout[(size_t)grow * Dd + c] = (_Float16)val;
          } else if (z == 3) {
            sout[(size_t)grow * Dd + c] = val;
          } else {
            const int idx = ((c >> 2) << 3) + (c & 3) + (z == 2 ? 4 : 0);
            kvout[(size_t)grow * 512 + idx] = (_Float16)val;
          }
        }
      }
    }
  }
}

// ---------------- per-node attention: TWO nodes per wave (online softmax x2) ----------------
// q: fp16 [Nn][256]; kv: fp16 [Nn][512], lane's 16B slot = {K[4c..4c+3], V[4c..4c+3]}
// 4-edge masked batches per node, 8 gathers in flight, 2 independent VALU chains.
// MODE 0: write relu(out) bf16 [Nn][256]; MODE 1: fp32.

__device__ inline float hdot4(half2v a01, half2v a23, half2v b01, half2v b23) {
#ifdef HAS_FDOT2
  return __builtin_amdgcn_fdot2(a01, b01, __builtin_amdgcn_fdot2(a23, b23, 0.f, false), false);
#else
  float r = (float)a01[0] * (float)b01[0];
  r = fmaf((float)a01[1], (float)b01[1], r);
  r = fmaf((float)a23[0], (float)b23[0], r);
  r = fmaf((float)a23[1], (float)b23[1], r);
  return r;
#endif
}

template <int MODE>
__global__ __launch_bounds__(256)
void attn_kernel(const _Float16* __restrict__ qbuf, const _Float16* __restrict__ kvbuf,
                 const float* __restrict__ sbuf, const int* __restrict__ off,
                 const int* __restrict__ ssrc, float* __restrict__ hout,
                 unsigned short* __restrict__ hbout) {
  const int wv = (int)((blockIdx.x * 256 + threadIdx.x) >> 6);
  const int g0 = wv * 2;
  if (g0 >= Nn) return;
  const int g1 = g0 + 1;
  const bool has1 = g1 < Nn;
  const int lane = threadIdx.x & 63;
  const float scale = 0.08838834764831845f;

  const uint2 qv0 = *(const uint2*)(qbuf + (size_t)g0 * Dd + lane * 4);
  const uint2 qv1 = has1 ? *(const uint2*)(qbuf + (size_t)g1 * Dd + lane * 4) : qv0;
  const half2v q001 = __builtin_bit_cast(half2v, qv0.x);
  const half2v q023 = __builtin_bit_cast(half2v, qv0.y);
  const half2v q101 = __builtin_bit_cast(half2v, qv1.x);
  const half2v q123 = __builtin_bit_cast(half2v, qv1.y);

  const int a0 = off[g0], a1 = off[g0 + 1];
  const int b0 = a1, b1 = has1 ? off[g1 + 1] : a1;
  const int la = (a1 > a0) ? a1 - 1 : 0;
  const int lb = (b1 > b0) ? b1 - 1 : 0;
  const int nb = max(a1 - a0, b1 - b0);

  float m0 = -3.4e38f, d0 = 0.f, m1 = -3.4e38f, d1 = 0.f;
  float ax0 = 0, ay0 = 0, az0 = 0, aw0 = 0;
  float ax1 = 0, ay1 = 0, az1 = 0, aw1 = 0;

  for (int t0 = 0; t0 < nb; t0 += 4) {
    int sx[8];
#pragma unroll
    for (int t = 0; t < 4; ++t) {
      const int ea = a0 + t0 + t;
      sx[t] = ssrc[ea < a1 ? ea : la];
      const int eb = b0 + t0 + t;
      sx[4 + t] = ssrc[eb < b1 ? eb : lb];
    }
    uint4 u[8];
#pragma unroll
    for (int t = 0; t < 8; ++t)
      u[t] = *(const uint4*)(kvbuf + (size_t)sx[t] * 512 + lane * 8);
    float p[8];
#pragma unroll
    for (int t = 0; t < 4; ++t) {
      p[t] = hdot4(q001, q023, __builtin_bit_cast(half2v, u[t].x),
                   __builtin_bit_cast(half2v, u[t].y));
      p[4 + t] = hdot4(q101, q123, __builtin_bit_cast(half2v, u[4 + t].x),
                       __builtin_bit_cast(half2v, u[4 + t].y));
    }
#pragma unroll
    for (int o = 16; o >= 1; o >>= 1)
#pragma unroll
      for (int t = 0; t < 8; ++t) p[t] += __shfl_xor(p[t], o);
    float sc[8];
#pragma unroll
    for (int t = 0; t < 4; ++t) {
      sc[t] = (a0 + t0 + t < a1) ? p[t] * scale : -3.0e38f;
      sc[4 + t] = (b0 + t0 + t < b1) ? p[4 + t] * scale : -3.0e38f;
    }
    // node 0 update
    {
      float mx = m0;
#pragma unroll
      for (int t = 0; t < 4; ++t) mx = fmaxf(mx, sc[t]);
      const float f = __expf(m0 - mx);
      float wsum = 0.f, vx = 0.f, vy = 0.f, vz = 0.f, vw = 0.f;
#pragma unroll
      for (int t = 0; t < 4; ++t) {
        const float wt = __expf(sc[t] - mx);
        const half2v v01 = __builtin_bit_cast(half2v, u[t].z);
        const half2v v23 = __builtin_bit_cast(half2v, u[t].w);
        wsum += wt;
        vx = fmaf(wt, (float)v01[0], vx);
        vy = fmaf(wt, (float)v01[1], vy);
        vz = fmaf(wt, (float)v23[0], vz);
        vw = fmaf(wt, (float)v23[1], vw);
      }
      d0 = d0 * f + wsum;
      ax0 = ax0 * f + vx; ay0 = ay0 * f + vy;
      az0 = az0 * f + vz; aw0 = aw0 * f + vw;
      m0 = mx;
    }
    // node 1 update
    {
      float mx = m1;
#pragma unroll
      for (int t = 4; t < 8; ++t) mx = fmaxf(mx, sc[t]);
      const float f = __expf(m1 - mx);
      float wsum = 0.f, vx = 0.f, vy = 0.f, vz = 0.f, vw = 0.f;
#pragma unroll
      for (int t = 4; t < 8; ++t) {
        const float wt = __expf(sc[t] - mx);
        const half2v v01 = __builtin_bit_cast(half2v, u[t].z);
        const half2v v23 = __builtin_bit_cast(half2v, u[t].w);
        wsum += wt;
        vx = fmaf(wt, (float)v01[0], vx);
        vy = fmaf(wt, (float)v01[1], vy);
        vz = fmaf(wt, (float)v23[0], vz);
        vw = fmaf(wt, (float)v23[1], vw);
      }
      d1 = d1 * f + wsum;
      ax1 = ax1 * f + vx; ay1 = ay1 * f + vy;
      az1 = az1 * f + vz; aw1 = aw1 * f + vw;
      m1 = mx;
    }
  }

  {
    const float inv = 1.f / (d0 + 1e-16f);
    const float4 sk = *(const float4*)(sbuf + (size_t)g0 * Dd + lane * 4);
    float4 o;
    o.x = fmaxf(ax0 * inv + sk.x, 0.f);
    o.y = fmaxf(ay0 * inv + sk.y, 0.f);
    o.z = fmaxf(az0 * inv + sk.z, 0.f);
    o.w = fmaxf(aw0 * inv + sk.w, 0.f);
    if (MODE == 0) {
      ushort4 hh;
      hh.x = f2bf(o.x); hh.y = f2bf(o.y); hh.z = f2bf(o.z); hh.w = f2bf(o.w);
      *(ushort4*)(hbout + (size_t)g0 * Dd + lane * 4) = hh;
    } else {
      *(float4*)(hout + (size_t)g0 * Dd + lane * 4) = o;
    }
  }
  if (has1) {
    const float inv = 1.f / (d1 + 1e-16f);
    const float4 sk = *(const float4*)(sbuf + (size_t)g1 * Dd + lane * 4);
    float4 o;
    o.x = fmaxf(ax1 * inv + sk.x, 0.f);
    o.y = fmaxf(ay1 * inv + sk.y, 0.f);
    o.z = fmaxf(az1 * inv + sk.z, 0.f);
    o.w = fmaxf(aw1 * inv + sk.w, 0.f);
    if (MODE == 0) {
      ushort4 hh;
      hh.x = f2bf(o.x); hh.y = f2bf(o.y); hh.z = f2bf(o.z); hh.w = f2bf(o.w);
      *(ushort4*)(hbout + (size_t)g1 * Dd + lane * 4) = hh;
    } else {
      *(float4*)(hout + (size_t)g1 * Dd + lane * 4) = o;
    }
  }
}

// ---------------- pooling + fc ----------------

__global__ __launch_bounds__(256)
void pool_kernel(const float* __restrict__ h, const int* __restrict__ batch,
                 float* __restrict__ pooled) {
  int c = threadIdx.x;
  int n0 = blockIdx.x * 128;
  int n1 = min(n0 + 128, Nn);
  int curg = batch[n0];
  float mx = 0.f;
  for (int n = n0; n < n1; ++n) {
    int g = batch[n];
    if (g != curg) {
      atomicMax((int*)(pooled + curg * Dd + c), __float_as_int(mx));
      mx = 0.f;
      curg = g;
    }
    mx = fmaxf(mx, h[(size_t)n * Dd + c]);
  }
  atomicMax((int*)(pooled + curg * Dd + c), __float_as_int(mx));
}

__global__ __launch_bounds__(512)
void fc_kernel(const float* __restrict__ pooled,
               const float* __restrict__ wf1, const float* __restrict__ bf1,
               const float* __restrict__ wf2, const float* __restrict__ bf2,
               float* __restrict__ outp) {
  __shared__ float t[Gg][64];
  int tid = threadIdx.x;
  int g = tid >> 6, j = tid & 63;
  float acc = bf1[j];
  for (int c = 0; c < Dd; ++c) acc = fmaf(pooled[g * Dd + c], wf1[c * 64 + j], acc);
  t[g][j] = acc;
  __syncthreads();
  if (tid < Gg * 4) {
    int gg = tid >> 2, cc = tid & 3;
    float a2 = bf2[cc];
    for (int j2 = 0; j2 < 64; ++j2) a2 = fmaf(t[gg][j2], wf2[j2 * 4 + cc], a2);
    outp[gg * 4 + cc] = a2;
  }
}

// ---------------- host ----------------

extern "C" void kernel_launch(void* const* d_in, const int* in_sizes, int n_in,
                              void* d_out, int out_size, void* d_ws, size_t ws_size,
                              hipStream_t stream) {
  const float* x   = (const float*)d_in[0];
  const int* ei    = (const int*)d_in[1];
  const int* srcE  = ei;
  const int* dstE  = ei + Ee;
  const int* batch = (const int*)d_in[2];
  const float* wq1 = (const float*)d_in[3];  const float* bq1 = (const float*)d_in[4];
  const float* wk1 = (const float*)d_in[5];  const float* bk1 = (const float*)d_in[6];
  const float* wv1 = (const float*)d_in[7];  const float* bv1 = (const float*)d_in[8];
  const float* ws1 = (const float*)d_in[9];  const float* bs1 = (const float*)d_in[10];
  const float* wq2 = (const float*)d_in[11]; const float* bq2 = (const float*)d_in[12];
  const float* wk2 = (const float*)d_in[13]; const float* bk2 = (const float*)d_in[14];
  const float* wv2 = (const float*)d_in[15]; const float* bv2 = (const float*)d_in[16];
  const float* ws2 = (const float*)d_in[17]; const float* bs2 = (const float*)d_in[18];
  const float* wf1 = (const float*)d_in[19]; const float* bf1 = (const float*)d_in[20];
  const float* wf2 = (const float*)d_in[21]; const float* bf2 = (const float*)d_in[22];
  float* outp = (float*)d_out;
  char* ws = (char*)d_ws;

  auto al256 = [](size_t v) { return (v + 255) & ~(size_t)255; };
  size_t o_deg  = 0;
  size_t o_cur  = o_deg + (size_t)Nn * 4;
  size_t o_pool = o_cur + (size_t)Nn * 4;
  size_t zbytes = o_pool + (size_t)Gg * Dd * 4;
  size_t o_off  = al256(zbytes);
  size_t o_ssrc = al256(o_off + (size_t)(Nn + 1) * 4);
  size_t o_q    = al256(o_ssrc + (size_t)Ee * 4);                 // fp16 [Nn][256]
  size_t o_kv   = al256(o_q + (size_t)Nn * Dd * 2);               // fp16 [Nn][512]
  size_t o_s    = al256(o_kv + (size_t)Nn * 512 * 2);             // fp32 [Nn][256]
  size_t o_b1   = al256(o_s + (size_t)Nn * Dd * 4);               // bf16 [1024][512]
  size_t o_b2   = al256(o_b1 + (size_t)1024 * Ff * 2);            // bf16 [1024][256]
  size_t o_a    = al256(o_b2 + (size_t)1024 * Dd * 2);            // bf16 [Nn][512] / h bf16 overlay
  size_t o_h2   = al256(o_a + (size_t)Nn * Ff * 2);
  size_t o_bsum = al256(o_h2 + (size_t)Nn * Dd * 4);
  size_t o_boff = al256(o_bsum + (size_t)SCANB * 4);
  size_t total  = o_boff + (size_t)SCANB * 4;
  if (ws_size < total) {
    fprintf(stderr, "kernel_launch: ws too small: %zu < %zu\n", ws_size, total);
    return;
  }

  int*   deg    = (int*)(ws + o_deg);
  int*   cur    = (int*)(ws + o_cur);
  float* pooled = (float*)(ws + o_pool);
  int*   off    = (int*)(ws + o_off);
  int*   ssrc   = (int*)(ws + o_ssrc);
  _Float16* qb  = (_Float16*)(ws + o_q);
  _Float16* kvb = (_Float16*)(ws + o_kv);
  float* sb     = (float*)(ws + o_s);
  unsigned short* b1 = (unsigned short*)(ws + o_b1);
  unsigned short* b2 = (unsigned short*)(ws + o_b2);
  unsigned short* a2  = (unsigned short*)(ws + o_a);    // [Nn][512] bf16
  unsigned short* h2b = (unsigned short*)(ws + o_a);    // [Nn][256] bf16 (overlays a2)
  float* h2     = (float*)(ws + o_h2);                  // [Nn][256] fp32
  int* bsum     = (int*)(ws + o_bsum);
  int* boff     = (int*)(ws + o_boff);

  hipMemsetAsync(ws, 0, zbytes, stream);
  hist_kernel<<<1024, 256, 0, stream>>>(dstE, deg);
  scan1_kernel<<<SCANB, 1024, 0, stream>>>(deg, off, bsum);
  scan2_kernel<<<1, 64, 0, stream>>>(bsum, boff, off + Nn);
  scan3_kernel<<<(Nn + 255) / 256, 256, 0, stream>>>(off, boff);
  scatter_kernel<<<1024, 256, 0, stream>>>(srcE, dstE, off, cur, ssrc);

  convw_kernel<<<1024, 256, 0, stream>>>(wq1, wk1, wv1, ws1, b1, Ff);
  convw_kernel<<<1024, 256, 0, stream>>>(wq2, wk2, wv2, ws2, b2, Dd);
  round_kernel<<<4096, 256, 0, stream>>>(x, a2, Nn, Ff);

  gemm_mfma<<<3136, 256, 0, stream>>>(a2, Nn, Ff, b1, bq1, bk1, bv1, bs1, qb, kvb, sb);
  attn_kernel<0><<<(Nn + 7) / 8, 256, 0, stream>>>(qb, kvb, sb, off, ssrc, nullptr, h2b);
  gemm_mfma<<<3136, 256, 0, stream>>>(h2b, Nn, Dd, b2, bq2, bk2, bv2, bs2, qb, kvb, sb);
  attn_kernel<1><<<(Nn + 7) / 8, 256, 0, stream>>>(qb, kvb, sb, off, ssrc, h2, nullptr);

  pool_kernel<<<(Nn + 127) / 128, 256, 0, stream>>>(h2, batch, pooled);
  fc_kernel<<<1, 512, 0, stream>>>(pooled, wf1, bf1, wf2, bf2, outp);
}

// Round 11
// 563.177 us; speedup vs baseline: 1.6823x; 1.0786x over previous
//
#include <hip/hip_runtime.h>
#include <cstdio>

#define Nn 50000
#define Ee 800000
#define Ff 512
#define Dd 256
#define Gg 8
#define SCANB 49   // ceil(Nn/1024)

typedef short short8 __attribute__((ext_vector_type(8)));
typedef __bf16 bf16x8 __attribute__((ext_vector_type(8)));
typedef float f32x4 __attribute__((ext_vector_type(4)));
typedef _Float16 half2v __attribute__((ext_vector_type(2)));

#if defined(__has_builtin)
#if __has_builtin(__builtin_amdgcn_fdot2)
#define HAS_FDOT2 1
#endif
#if __has_builtin(__builtin_amdgcn_cvt_f32_fp8)
#define HAS_CVTFP8 1
#endif
#endif

__device__ inline unsigned short f2bf(float f) {
  unsigned u = __float_as_uint(f);
  u += 0x7FFFu + ((u >> 16) & 1u);
  return (unsigned short)(u >> 16);
}
__device__ inline float bf2f(unsigned short h) {
  return __uint_as_float(((unsigned)h) << 16);
}

// OCP e4m3 encode (RNE, clamp to +-448, denormals handled)
__device__ inline unsigned char f2fp8(float f) {
  const float af = fabsf(f);
  const unsigned s = (f < 0.f) ? 0x80u : 0u;
  if (af >= 448.f) return (unsigned char)(s | 0x7E);
  if (af < 0.015625f) {                       // denormal range (< 2^-6)
    int q = (int)(af * 512.f + 0.5f);         // step 2^-9; q==8 -> 2^-6 normal (bits align)
    return (unsigned char)(s | q);
  }
  unsigned u = __float_as_uint(af);
  unsigned m = u & 0x7fffffu;
  unsigned e = u >> 23;
  unsigned r = m + 0x7ffffu + ((m >> 20) & 1u);
  if (r >> 23) { e += 1; r = 0; }
  unsigned em = ((e - 120u) << 3) | ((r >> 20) & 7u);
  if (em > 0x7Eu) em = 0x7Eu;
  return (unsigned char)(s | em);
}

// OCP e4m3 decode, byte SEL of a dword (SEL is a compile-time constant)
template <int SEL>
__device__ inline float fp8tof(unsigned v) {
#ifdef HAS_CVTFP8
  return __builtin_amdgcn_cvt_f32_fp8(v, SEL);
#else
  unsigned b = (v >> (SEL * 8)) & 0xffu;
  unsigned em = b & 0x7fu;
  float n = __uint_as_float((em << 20) + 0x3C000000u);   // normal: (em>>3)-7 exp, 3-bit mant
  float dn = (float)em * 0.001953125f;                   // em * 2^-9
  float r = (em < 8u) ? dn : n;
  return (b & 0x80u) ? -r : r;
#endif
}

__device__ inline void gload16(const void* g, void* l) {
  __builtin_amdgcn_global_load_lds((const __attribute__((address_space(1))) void*)g,
                                   (__attribute__((address_space(3))) void*)l, 16, 0, 0);
}

// ---------------- CSR build ----------------

__global__ void hist_kernel(const int* __restrict__ dst, int* __restrict__ deg) {
  int i = blockIdx.x * blockDim.x + threadIdx.x;
  int stride = gridDim.x * blockDim.x;
  for (; i < Ee; i += stride) atomicAdd(&deg[dst[i]], 1);
}

__global__ __launch_bounds__(1024) void scan1_kernel(const int* __restrict__ deg,
                                                     int* __restrict__ off,
                                                     int* __restrict__ bsum) {
  __shared__ int wsum[16];
  int tid = threadIdx.x, lane = tid & 63, w = tid >> 6;
  int i = blockIdx.x * 1024 + tid;
  int v = (i < Nn) ? deg[i] : 0;
  int x = v;
#pragma unroll
  for (int o = 1; o < 64; o <<= 1) {
    int t = __shfl_up(x, o);
    if (lane >= o) x += t;
  }
  if (lane == 63) wsum[w] = x;
  __syncthreads();
  if (w == 0 && lane < 16) {
    int y = wsum[lane];
#pragma unroll
    for (int o = 1; o < 16; o <<= 1) {
      int t = __shfl_up(y, o);
      if (lane >= o) y += t;
    }
    wsum[lane] = y;
  }
  __syncthreads();
  int incl = x + (w ? wsum[w - 1] : 0);
  if (i < Nn) off[i] = incl - v;
  if (tid == 1023) bsum[blockIdx.x] = incl;
}

__global__ void scan2_kernel(const int* __restrict__ bsum, int* __restrict__ boff,
                             int* __restrict__ offN) {
  int lane = threadIdx.x;  // 64 threads
  int v = (lane < SCANB) ? bsum[lane] : 0;
  int x = v;
#pragma unroll
  for (int o = 1; o < 64; o <<= 1) {
    int t = __shfl_up(x, o);
    if (lane >= o) x += t;
  }
  if (lane < SCANB) boff[lane] = x - v;
  if (lane == 63) *offN = x;
}

__global__ void scan3_kernel(int* __restrict__ off, const int* __restrict__ boff) {
  int i = blockIdx.x * 256 + threadIdx.x;
  if (i < Nn) off[i] += boff[i >> 10];
}

__global__ void scatter_kernel(const int* __restrict__ src, const int* __restrict__ dst,
                               const int* __restrict__ off, int* __restrict__ cur,
                               int* __restrict__ ssrc) {
  int i = blockIdx.x * blockDim.x + threadIdx.x;
  int stride = gridDim.x * blockDim.x;
  for (; i < Ee; i += stride) {
    int d = dst[i];
    int pos = off[d] + atomicAdd(&cur[d], 1);
    ssrc[pos] = src[i];
  }
}

// ---------------- conversions ----------------

__global__ void round_kernel(const float* __restrict__ in, unsigned short* __restrict__ out,
                             int M, int K) {
  const int kg4 = K >> 2;
  int i = blockIdx.x * blockDim.x + threadIdx.x;
  const int total = M * kg4;
  const int stride = gridDim.x * blockDim.x;
  for (; i < total; i += stride) {
    const int row = i / kg4, kg = i - row * kg4;
    const float4 v = *(const float4*)(in + (size_t)row * K + kg * 4);
    ushort4 h;
    h.x = f2bf(v.x); h.y = f2bf(v.y); h.z = f2bf(v.z); h.w = f2bf(v.w);
    *(ushort4*)(out + (size_t)row * K + kg * 4) = h;
  }
}

// 4x W [K][256] fp32 -> B [1024][K] bf16 hi-only, transposed; row n = z*256+c
__global__ void convw_kernel(const float* __restrict__ W0, const float* __restrict__ W1,
                             const float* __restrict__ W2, const float* __restrict__ W3,
                             unsigned short* __restrict__ B, int K) {
  int i = blockIdx.x * blockDim.x + threadIdx.x;
  const int total = 1024 * K;
  const int stride = gridDim.x * blockDim.x;
  for (; i < total; i += stride) {
    const int n = i & 1023;
    const int k = i >> 10;
    const int z = n >> 8, c = n & 255;
    const float* W = z == 0 ? W0 : z == 1 ? W1 : z == 2 ? W2 : W3;
    B[(size_t)n * K + k] = f2bf(W[(size_t)k * Dd + c]);
  }
}

// ---------------- 1-term bf16 MFMA GEMM (128x128 tile, 2-barrier loop) ----------------
// C = A_bf16 @ B_hi + bias.  A [M][K] bf16, B [1024][K] bf16.
// outputs: z=0 -> q fp16 [M][256]; z=1 -> K fp16 into kv row bytes [c*2];
// z=2 -> V fp8 into kv row bytes [512+c]; z=3 -> s fp16 [M][256].
// kv row stride = 768 bytes.

__global__ __launch_bounds__(256)
void gemm_mfma(const unsigned short* __restrict__ A2, int M, int K,
               const unsigned short* __restrict__ B,
               const float* __restrict__ b0, const float* __restrict__ b1,
               const float* __restrict__ b2, const float* __restrict__ b3,
               _Float16* __restrict__ qout, unsigned char* __restrict__ kvout,
               _Float16* __restrict__ sout) {
  __shared__ __align__(16) unsigned short As[128 * 64];
  __shared__ __align__(16) unsigned short Bs[128 * 64];
  const int tid = threadIdx.x;
  const int lane = tid & 63, w = tid >> 6;
  const int wr = w >> 1, wc = w & 1;
  const int p = blockIdx.x;
  const int xcd = p & 7;
  const int i2 = p >> 3;
  const int bm = (xcd * 49 + (i2 >> 3)) * 128;
  const int bn = (i2 & 7) * 128;
  const int lda = K, ldb = K;
  const int nsteps = K >> 6;
  const int srow = lane >> 3, sslot = lane & 7;
  const int fr = lane & 15, fq = lane >> 4;

  f32x4 acc[4][4] = {};

  for (int s = 0; s < nsteps; ++s) {
    const int kk = s << 6;
    __syncthreads();
#pragma unroll
    for (int h = 0; h < 4; ++h) {
      const int q = h * 4 + w;
      const int r = q * 8 + srow;
      const int g = sslot ^ (r & 7);
      int ga = bm + r; if (ga > M - 1) ga = M - 1;
      gload16(A2 + (size_t)ga * lda + kk + g * 8, (char*)As + q * 1024);
      const int gb = bn + r;
      gload16(B + (size_t)gb * ldb + kk + g * 8, (char*)Bs + q * 1024);
    }
    __syncthreads();
    short8 av[2][4], bv[2][4];
#pragma unroll
    for (int kh = 0; kh < 2; ++kh)
#pragma unroll
      for (int i = 0; i < 4; ++i) {
        const int ra = wr * 64 + i * 16 + fr;
        av[kh][i] = *(const short8*)((const char*)As + ra * 128 + (((kh * 4 + fq) ^ (ra & 7)) << 4));
        const int rb = wc * 64 + i * 16 + fr;
        bv[kh][i] = *(const short8*)((const char*)Bs + rb * 128 + (((kh * 4 + fq) ^ (rb & 7)) << 4));
      }
#pragma unroll
    for (int kh = 0; kh < 2; ++kh)
#pragma unroll
      for (int mi = 0; mi < 4; ++mi)
#pragma unroll
        for (int ni = 0; ni < 4; ++ni)
          acc[mi][ni] = __builtin_amdgcn_mfma_f32_16x16x32_bf16(
              __builtin_bit_cast(bf16x8, av[kh][mi]),
              __builtin_bit_cast(bf16x8, bv[kh][ni]), acc[mi][ni], 0, 0, 0);
  }

#pragma unroll
  for (int mi = 0; mi < 4; ++mi) {
    const int grow0 = bm + wr * 64 + mi * 16 + fq * 4;
#pragma unroll
    for (int ni = 0; ni < 4; ++ni) {
      const int nbase = bn + wc * 64 + ni * 16;
      const int z = nbase >> 8;
      const int c = (nbase & 255) + fr;
      const float* bp = z == 0 ? b0 : z == 1 ? b1 : z == 2 ? b2 : b3;
      const float bias = bp[c];
#pragma unroll
      for (int j = 0; j < 4; ++j) {
        const int grow = grow0 + j;
        if (grow < M) {
          const float val = acc[mi][ni][j] + bias;
          if (z == 0) {
            qout[(size_t)grow * Dd + c] = (_Float16)val;
          } else if (z == 3) {
            sout[(size_t)grow * Dd + c] = (_Float16)val;
          } else if (z == 1) {
            *(_Float16*)(kvout + (size_t)grow * 768 + c * 2) = (_Float16)val;
          } else {
            kvout[(size_t)grow * 768 + 512 + c] = f2fp8(val);
          }
        }
      }
    }
  }
}

// ---------------- per-node attention (one wave per dst node, online softmax) ----------------
// q: fp16 [Nn][256]; kv row 768B: K fp16 at [c*2], V fp8 at [512+c]; s fp16 [Nn][256].
// masked 8-edge unroll; dot via v_dot2_f32_f16; output relu(.) bf16 [Nn][256].

__device__ inline float hdot4(half2v a01, half2v a23, half2v b01, half2v b23) {
#ifdef HAS_FDOT2
  return __builtin_amdgcn_fdot2(a01, b01, __builtin_amdgcn_fdot2(a23, b23, 0.f, false), false);
#else
  float r = (float)a01[0] * (float)b01[0];
  r = fmaf((float)a01[1], (float)b01[1], r);
  r = fmaf((float)a23[0], (float)b23[0], r);
  r = fmaf((float)a23[1], (float)b23[1], r);
  return r;
#endif
}

__global__ __launch_bounds__(256)
void attn_kernel(const _Float16* __restrict__ qbuf, const unsigned char* __restrict__ kvb,
                 const _Float16* __restrict__ sbuf, const int* __restrict__ off,
                 const int* __restrict__ ssrc, unsigned short* __restrict__ hbout) {
  int gw = (int)((blockIdx.x * 256 + threadIdx.x) >> 6);
  if (gw >= Nn) return;
  int lane = threadIdx.x & 63;

  const uint2 qv = *(const uint2*)(qbuf + (size_t)gw * Dd + lane * 4);
  const half2v q01 = __builtin_bit_cast(half2v, qv.x);
  const half2v q23 = __builtin_bit_cast(half2v, qv.y);
  int e0 = off[gw], e1 = off[gw + 1];
  const float scale = 0.08838834764831845f;

  float m = -3.4e38f, d = 0.f;
  float ax = 0.f, ay = 0.f, az = 0.f, aw = 0.f;

  for (int e = e0; e < e1; e += 8) {
    int sx[8];
#pragma unroll
    for (int t = 0; t < 8; ++t) {
      const int ee = e + t;
      sx[t] = ssrc[ee < e1 ? ee : e1 - 1];
    }
    uint2 ku[8];
    unsigned vu[8];
#pragma unroll
    for (int t = 0; t < 8; ++t) {
      const unsigned char* row = kvb + (size_t)sx[t] * 768;
      ku[t] = *(const uint2*)(row + lane * 8);
      vu[t] = *(const unsigned*)(row + 512 + lane * 4);
    }
    float p[8];
#pragma unroll
    for (int t = 0; t < 8; ++t)
      p[t] = hdot4(q01, q23, __builtin_bit_cast(half2v, ku[t].x),
                   __builtin_bit_cast(half2v, ku[t].y));
#pragma unroll
    for (int o = 16; o >= 1; o >>= 1)
#pragma unroll
      for (int t = 0; t < 8; ++t) p[t] += __shfl_xor(p[t], o);
    float sc[8];
#pragma unroll
    for (int t = 0; t < 8; ++t)
      sc[t] = (e + t < e1) ? p[t] * scale : -3.0e38f;
    float mx = m;
#pragma unroll
    for (int t = 0; t < 8; ++t) mx = fmaxf(mx, sc[t]);
    const float f = __expf(m - mx);
    float wsum = 0.f, vx = 0.f, vy = 0.f, vz = 0.f, vw = 0.f;
#pragma unroll
    for (int t = 0; t < 8; ++t) {
      const float wt = __expf(sc[t] - mx);
      wsum += wt;
      vx = fmaf(wt, fp8tof<0>(vu[t]), vx);
      vy = fmaf(wt, fp8tof<1>(vu[t]), vy);
      vz = fmaf(wt, fp8tof<2>(vu[t]), vz);
      vw = fmaf(wt, fp8tof<3>(vu[t]), vw);
    }
    d = d * f + wsum;
    ax = ax * f + vx;
    ay = ay * f + vy;
    az = az * f + vz;
    aw = aw * f + vw;
    m = mx;
  }

  float inv = 1.f / (d + 1e-16f);
  const uint2 sv = *(const uint2*)(sbuf + (size_t)gw * Dd + lane * 4);
  const half2v s01 = __builtin_bit_cast(half2v, sv.x);
  const half2v s23 = __builtin_bit_cast(half2v, sv.y);
  ushort4 hh;
  hh.x = f2bf(fmaxf(fmaf(ax, inv, (float)s01[0]), 0.f));
  hh.y = f2bf(fmaxf(fmaf(ay, inv, (float)s01[1]), 0.f));
  hh.z = f2bf(fmaxf(fmaf(az, inv, (float)s23[0]), 0.f));
  hh.w = f2bf(fmaxf(fmaf(aw, inv, (float)s23[1]), 0.f));
  *(ushort4*)(hbout + (size_t)gw * Dd + lane * 4) = hh;
}

// ---------------- pooling (bf16 input) + fc ----------------

__global__ __launch_bounds__(256)
void pool_kernel(const unsigned short* __restrict__ h, const int* __restrict__ batch,
                 float* __restrict__ pooled) {
  int c = threadIdx.x;
  int n0 = blockIdx.x * 128;
  int n1 = min(n0 + 128, Nn);
  int curg = batch[n0];
  float mx = 0.f;
  for (int n = n0; n < n1; ++n) {
    int g = batch[n];
    if (g != curg) {
      atomicMax((int*)(pooled + curg * Dd + c), __float_as_int(mx));
      mx = 0.f;
      curg = g;
    }
    mx = fmaxf(mx, bf2f(h[(size_t)n * Dd + c]));
  }
  atomicMax((int*)(pooled + curg * Dd + c), __float_as_int(mx));
}

__global__ __launch_bounds__(512)
void fc_kernel(const float* __restrict__ pooled,
               const float* __restrict__ wf1, const float* __restrict__ bf1,
               const float* __restrict__ wf2, const float* __restrict__ bf2,
               float* __restrict__ outp) {
  __shared__ float t[Gg][64];
  int tid = threadIdx.x;
  int g = tid >> 6, j = tid & 63;
  float acc = bf1[j];
  for (int c = 0; c < Dd; ++c) acc = fmaf(pooled[g * Dd + c], wf1[c * 64 + j], acc);
  t[g][j] = acc;
  __syncthreads();
  if (tid < Gg * 4) {
    int gg = tid >> 2, cc = tid & 3;
    float a2 = bf2[cc];
    for (int j2 = 0; j2 < 64; ++j2) a2 = fmaf(t[gg][j2], wf2[j2 * 4 + cc], a2);
    outp[gg * 4 + cc] = a2;
  }
}

// ---------------- host ----------------

extern "C" void kernel_launch(void* const* d_in, const int* in_sizes, int n_in,
                              void* d_out, int out_size, void* d_ws, size_t ws_size,
                              hipStream_t stream) {
  const float* x   = (const float*)d_in[0];
  const int* ei    = (const int*)d_in[1];
  const int* srcE  = ei;
  const int* dstE  = ei + Ee;
  const int* batch = (const int*)d_in[2];
  const float* wq1 = (const float*)d_in[3];  const float* bq1 = (const float*)d_in[4];
  const float* wk1 = (const float*)d_in[5];  const float* bk1 = (const float*)d_in[6];
  const float* wv1 = (const float*)d_in[7];  const float* bv1 = (const float*)d_in[8];
  const float* ws1 = (const float*)d_in[9];  const float* bs1 = (const float*)d_in[10];
  const float* wq2 = (const float*)d_in[11]; const float* bq2 = (const float*)d_in[12];
  const float* wk2 = (const float*)d_in[13]; const float* bk2 = (const float*)d_in[14];
  const float* wv2 = (const float*)d_in[15]; const float* bv2 = (const float*)d_in[16];
  const float* ws2 = (const float*)d_in[17]; const float* bs2 = (const float*)d_in[18];
  const float* wf1 = (const float*)d_in[19]; const float* bf1 = (const float*)d_in[20];
  const float* wf2 = (const float*)d_in[21]; const float* bf2 = (const float*)d_in[22];
  float* outp = (float*)d_out;
  char* ws = (char*)d_ws;

  auto al256 = [](size_t v) { return (v + 255) & ~(size_t)255; };
  size_t o_deg  = 0;
  size_t o_cur  = o_deg + (size_t)Nn * 4;
  size_t o_pool = o_cur + (size_t)Nn * 4;
  size_t zbytes = o_pool + (size_t)Gg * Dd * 4;
  size_t o_off  = al256(zbytes);
  size_t o_ssrc = al256(o_off + (size_t)(Nn + 1) * 4);
  size_t o_q    = al256(o_ssrc + (size_t)Ee * 4);                 // fp16 [Nn][256]
  size_t o_kv   = al256(o_q + (size_t)Nn * Dd * 2);               // 768B rows [Nn]
  size_t o_s    = al256(o_kv + (size_t)Nn * 768);                 // fp16 [Nn][256]
  size_t o_b1   = al256(o_s + (size_t)Nn * Dd * 2);               // bf16 [1024][512]
  size_t o_b2   = al256(o_b1 + (size_t)1024 * Ff * 2);            // bf16 [1024][256]
  size_t o_a    = al256(o_b2 + (size_t)1024 * Dd * 2);            // bf16 [Nn][512] x / h overlay
  size_t o_bsum = al256(o_a + (size_t)Nn * Ff * 2);
  size_t o_boff = al256(o_bsum + (size_t)SCANB * 4);
  size_t total  = o_boff + (size_t)SCANB * 4;
  if (ws_size < total) {
    fprintf(stderr, "kernel_launch: ws too small: %zu < %zu\n", ws_size, total);
    return;
  }

  int*   deg    = (int*)(ws + o_deg);
  int*   cur    = (int*)(ws + o_cur);
  float* pooled = (float*)(ws + o_pool);
  int*   off    = (int*)(ws + o_off);
  int*   ssrc   = (int*)(ws + o_ssrc);
  _Float16* qb  = (_Float16*)(ws + o_q);
  unsigned char* kvb = (unsigned char*)(ws + o_kv);
  _Float16* sb  = (_Float16*)(ws + o_s);
  unsigned short* b1 = (unsigned short*)(ws + o_b1);
  unsigned short* b2 = (unsigned short*)(ws + o_b2);
  unsigned short* a2  = (unsigned short*)(ws + o_a);    // [Nn][512] bf16 (x)
  unsigned short* hb  = (unsigned short*)(ws + o_a);    // [Nn][256] bf16 h (overlays a2)
  int* bsum     = (int*)(ws + o_bsum);
  int* boff     = (int*)(ws + o_boff);

  (void)hipMemsetAsync(ws, 0, zbytes, stream);
  hist_kernel<<<1024, 256, 0, stream>>>(dstE, deg);
  scan1_kernel<<<SCANB, 1024, 0, stream>>>(deg, off, bsum);
  scan2_kernel<<<1, 64, 0, stream>>>(bsum, boff, off + Nn);
  scan3_kernel<<<(Nn + 255) / 256, 256, 0, stream>>>(off, boff);
  scatter_kernel<<<1024, 256, 0, stream>>>(srcE, dstE, off, cur, ssrc);

  convw_kernel<<<1024, 256, 0, stream>>>(wq1, wk1, wv1, ws1, b1, Ff);
  convw_kernel<<<1024, 256, 0, stream>>>(wq2, wk2, wv2, ws2, b2, Dd);
  round_kernel<<<4096, 256, 0, stream>>>(x, a2, Nn, Ff);

  gemm_mfma<<<3136, 256, 0, stream>>>(a2, Nn, Ff, b1, bq1, bk1, bv1, bs1, qb, kvb, sb);
  attn_kernel<<<(Nn + 3) / 4, 256, 0, stream>>>(qb, kvb, sb, off, ssrc, hb);
  gemm_mfma<<<3136, 256, 0, stream>>>(hb, Nn, Dd, b2, bq2, bk2, bv2, bs2, qb, kvb, sb);
  attn_kernel<<<(Nn + 3) / 4, 256, 0, stream>>>(qb, kvb, sb, off, ssrc, hb);

  pool_kernel<<<(Nn + 127) / 128, 256, 0, stream>>>(hb, batch, pooled);
  fc_kernel<<<1, 512, 0, stream>>>(pooled, wf1, bf1, wf2, bf2, outp);
}

// Round 12
// 514.803 us; speedup vs baseline: 1.8403x; 1.0940x over previous
//
#include <hip/hip_runtime.h>
#include <cstdio>

#define Nn 50000
#define Ee 800000
#define Ff 512
#define Dd 256
#define Gg 8
#define SCANB 49   // ceil(Nn/1024)

typedef short short8 __attribute__((ext_vector_type(8)));
typedef __bf16 bf16x8 __attribute__((ext_vector_type(8)));
typedef float f32x4 __attribute__((ext_vector_type(4)));
typedef _Float16 half2v __attribute__((ext_vector_type(2)));

#if defined(__has_builtin)
#if __has_builtin(__builtin_amdgcn_fdot2)
#define HAS_FDOT2 1
#endif
#if __has_builtin(__builtin_amdgcn_cvt_f32_fp8)
#define HAS_CVTFP8 1
#endif
#endif

__device__ inline unsigned short f2bf(float f) {
  unsigned u = __float_as_uint(f);
  u += 0x7FFFu + ((u >> 16) & 1u);
  return (unsigned short)(u >> 16);
}
__device__ inline float bf2f(unsigned short h) {
  return __uint_as_float(((unsigned)h) << 16);
}

// OCP e4m3 encode (RNE, clamp to +-448, denormals handled)
__device__ inline unsigned char f2fp8(float f) {
  const float af = fabsf(f);
  const unsigned s = (f < 0.f) ? 0x80u : 0u;
  if (af >= 448.f) return (unsigned char)(s | 0x7E);
  if (af < 0.015625f) {
    int q = (int)(af * 512.f + 0.5f);
    return (unsigned char)(s | q);
  }
  unsigned u = __float_as_uint(af);
  unsigned m = u & 0x7fffffu;
  unsigned e = u >> 23;
  unsigned r = m + 0x7ffffu + ((m >> 20) & 1u);
  if (r >> 23) { e += 1; r = 0; }
  unsigned em = ((e - 120u) << 3) | ((r >> 20) & 7u);
  if (em > 0x7Eu) em = 0x7Eu;
  return (unsigned char)(s | em);
}

// OCP e4m3 decode, byte SEL of a dword (compile-time constant)
template <int SEL>
__device__ inline float fp8tof(unsigned v) {
#ifdef HAS_CVTFP8
  return __builtin_amdgcn_cvt_f32_fp8(v, SEL);
#else
  unsigned b = (v >> (SEL * 8)) & 0xffu;
  unsigned em = b & 0x7fu;
  float n = __uint_as_float((em << 20) + 0x3C000000u);
  float dn = (float)em * 0.001953125f;
  float r = (em < 8u) ? dn : n;
  return (b & 0x80u) ? -r : r;
#endif
}

__device__ inline void gload16(const void* g, void* l) {
  __builtin_amdgcn_global_load_lds((const __attribute__((address_space(1))) void*)g,
                                   (__attribute__((address_space(3))) void*)l, 16, 0, 0);
}

// ---------------- CSR build (rank-based: one atomic pass) ----------------

__global__ void hist_kernel(const int* __restrict__ dst, int* __restrict__ deg,
                            int* __restrict__ rank) {
  int i = blockIdx.x * blockDim.x + threadIdx.x;
  int stride = gridDim.x * blockDim.x;
  for (; i < Ee; i += stride) rank[i] = atomicAdd(&deg[dst[i]], 1);
}

__global__ __launch_bounds__(1024) void scan1_kernel(const int* __restrict__ deg,
                                                     int* __restrict__ off,
                                                     int* __restrict__ bsum) {
  __shared__ int wsum[16];
  int tid = threadIdx.x, lane = tid & 63, w = tid >> 6;
  int i = blockIdx.x * 1024 + tid;
  int v = (i < Nn) ? deg[i] : 0;
  int x = v;
#pragma unroll
  for (int o = 1; o < 64; o <<= 1) {
    int t = __shfl_up(x, o);
    if (lane >= o) x += t;
  }
  if (lane == 63) wsum[w] = x;
  __syncthreads();
  if (w == 0 && lane < 16) {
    int y = wsum[lane];
#pragma unroll
    for (int o = 1; o < 16; o <<= 1) {
      int t = __shfl_up(y, o);
      if (lane >= o) y += t;
    }
    wsum[lane] = y;
  }
  __syncthreads();
  int incl = x + (w ? wsum[w - 1] : 0);
  if (i < Nn) off[i] = incl - v;
  if (tid == 1023) bsum[blockIdx.x] = incl;
}

__global__ void scan2_kernel(const int* __restrict__ bsum, int* __restrict__ boff,
                             int* __restrict__ offN) {
  int lane = threadIdx.x;
  int v = (lane < SCANB) ? bsum[lane] : 0;
  int x = v;
#pragma unroll
  for (int o = 1; o < 64; o <<= 1) {
    int t = __shfl_up(x, o);
    if (lane >= o) x += t;
  }
  if (lane < SCANB) boff[lane] = x - v;
  if (lane == 63) *offN = x;
}

__global__ void scan3_kernel(int* __restrict__ off, const int* __restrict__ boff) {
  int i = blockIdx.x * 256 + threadIdx.x;
  if (i < Nn) off[i] += boff[i >> 10];
}

__global__ void scatter_kernel(const int* __restrict__ src, const int* __restrict__ dst,
                               const int* __restrict__ off, const int* __restrict__ rank,
                               int* __restrict__ ssrc) {
  int i = blockIdx.x * blockDim.x + threadIdx.x;
  int stride = gridDim.x * blockDim.x;
  for (; i < Ee; i += stride) {
    ssrc[off[dst[i]] + rank[i]] = src[i];
  }
}

// ---------------- conversions ----------------

__global__ void round_kernel(const float* __restrict__ in, unsigned short* __restrict__ out,
                             int M, int K) {
  const int kg4 = K >> 2;
  int i = blockIdx.x * blockDim.x + threadIdx.x;
  const int total = M * kg4;
  const int stride = gridDim.x * blockDim.x;
  for (; i < total; i += stride) {
    const int row = i / kg4, kg = i - row * kg4;
    const float4 v = *(const float4*)(in + (size_t)row * K + kg * 4);
    ushort4 h;
    h.x = f2bf(v.x); h.y = f2bf(v.y); h.z = f2bf(v.z); h.w = f2bf(v.w);
    *(ushort4*)(out + (size_t)row * K + kg * 4) = h;
  }
}

// 4x W [K][256] fp32 -> B [1024][K] bf16 hi-only, transposed; row n = z*256+c
__global__ void convw_kernel(const float* __restrict__ W0, const float* __restrict__ W1,
                             const float* __restrict__ W2, const float* __restrict__ W3,
                             unsigned short* __restrict__ B, int K) {
  int i = blockIdx.x * blockDim.x + threadIdx.x;
  const int total = 1024 * K;
  const int stride = gridDim.x * blockDim.x;
  for (; i < total; i += stride) {
    const int n = i & 1023;
    const int k = i >> 10;
    const int z = n >> 8, c = n & 255;
    const float* W = z == 0 ? W0 : z == 1 ? W1 : z == 2 ? W2 : W3;
    B[(size_t)n * K + k] = f2bf(W[(size_t)k * Dd + c]);
  }
}

// ---------------- 1-term bf16 MFMA GEMM (128x128 tile) with LDS-restaged epilogue ----
// C = A_bf16 @ B_hi + bias.  A [M][K] bf16, B [1024][K] bf16.
// Block's 128 output cols lie in ONE z: z=(i2&7)>>1 (0:q fp16, 1:K fp16 in kv[.,c*2],
// 2:V fp8 in kv[.,512+c], 3:s fp16). Epilogue: fragments -> LDS -> coalesced 16B stores.

#define SROWB 264  // LDS restage row stride (bytes); 66 dwords -> bank shift 2

__global__ __launch_bounds__(256)
void gemm_mfma(const unsigned short* __restrict__ A2, int M, int K,
               const unsigned short* __restrict__ B,
               const float* __restrict__ b0, const float* __restrict__ b1,
               const float* __restrict__ b2, const float* __restrict__ b3,
               _Float16* __restrict__ qout, unsigned char* __restrict__ kvout,
               _Float16* __restrict__ sout) {
  __shared__ __align__(16) char smem[128 * SROWB];   // 33792 B; K-loop uses first 32KB
  unsigned short* As = (unsigned short*)smem;
  unsigned short* Bs = (unsigned short*)(smem + 16384);
  const int tid = threadIdx.x;
  const int lane = tid & 63, w = tid >> 6;
  const int wr = w >> 1, wc = w & 1;
  const int p = blockIdx.x;
  const int xcd = p & 7;
  const int i2 = p >> 3;
  const int bm = (xcd * 49 + (i2 >> 3)) * 128;
  const int zblk = (i2 & 7) >> 1;
  const int colbase = (i2 & 1) * 128;          // block's 128 cols within its z
  const int lda = K, ldb = K;
  const int nsteps = K >> 6;
  const int srow = lane >> 3, sslot = lane & 7;
  const int fr = lane & 15, fq = lane >> 4;

  f32x4 acc[4][4] = {};

  for (int s = 0; s < nsteps; ++s) {
    const int kk = s << 6;
    __syncthreads();
#pragma unroll
    for (int h = 0; h < 4; ++h) {
      const int q = h * 4 + w;
      const int r = q * 8 + srow;
      const int g = sslot ^ (r & 7);
      int ga = bm + r; if (ga > M - 1) ga = M - 1;
      gload16(A2 + (size_t)ga * lda + kk + g * 8, (char*)As + q * 1024);
      const int gb = (zblk * 256 + colbase) + r;   // B row = z*256 + c
      gload16(B + (size_t)gb * ldb + kk + g * 8, (char*)Bs + q * 1024);
    }
    __syncthreads();
    short8 av[2][4], bv[2][4];
#pragma unroll
    for (int kh = 0; kh < 2; ++kh)
#pragma unroll
      for (int i = 0; i < 4; ++i) {
        const int ra = wr * 64 + i * 16 + fr;
        av[kh][i] = *(const short8*)((const char*)As + ra * 128 + (((kh * 4 + fq) ^ (ra & 7)) << 4));
        const int rb = wc * 64 + i * 16 + fr;
        bv[kh][i] = *(const short8*)((const char*)Bs + rb * 128 + (((kh * 4 + fq) ^ (rb & 7)) << 4));
      }
#pragma unroll
    for (int kh = 0; kh < 2; ++kh)
#pragma unroll
      for (int mi = 0; mi < 4; ++mi)
#pragma unroll
        for (int ni = 0; ni < 4; ++ni)
          acc[mi][ni] = __builtin_amdgcn_mfma_f32_16x16x32_bf16(
              __builtin_bit_cast(bf16x8, av[kh][mi]),
              __builtin_bit_cast(bf16x8, bv[kh][ni]), acc[mi][ni], 0, 0, 0);
  }

  // ---- epilogue: fragments -> LDS (row stride SROWB bytes) ----
  const float* bp = zblk == 0 ? b0 : zblk == 1 ? b1 : zblk == 2 ? b2 : b3;
  __syncthreads();   // K-loop LDS reads done before overwrite
  if (zblk == 2) {
    unsigned char* S8 = (unsigned char*)smem;
#pragma unroll
    for (int mi = 0; mi < 4; ++mi)
#pragma unroll
      for (int ni = 0; ni < 4; ++ni) {
        const int col = wc * 64 + ni * 16 + fr;
        const float bias = bp[colbase + col];
#pragma unroll
        for (int j = 0; j < 4; ++j) {
          const int row = wr * 64 + mi * 16 + fq * 4 + j;
          S8[row * SROWB + col] = f2fp8(acc[mi][ni][j] + bias);
        }
      }
  } else {
#pragma unroll
    for (int mi = 0; mi < 4; ++mi)
#pragma unroll
      for (int ni = 0; ni < 4; ++ni) {
        const int col = wc * 64 + ni * 16 + fr;
        const float bias = bp[colbase + col];
#pragma unroll
        for (int j = 0; j < 4; ++j) {
          const int row = wr * 64 + mi * 16 + fq * 4 + j;
          *(_Float16*)(smem + row * SROWB + col * 2) = (_Float16)(acc[mi][ni][j] + bias);
        }
      }
  }
  __syncthreads();

  // ---- flush: one 128B (fp16) / 64B (fp8) half-row per thread, coalesced ----
  const int row = tid >> 1, half = tid & 1;
  const int grow = bm + row;
  if (grow < M) {
    if (zblk == 2) {
      const uint4* srcp = (const uint4*)(smem + row * SROWB + half * 64);
      uint4* dstp = (uint4*)(kvout + (size_t)grow * 768 + 512 + colbase + half * 64);
#pragma unroll
      for (int k = 0; k < 4; ++k) dstp[k] = srcp[k];
    } else {
      char* dbase = zblk == 0 ? (char*)qout + (size_t)grow * 512 + colbase * 2
                  : zblk == 1 ? (char*)kvout + (size_t)grow * 768 + colbase * 2
                              : (char*)sout + (size_t)grow * 512 + colbase * 2;
      const uint4* srcp = (const uint4*)(smem + row * SROWB + half * 128);
      uint4* dstp = (uint4*)(dbase + half * 128);
#pragma unroll
      for (int k = 0; k < 8; ++k) dstp[k] = srcp[k];
    }
  }
}

// ---------------- per-node attention (one wave per dst node, online softmax) ----------------
// q: fp16 [Nn][256]; kv row 768B: K fp16 at [c*2], V fp8 at [512+c]; s fp16 [Nn][256].

__device__ inline float hdot4(half2v a01, half2v a23, half2v b01, half2v b23) {
#ifdef HAS_FDOT2
  return __builtin_amdgcn_fdot2(a01, b01, __builtin_amdgcn_fdot2(a23, b23, 0.f, false), false);
#else
  float r = (float)a01[0] * (float)b01[0];
  r = fmaf((float)a01[1], (float)b01[1], r);
  r = fmaf((float)a23[0], (float)b23[0], r);
  r = fmaf((float)a23[1], (float)b23[1], r);
  return r;
#endif
}

__global__ __launch_bounds__(256)
void attn_kernel(const _Float16* __restrict__ qbuf, const unsigned char* __restrict__ kvb,
                 const _Float16* __restrict__ sbuf, const int* __restrict__ off,
                 const int* __restrict__ ssrc, unsigned short* __restrict__ hbout) {
  int gw = (int)((blockIdx.x * 256 + threadIdx.x) >> 6);
  if (gw >= Nn) return;
  int lane = threadIdx.x & 63;

  const uint2 qv = *(const uint2*)(qbuf + (size_t)gw * Dd + lane * 4);
  const half2v q01 = __builtin_bit_cast(half2v, qv.x);
  const half2v q23 = __builtin_bit_cast(half2v, qv.y);
  int e0 = off[gw], e1 = off[gw + 1];
  const float scale = 0.08838834764831845f;

  float m = -3.4e38f, d = 0.f;
  float ax = 0.f, ay = 0.f, az = 0.f, aw = 0.f;

  for (int e = e0; e < e1; e += 8) {
    int sx[8];
#pragma unroll
    for (int t = 0; t < 8; ++t) {
      const int ee = e + t;
      sx[t] = ssrc[ee < e1 ? ee : e1 - 1];
    }
    uint2 ku[8];
    unsigned vu[8];
#pragma unroll
    for (int t = 0; t < 8; ++t) {
      const unsigned char* row = kvb + (size_t)sx[t] * 768;
      ku[t] = *(const uint2*)(row + lane * 8);
      vu[t] = *(const unsigned*)(row + 512 + lane * 4);
    }
    float p[8];
#pragma unroll
    for (int t = 0; t < 8; ++t)
      p[t] = hdot4(q01, q23, __builtin_bit_cast(half2v, ku[t].x),
                   __builtin_bit_cast(half2v, ku[t].y));
#pragma unroll
    for (int o = 16; o >= 1; o >>= 1)
#pragma unroll
      for (int t = 0; t < 8; ++t) p[t] += __shfl_xor(p[t], o);
    float sc[8];
#pragma unroll
    for (int t = 0; t < 8; ++t)
      sc[t] = (e + t < e1) ? p[t] * scale : -3.0e38f;
    float mx = m;
#pragma unroll
    for (int t = 0; t < 8; ++t) mx = fmaxf(mx, sc[t]);
    const float f = __expf(m - mx);
    float wsum = 0.f, vx = 0.f, vy = 0.f, vz = 0.f, vw = 0.f;
#pragma unroll
    for (int t = 0; t < 8; ++t) {
      const float wt = __expf(sc[t] - mx);
      wsum += wt;
      vx = fmaf(wt, fp8tof<0>(vu[t]), vx);
      vy = fmaf(wt, fp8tof<1>(vu[t]), vy);
      vz = fmaf(wt, fp8tof<2>(vu[t]), vz);
      vw = fmaf(wt, fp8tof<3>(vu[t]), vw);
    }
    d = d * f + wsum;
    ax = ax * f + vx;
    ay = ay * f + vy;
    az = az * f + vz;
    aw = aw * f + vw;
    m = mx;
  }

  float inv = 1.f / (d + 1e-16f);
  const uint2 sv = *(const uint2*)(sbuf + (size_t)gw * Dd + lane * 4);
  const half2v s01 = __builtin_bit_cast(half2v, sv.x);
  const half2v s23 = __builtin_bit_cast(half2v, sv.y);
  ushort4 hh;
  hh.x = f2bf(fmaxf(fmaf(ax, inv, (float)s01[0]), 0.f));
  hh.y = f2bf(fmaxf(fmaf(ay, inv, (float)s01[1]), 0.f));
  hh.z = f2bf(fmaxf(fmaf(az, inv, (float)s23[0]), 0.f));
  hh.w = f2bf(fmaxf(fmaf(aw, inv, (float)s23[1]), 0.f));
  *(ushort4*)(hbout + (size_t)gw * Dd + lane * 4) = hh;
}

// ---------------- pooling (bf16 input) + fc ----------------

__global__ __launch_bounds__(256)
void pool_kernel(const unsigned short* __restrict__ h, const int* __restrict__ batch,
                 float* __restrict__ pooled) {
  int c = threadIdx.x;
  int n0 = blockIdx.x * 128;
  int n1 = min(n0 + 128, Nn);
  int curg = batch[n0];
  float mx = 0.f;
  for (int n = n0; n < n1; ++n) {
    int g = batch[n];
    if (g != curg) {
      atomicMax((int*)(pooled + curg * Dd + c), __float_as_int(mx));
      mx = 0.f;
      curg = g;
    }
    mx = fmaxf(mx, bf2f(h[(size_t)n * Dd + c]));
  }
  atomicMax((int*)(pooled + curg * Dd + c), __float_as_int(mx));
}

__global__ __launch_bounds__(512)
void fc_kernel(const float* __restrict__ pooled,
               const float* __restrict__ wf1, const float* __restrict__ bf1,
               const float* __restrict__ wf2, const float* __restrict__ bf2,
               float* __restrict__ outp) {
  __shared__ float t[Gg][64];
  int tid = threadIdx.x;
  int g = tid >> 6, j = tid & 63;
  float acc = bf1[j];
  for (int c = 0; c < Dd; ++c) acc = fmaf(pooled[g * Dd + c], wf1[c * 64 + j], acc);
  t[g][j] = acc;
  __syncthreads();
  if (tid < Gg * 4) {
    int gg = tid >> 2, cc = tid & 3;
    float a2 = bf2[cc];
    for (int j2 = 0; j2 < 64; ++j2) a2 = fmaf(t[gg][j2], wf2[j2 * 4 + cc], a2);
    outp[gg * 4 + cc] = a2;
  }
}

// ---------------- host ----------------

extern "C" void kernel_launch(void* const* d_in, const int* in_sizes, int n_in,
                              void* d_out, int out_size, void* d_ws, size_t ws_size,
                              hipStream_t stream) {
  const float* x   = (const float*)d_in[0];
  const int* ei    = (const int*)d_in[1];
  const int* srcE  = ei;
  const int* dstE  = ei + Ee;
  const int* batch = (const int*)d_in[2];
  const float* wq1 = (const float*)d_in[3];  const float* bq1 = (const float*)d_in[4];
  const float* wk1 = (const float*)d_in[5];  const float* bk1 = (const float*)d_in[6];
  const float* wv1 = (const float*)d_in[7];  const float* bv1 = (const float*)d_in[8];
  const float* ws1 = (const float*)d_in[9];  const float* bs1 = (const float*)d_in[10];
  const float* wq2 = (const float*)d_in[11]; const float* bq2 = (const float*)d_in[12];
  const float* wk2 = (const float*)d_in[13]; const float* bk2 = (const float*)d_in[14];
  const float* wv2 = (const float*)d_in[15]; const float* bv2 = (const float*)d_in[16];
  const float* ws2 = (const float*)d_in[17]; const float* bs2 = (const float*)d_in[18];
  const float* wf1 = (const float*)d_in[19]; const float* bf1 = (const float*)d_in[20];
  const float* wf2 = (const float*)d_in[21]; const float* bf2 = (const float*)d_in[22];
  float* outp = (float*)d_out;
  char* ws = (char*)d_ws;

  auto al256 = [](size_t v) { return (v + 255) & ~(size_t)255; };
  size_t o_deg  = 0;
  size_t o_pool = o_deg + (size_t)Nn * 4;
  size_t zbytes = o_pool + (size_t)Gg * Dd * 4;
  size_t o_off  = al256(zbytes);
  size_t o_ssrc = al256(o_off + (size_t)(Nn + 1) * 4);
  size_t o_rank = al256(o_ssrc + (size_t)Ee * 4);
  size_t o_q    = al256(o_rank + (size_t)Ee * 4);                 // fp16 [Nn][256]
  size_t o_kv   = al256(o_q + (size_t)Nn * Dd * 2);               // 768B rows [Nn]
  size_t o_s    = al256(o_kv + (size_t)Nn * 768);                 // fp16 [Nn][256]
  size_t o_b1   = al256(o_s + (size_t)Nn * Dd * 2);               // bf16 [1024][512]
  size_t o_b2   = al256(o_b1 + (size_t)1024 * Ff * 2);            // bf16 [1024][256]
  size_t o_a    = al256(o_b2 + (size_t)1024 * Dd * 2);            // bf16 [Nn][512] x / h overlay
  size_t o_bsum = al256(o_a + (size_t)Nn * Ff * 2);
  size_t o_boff = al256(o_bsum + (size_t)SCANB * 4);
  size_t total  = o_boff + (size_t)SCANB * 4;
  if (ws_size < total) {
    fprintf(stderr, "kernel_launch: ws too small: %zu < %zu\n", ws_size, total);
    return;
  }

  int*   deg    = (int*)(ws + o_deg);
  float* pooled = (float*)(ws + o_pool);
  int*   off    = (int*)(ws + o_off);
  int*   ssrc   = (int*)(ws + o_ssrc);
  int*   rank   = (int*)(ws + o_rank);
  _Float16* qb  = (_Float16*)(ws + o_q);
  unsigned char* kvb = (unsigned char*)(ws + o_kv);
  _Float16* sb  = (_Float16*)(ws + o_s);
  unsigned short* b1 = (unsigned short*)(ws + o_b1);
  unsigned short* b2 = (unsigned short*)(ws + o_b2);
  unsigned short* a2  = (unsigned short*)(ws + o_a);    // [Nn][512] bf16 (x)
  unsigned short* hb  = (unsigned short*)(ws + o_a);    // [Nn][256] bf16 h (overlays a2)
  int* bsum     = (int*)(ws + o_bsum);
  int* boff     = (int*)(ws + o_boff);

  (void)hipMemsetAsync(ws, 0, zbytes, stream);
  hist_kernel<<<1024, 256, 0, stream>>>(dstE, deg, rank);
  scan1_kernel<<<SCANB, 1024, 0, stream>>>(deg, off, bsum);
  scan2_kernel<<<1, 64, 0, stream>>>(bsum, boff, off + Nn);
  scan3_kernel<<<(Nn + 255) / 256, 256, 0, stream>>>(off, boff);
  scatter_kernel<<<1024, 256, 0, stream>>>(srcE, dstE, off, rank, ssrc);

  convw_kernel<<<1024, 256, 0, stream>>>(wq1, wk1, wv1, ws1, b1, Ff);
  convw_kernel<<<1024, 256, 0, stream>>>(wq2, wk2, wv2, ws2, b2, Dd);
  round_kernel<<<4096, 256, 0, stream>>>(x, a2, Nn, Ff);

  gemm_mfma<<<3136, 256, 0, stream>>>(a2, Nn, Ff, b1, bq1, bk1, bv1, bs1, qb, kvb, sb);
  attn_kernel<<<(Nn + 3) / 4, 256, 0, stream>>>(qb, kvb, sb, off, ssrc, hb);
  gemm_mfma<<<3136, 256, 0, stream>>>(hb, Nn, Dd, b2, bq2, bk2, bv2, bs2, qb, kvb, sb);
  attn_kernel<<<(Nn + 3) / 4, 256, 0, stream>>>(qb, kvb, sb, off, ssrc, hb);

  pool_kernel<<<(Nn + 127) / 128, 256, 0, stream>>>(hb, batch, pooled);
  fc_kernel<<<1, 512, 0, stream>>>(pooled, wf1, bf1, wf2, bf2, outp);
}

// Round 13
// 512.408 us; speedup vs baseline: 1.8489x; 1.0047x over previous
//
#include <hip/hip_runtime.h>
#include <cstdio>

#define Nn 50000
#define Ee 800000
#define Ff 512
#define Dd 256
#define Gg 8
#define SCANB 49   // ceil(Nn/1024)

typedef short short8 __attribute__((ext_vector_type(8)));
typedef __bf16 bf16x8 __attribute__((ext_vector_type(8)));
typedef float f32x4 __attribute__((ext_vector_type(4)));
typedef _Float16 half2v __attribute__((ext_vector_type(2)));

#if defined(__has_builtin)
#if __has_builtin(__builtin_amdgcn_fdot2)
#define HAS_FDOT2 1
#endif
#if __has_builtin(__builtin_amdgcn_cvt_f32_fp8)
#define HAS_CVTFP8 1
#endif
#endif

__device__ inline unsigned short f2bf(float f) {
  unsigned u = __float_as_uint(f);
  u += 0x7FFFu + ((u >> 16) & 1u);
  return (unsigned short)(u >> 16);
}
__device__ inline float bf2f(unsigned short h) {
  return __uint_as_float(((unsigned)h) << 16);
}

// OCP e4m3 encode (RNE, clamp to +-448, denormals handled)
__device__ inline unsigned char f2fp8(float f) {
  const float af = fabsf(f);
  const unsigned s = (f < 0.f) ? 0x80u : 0u;
  if (af >= 448.f) return (unsigned char)(s | 0x7E);
  if (af < 0.015625f) {
    int q = (int)(af * 512.f + 0.5f);
    return (unsigned char)(s | q);
  }
  unsigned u = __float_as_uint(af);
  unsigned m = u & 0x7fffffu;
  unsigned e = u >> 23;
  unsigned r = m + 0x7ffffu + ((m >> 20) & 1u);
  if (r >> 23) { e += 1; r = 0; }
  unsigned em = ((e - 120u) << 3) | ((r >> 20) & 7u);
  if (em > 0x7Eu) em = 0x7Eu;
  return (unsigned char)(s | em);
}

// OCP e4m3 decode, byte SEL of a dword (compile-time constant)
template <int SEL>
__device__ inline float fp8tof(unsigned v) {
#ifdef HAS_CVTFP8
  return __builtin_amdgcn_cvt_f32_fp8(v, SEL);
#else
  unsigned b = (v >> (SEL * 8)) & 0xffu;
  unsigned em = b & 0x7fu;
  float n = __uint_as_float((em << 20) + 0x3C000000u);
  float dn = (float)em * 0.001953125f;
  float r = (em < 8u) ? dn : n;
  return (b & 0x80u) ? -r : r;
#endif
}

__device__ inline void gload16(const void* g, void* l) {
  __builtin_amdgcn_global_load_lds((const __attribute__((address_space(1))) void*)g,
                                   (__attribute__((address_space(3))) void*)l, 16, 0, 0);
}

// ---------------- CSR build (rank-based: one atomic pass) ----------------

__global__ void hist_kernel(const int* __restrict__ dst, int* __restrict__ deg,
                            int* __restrict__ rank) {
  int i = blockIdx.x * blockDim.x + threadIdx.x;
  int stride = gridDim.x * blockDim.x;
  for (; i < Ee; i += stride) rank[i] = atomicAdd(&deg[dst[i]], 1);
}

__global__ __launch_bounds__(1024) void scan1_kernel(const int* __restrict__ deg,
                                                     int* __restrict__ off,
                                                     int* __restrict__ bsum) {
  __shared__ int wsum[16];
  int tid = threadIdx.x, lane = tid & 63, w = tid >> 6;
  int i = blockIdx.x * 1024 + tid;
  int v = (i < Nn) ? deg[i] : 0;
  int x = v;
#pragma unroll
  for (int o = 1; o < 64; o <<= 1) {
    int t = __shfl_up(x, o);
    if (lane >= o) x += t;
  }
  if (lane == 63) wsum[w] = x;
  __syncthreads();
  if (w == 0 && lane < 16) {
    int y = wsum[lane];
#pragma unroll
    for (int o = 1; o < 16; o <<= 1) {
      int t = __shfl_up(y, o);
      if (lane >= o) y += t;
    }
    wsum[lane] = y;
  }
  __syncthreads();
  int incl = x + (w ? wsum[w - 1] : 0);
  if (i < Nn) off[i] = incl - v;
  if (tid == 1023) bsum[blockIdx.x] = incl;
}

__global__ void scan2_kernel(const int* __restrict__ bsum, int* __restrict__ boff,
                             int* __restrict__ offN) {
  int lane = threadIdx.x;
  int v = (lane < SCANB) ? bsum[lane] : 0;
  int x = v;
#pragma unroll
  for (int o = 1; o < 64; o <<= 1) {
    int t = __shfl_up(x, o);
    if (lane >= o) x += t;
  }
  if (lane < SCANB) boff[lane] = x - v;
  if (lane == 63) *offN = x;
}

__global__ void scan3_kernel(int* __restrict__ off, const int* __restrict__ boff) {
  int i = blockIdx.x * 256 + threadIdx.x;
  if (i < Nn) off[i] += boff[i >> 10];
}

__global__ void scatter_kernel(const int* __restrict__ src, const int* __restrict__ dst,
                               const int* __restrict__ off, const int* __restrict__ rank,
                               int* __restrict__ ssrc) {
  int i = blockIdx.x * blockDim.x + threadIdx.x;
  int stride = gridDim.x * blockDim.x;
  for (; i < Ee; i += stride) {
    ssrc[off[dst[i]] + rank[i]] = src[i];
  }
}

// ---------------- conversions ----------------

__global__ void round_kernel(const float* __restrict__ in, unsigned short* __restrict__ out,
                             int M, int K) {
  const int kg4 = K >> 2;
  int i = blockIdx.x * blockDim.x + threadIdx.x;
  const int total = M * kg4;
  const int stride = gridDim.x * blockDim.x;
  for (; i < total; i += stride) {
    const int row = i / kg4, kg = i - row * kg4;
    const float4 v = *(const float4*)(in + (size_t)row * K + kg * 4);
    ushort4 h;
    h.x = f2bf(v.x); h.y = f2bf(v.y); h.z = f2bf(v.z); h.w = f2bf(v.w);
    *(ushort4*)(out + (size_t)row * K + kg * 4) = h;
  }
}

// 4x W [K][256] fp32 -> B [1024][K] bf16 hi-only, transposed; row n = z*256+c
__global__ void convw_kernel(const float* __restrict__ W0, const float* __restrict__ W1,
                             const float* __restrict__ W2, const float* __restrict__ W3,
                             unsigned short* __restrict__ B, int K) {
  int i = blockIdx.x * blockDim.x + threadIdx.x;
  const int total = 1024 * K;
  const int stride = gridDim.x * blockDim.x;
  for (; i < total; i += stride) {
    const int n = i & 1023;
    const int k = i >> 10;
    const int z = n >> 8, c = n & 255;
    const float* W = z == 0 ? W0 : z == 1 ? W1 : z == 2 ? W2 : W3;
    B[(size_t)n * K + k] = f2bf(W[(size_t)k * Dd + c]);
  }
}

// ---------------- 1-term bf16 MFMA GEMM (128x128 tile) with XOR-swizzled LDS epilogue ----
// C = A_bf16 @ B_hi + bias.  A [M][K] bf16, B [1024][K] bf16.
// Block's 128 output cols lie in ONE z: z=(i2&7)>>1 (0:q fp16, 1:K fp16 in kv[.,c*2],
// 2:V fp8 in kv[.,512+c], 3:s fp16). Epilogue restages into the SAME 32KB LDS
// (row stride 256B, byte XOR ^((row&7)<<4)) -> coalesced 16B flush. LDS stays 32768.

__global__ __launch_bounds__(256)
void gemm_mfma(const unsigned short* __restrict__ A2, int M, int K,
               const unsigned short* __restrict__ B,
               const float* __restrict__ b0, const float* __restrict__ b1,
               const float* __restrict__ b2, const float* __restrict__ b3,
               _Float16* __restrict__ qout, unsigned char* __restrict__ kvout,
               _Float16* __restrict__ sout) {
  __shared__ __align__(16) char smem[32768];
  unsigned short* As = (unsigned short*)smem;
  unsigned short* Bs = (unsigned short*)(smem + 16384);
  const int tid = threadIdx.x;
  const int lane = tid & 63, w = tid >> 6;
  const int wr = w >> 1, wc = w & 1;
  const int p = blockIdx.x;
  const int xcd = p & 7;
  const int i2 = p >> 3;
  const int bm = (xcd * 49 + (i2 >> 3)) * 128;
  const int zblk = (i2 & 7) >> 1;
  const int colbase = (i2 & 1) * 128;          // block's 128 cols within its z
  const int lda = K, ldb = K;
  const int nsteps = K >> 6;
  const int srow = lane >> 3, sslot = lane & 7;
  const int fr = lane & 15, fq = lane >> 4;

  f32x4 acc[4][4] = {};

  for (int s = 0; s < nsteps; ++s) {
    const int kk = s << 6;
    __syncthreads();
#pragma unroll
    for (int h = 0; h < 4; ++h) {
      const int q = h * 4 + w;
      const int r = q * 8 + srow;
      const int g = sslot ^ (r & 7);
      int ga = bm + r; if (ga > M - 1) ga = M - 1;
      gload16(A2 + (size_t)ga * lda + kk + g * 8, (char*)As + q * 1024);
      const int gb = (zblk * 256 + colbase) + r;   // B row = z*256 + c
      gload16(B + (size_t)gb * ldb + kk + g * 8, (char*)Bs + q * 1024);
    }
    __syncthreads();
    short8 av[2][4], bv[2][4];
#pragma unroll
    for (int kh = 0; kh < 2; ++kh)
#pragma unroll
      for (int i = 0; i < 4; ++i) {
        const int ra = wr * 64 + i * 16 + fr;
        av[kh][i] = *(const short8*)((const char*)As + ra * 128 + (((kh * 4 + fq) ^ (ra & 7)) << 4));
        const int rb = wc * 64 + i * 16 + fr;
        bv[kh][i] = *(const short8*)((const char*)Bs + rb * 128 + (((kh * 4 + fq) ^ (rb & 7)) << 4));
      }
#pragma unroll
    for (int kh = 0; kh < 2; ++kh)
#pragma unroll
      for (int mi = 0; mi < 4; ++mi)
#pragma unroll
        for (int ni = 0; ni < 4; ++ni)
          acc[mi][ni] = __builtin_amdgcn_mfma_f32_16x16x32_bf16(
              __builtin_bit_cast(bf16x8, av[kh][mi]),
              __builtin_bit_cast(bf16x8, bv[kh][ni]), acc[mi][ni], 0, 0, 0);
  }

  // ---- epilogue: fragments -> LDS (row stride 256B, byte XOR ^((row&7)<<4)) ----
  const float* bp = zblk == 0 ? b0 : zblk == 1 ? b1 : zblk == 2 ? b2 : b3;
  __syncthreads();   // K-loop LDS reads done before overwrite
  if (zblk == 2) {
    unsigned char* S8 = (unsigned char*)smem;
#pragma unroll
    for (int mi = 0; mi < 4; ++mi)
#pragma unroll
      for (int ni = 0; ni < 4; ++ni) {
        const int col = wc * 64 + ni * 16 + fr;
        const float bias = bp[colbase + col];
#pragma unroll
        for (int j = 0; j < 4; ++j) {
          const int row = wr * 64 + mi * 16 + fq * 4 + j;
          S8[row * 256 + (col ^ ((row & 7) << 4))] = f2fp8(acc[mi][ni][j] + bias);
        }
      }
  } else {
#pragma unroll
    for (int mi = 0; mi < 4; ++mi)
#pragma unroll
      for (int ni = 0; ni < 4; ++ni) {
        const int col = wc * 64 + ni * 16 + fr;
        const float bias = bp[colbase + col];
#pragma unroll
        for (int j = 0; j < 4; ++j) {
          const int row = wr * 64 + mi * 16 + fq * 4 + j;
          *(_Float16*)(smem + row * 256 + ((col * 2) ^ ((row & 7) << 4))) =
              (_Float16)(acc[mi][ni][j] + bias);
        }
      }
  }
  __syncthreads();

  // ---- flush: one 128B (fp16) / 64B (fp8) half-row per thread, coalesced 16B stores ----
  const int row = tid >> 1, half = tid & 1;
  const int grow = bm + row;
  if (grow < M) {
    const int sh = (row & 7) << 4;
    if (zblk == 2) {
      uint4* dstp = (uint4*)(kvout + (size_t)grow * 768 + 512 + colbase + half * 64);
#pragma unroll
      for (int k = 0; k < 4; ++k)
        dstp[k] = *(const uint4*)(smem + row * 256 + ((half * 64 + k * 16) ^ sh));
    } else {
      char* dbase = zblk == 0 ? (char*)qout + (size_t)grow * 512 + colbase * 2
                  : zblk == 1 ? (char*)kvout + (size_t)grow * 768 + colbase * 2
                              : (char*)sout + (size_t)grow * 512 + colbase * 2;
      uint4* dstp = (uint4*)(dbase + half * 128);
#pragma unroll
      for (int k = 0; k < 8; ++k)
        dstp[k] = *(const uint4*)(smem + row * 256 + ((half * 128 + k * 16) ^ sh));
    }
  }
}

// ---------------- per-node attention (one wave per dst node, online softmax) ----------------
// q: fp16 [Nn][256]; kv row 768B: K fp16 at [c*2], V fp8 at [512+c]; s fp16 [Nn][256].

__device__ inline float hdot4(half2v a01, half2v a23, half2v b01, half2v b23) {
#ifdef HAS_FDOT2
  return __builtin_amdgcn_fdot2(a01, b01, __builtin_amdgcn_fdot2(a23, b23, 0.f, false), false);
#else
  float r = (float)a01[0] * (float)b01[0];
  r = fmaf((float)a01[1], (float)b01[1], r);
  r = fmaf((float)a23[0], (float)b23[0], r);
  r = fmaf((float)a23[1], (float)b23[1], r);
  return r;
#endif
}

__global__ __launch_bounds__(256)
void attn_kernel(const _Float16* __restrict__ qbuf, const unsigned char* __restrict__ kvb,
                 const _Float16* __restrict__ sbuf, const int* __restrict__ off,
                 const int* __restrict__ ssrc, unsigned short* __restrict__ hbout) {
  int gw = (int)((blockIdx.x * 256 + threadIdx.x) >> 6);
  if (gw >= Nn) return;
  int lane = threadIdx.x & 63;

  const uint2 qv = *(const uint2*)(qbuf + (size_t)gw * Dd + lane * 4);
  const half2v q01 = __builtin_bit_cast(half2v, qv.x);
  const half2v q23 = __builtin_bit_cast(half2v, qv.y);
  int e0 = off[gw], e1 = off[gw + 1];
  const float scale = 0.08838834764831845f;

  float m = -3.4e38f, d = 0.f;
  float ax = 0.f, ay = 0.f, az = 0.f, aw = 0.f;

  for (int e = e0; e < e1; e += 8) {
    int sx[8];
#pragma unroll
    for (int t = 0; t < 8; ++t) {
      const int ee = e + t;
      sx[t] = ssrc[ee < e1 ? ee : e1 - 1];
    }
    uint2 ku[8];
    unsigned vu[8];
#pragma unroll
    for (int t = 0; t < 8; ++t) {
      const unsigned char* row = kvb + (size_t)sx[t] * 768;
      ku[t] = *(const uint2*)(row + lane * 8);
      vu[t] = *(const unsigned*)(row + 512 + lane * 4);
    }
    float p[8];
#pragma unroll
    for (int t = 0; t < 8; ++t)
      p[t] = hdot4(q01, q23, __builtin_bit_cast(half2v, ku[t].x),
                   __builtin_bit_cast(half2v, ku[t].y));
#pragma unroll
    for (int o = 16; o >= 1; o >>= 1)
#pragma unroll
      for (int t = 0; t < 8; ++t) p[t] += __shfl_xor(p[t], o);
    float sc[8];
#pragma unroll
    for (int t = 0; t < 8; ++t)
      sc[t] = (e + t < e1) ? p[t] * scale : -3.0e38f;
    float mx = m;
#pragma unroll
    for (int t = 0; t < 8; ++t) mx = fmaxf(mx, sc[t]);
    const float f = __expf(m - mx);
    float wsum = 0.f, vx = 0.f, vy = 0.f, vz = 0.f, vw = 0.f;
#pragma unroll
    for (int t = 0; t < 8; ++t) {
      const float wt = __expf(sc[t] - mx);
      wsum += wt;
      vx = fmaf(wt, fp8tof<0>(vu[t]), vx);
      vy = fmaf(wt, fp8tof<1>(vu[t]), vy);
      vz = fmaf(wt, fp8tof<2>(vu[t]), vz);
      vw = fmaf(wt, fp8tof<3>(vu[t]), vw);
    }
    d = d * f + wsum;
    ax = ax * f + vx;
    ay = ay * f + vy;
    az = az * f + vz;
    aw = aw * f + vw;
    m = mx;
  }

  float inv = 1.f / (d + 1e-16f);
  const uint2 sv = *(const uint2*)(sbuf + (size_t)gw * Dd + lane * 4);
  const half2v s01 = __builtin_bit_cast(half2v, sv.x);
  const half2v s23 = __builtin_bit_cast(half2v, sv.y);
  ushort4 hh;
  hh.x = f2bf(fmaxf(fmaf(ax, inv, (float)s01[0]), 0.f));
  hh.y = f2bf(fmaxf(fmaf(ay, inv, (float)s01[1]), 0.f));
  hh.z = f2bf(fmaxf(fmaf(az, inv, (float)s23[0]), 0.f));
  hh.w = f2bf(fmaxf(fmaf(aw, inv, (float)s23[1]), 0.f));
  *(ushort4*)(hbout + (size_t)gw * Dd + lane * 4) = hh;
}

// ---------------- pooling (bf16 input) + fc ----------------

__global__ __launch_bounds__(256)
void pool_kernel(const unsigned short* __restrict__ h, const int* __restrict__ batch,
                 float* __restrict__ pooled) {
  int c = threadIdx.x;
  int n0 = blockIdx.x * 128;
  int n1 = min(n0 + 128, Nn);
  int curg = batch[n0];
  float mx = 0.f;
  for (int n = n0; n < n1; ++n) {
    int g = batch[n];
    if (g != curg) {
      atomicMax((int*)(pooled + curg * Dd + c), __float_as_int(mx));
      mx = 0.f;
      curg = g;
    }
    mx = fmaxf(mx, bf2f(h[(size_t)n * Dd + c]));
  }
  atomicMax((int*)(pooled + curg * Dd + c), __float_as_int(mx));
}

__global__ __launch_bounds__(512)
void fc_kernel(const float* __restrict__ pooled,
               const float* __restrict__ wf1, const float* __restrict__ bf1,
               const float* __restrict__ wf2, const float* __restrict__ bf2,
               float* __restrict__ outp) {
  __shared__ float t[Gg][64];
  int tid = threadIdx.x;
  int g = tid >> 6, j = tid & 63;
  float acc = bf1[j];
  for (int c = 0; c < Dd; ++c) acc = fmaf(pooled[g * Dd + c], wf1[c * 64 + j], acc);
  t[g][j] = acc;
  __syncthreads();
  if (tid < Gg * 4) {
    int gg = tid >> 2, cc = tid & 3;
    float a2 = bf2[cc];
    for (int j2 = 0; j2 < 64; ++j2) a2 = fmaf(t[gg][j2], wf2[j2 * 4 + cc], a2);
    outp[gg * 4 + cc] = a2;
  }
}

// ---------------- host ----------------

extern "C" void kernel_launch(void* const* d_in, const int* in_sizes, int n_in,
                              void* d_out, int out_size, void* d_ws, size_t ws_size,
                              hipStream_t stream) {
  const float* x   = (const float*)d_in[0];
  const int* ei    = (const int*)d_in[1];
  const int* srcE  = ei;
  const int* dstE  = ei + Ee;
  const int* batch = (const int*)d_in[2];
  const float* wq1 = (const float*)d_in[3];  const float* bq1 = (const float*)d_in[4];
  const float* wk1 = (const float*)d_in[5];  const float* bk1 = (const float*)d_in[6];
  const float* wv1 = (const float*)d_in[7];  const float* bv1 = (const float*)d_in[8];
  const float* ws1 = (const float*)d_in[9];  const float* bs1 = (const float*)d_in[10];
  const float* wq2 = (const float*)d_in[11]; const float* bq2 = (const float*)d_in[12];
  const float* wk2 = (const float*)d_in[13]; const float* bk2 = (const float*)d_in[14];
  const float* wv2 = (const float*)d_in[15]; const float* bv2 = (const float*)d_in[16];
  const float* ws2 = (const float*)d_in[17]; const float* bs2 = (const float*)d_in[18];
  const float* wf1 = (const float*)d_in[19]; const float* bf1 = (const float*)d_in[20];
  const float* wf2 = (const float*)d_in[21]; const float* bf2 = (const float*)d_in[22];
  float* outp = (float*)d_out;
  char* ws = (char*)d_ws;

  auto al256 = [](size_t v) { return (v + 255) & ~(size_t)255; };
  size_t o_deg  = 0;
  size_t o_pool = o_deg + (size_t)Nn * 4;
  size_t zbytes = o_pool + (size_t)Gg * Dd * 4;
  size_t o_off  = al256(zbytes);
  size_t o_ssrc = al256(o_off + (size_t)(Nn + 1) * 4);
  size_t o_rank = al256(o_ssrc + (size_t)Ee * 4);
  size_t o_q    = al256(o_rank + (size_t)Ee * 4);                 // fp16 [Nn][256]
  size_t o_kv   = al256(o_q + (size_t)Nn * Dd * 2);               // 768B rows [Nn]
  size_t o_s    = al256(o_kv + (size_t)Nn * 768);                 // fp16 [Nn][256]
  size_t o_b1   = al256(o_s + (size_t)Nn * Dd * 2);               // bf16 [1024][512]
  size_t o_b2   = al256(o_b1 + (size_t)1024 * Ff * 2);            // bf16 [1024][256]
  size_t o_a    = al256(o_b2 + (size_t)1024 * Dd * 2);            // bf16 [Nn][512] x / h overlay
  size_t o_bsum = al256(o_a + (size_t)Nn * Ff * 2);
  size_t o_boff = al256(o_bsum + (size_t)SCANB * 4);
  size_t total  = o_boff + (size_t)SCANB * 4;
  if (ws_size < total) {
    fprintf(stderr, "kernel_launch: ws too small: %zu < %zu\n", ws_size, total);
    return;
  }

  int*   deg    = (int*)(ws + o_deg);
  float* pooled = (float*)(ws + o_pool);
  int*   off    = (int*)(ws + o_off);
  int*   ssrc   = (int*)(ws + o_ssrc);
  int*   rank   = (int*)(ws + o_rank);
  _Float16* qb  = (_Float16*)(ws + o_q);
  unsigned char* kvb = (unsigned char*)(ws + o_kv);
  _Float16* sb  = (_Float16*)(ws + o_s);
  unsigned short* b1 = (unsigned short*)(ws + o_b1);
  unsigned short* b2 = (unsigned short*)(ws + o_b2);
  unsigned short* a2  = (unsigned short*)(ws + o_a);    // [Nn][512] bf16 (x)
  unsigned short* hb  = (unsigned short*)(ws + o_a);    // [Nn][256] bf16 h (overlays a2)
  int* bsum     = (int*)(ws + o_bsum);
  int* boff     = (int*)(ws + o_boff);

  (void)hipMemsetAsync(ws, 0, zbytes, stream);
  hist_kernel<<<1024, 256, 0, stream>>>(dstE, deg, rank);
  scan1_kernel<<<SCANB, 1024, 0, stream>>>(deg, off, bsum);
  scan2_kernel<<<1, 64, 0, stream>>>(bsum, boff, off + Nn);
  scan3_kernel<<<(Nn + 255) / 256, 256, 0, stream>>>(off, boff);
  scatter_kernel<<<1024, 256, 0, stream>>>(srcE, dstE, off, rank, ssrc);

  convw_kernel<<<1024, 256, 0, stream>>>(wq1, wk1, wv1, ws1, b1, Ff);
  convw_kernel<<<1024, 256, 0, stream>>>(wq2, wk2, wv2, ws2, b2, Dd);
  round_kernel<<<4096, 256, 0, stream>>>(x, a2, Nn, Ff);

  gemm_mfma<<<3136, 256, 0, stream>>>(a2, Nn, Ff, b1, bq1, bk1, bv1, bs1, qb, kvb, sb);
  attn_kernel<<<(Nn + 3) / 4, 256, 0, stream>>>(qb, kvb, sb, off, ssrc, hb);
  gemm_mfma<<<3136, 256, 0, stream>>>(hb, Nn, Dd, b2, bq2, bk2, bv2, bs2, qb, kvb, sb);
  attn_kernel<<<(Nn + 3) / 4, 256, 0, stream>>>(qb, kvb, sb, off, ssrc, hb);

  pool_kernel<<<(Nn + 127) / 128, 256, 0, stream>>>(hb, batch, pooled);
  fc_kernel<<<1, 512, 0, stream>>>(pooled, wf1, bf1, wf2, bf2, outp);
}

// Round 14
// 482.214 us; speedup vs baseline: 1.9647x; 1.0626x over previous
//
#include <hip/hip_runtime.h>
#include <cstdio>

#define Nn 50000
#define Ee 800000
#define Ff 512
#define Dd 256
#define Gg 8
#define SCANB 49   // ceil(Nn/1024)

typedef short short8 __attribute__((ext_vector_type(8)));
typedef __bf16 bf16x8 __attribute__((ext_vector_type(8)));
typedef float f32x4 __attribute__((ext_vector_type(4)));
typedef _Float16 half2v __attribute__((ext_vector_type(2)));

#if defined(__has_builtin)
#if __has_builtin(__builtin_amdgcn_cvt_f32_fp8)
#define HAS_CVTFP8 1
#endif
#endif

__device__ inline unsigned short f2bf(float f) {
  unsigned u = __float_as_uint(f);
  u += 0x7FFFu + ((u >> 16) & 1u);
  return (unsigned short)(u >> 16);
}
__device__ inline float bf2f(unsigned short h) {
  return __uint_as_float(((unsigned)h) << 16);
}

// OCP e4m3 encode (RNE, clamp to +-448, denormals handled)
__device__ inline unsigned char f2fp8(float f) {
  const float af = fabsf(f);
  const unsigned s = (f < 0.f) ? 0x80u : 0u;
  if (af >= 448.f) return (unsigned char)(s | 0x7E);
  if (af < 0.015625f) {
    int q = (int)(af * 512.f + 0.5f);
    return (unsigned char)(s | q);
  }
  unsigned u = __float_as_uint(af);
  unsigned m = u & 0x7fffffu;
  unsigned e = u >> 23;
  unsigned r = m + 0x7ffffu + ((m >> 20) & 1u);
  if (r >> 23) { e += 1; r = 0; }
  unsigned em = ((e - 120u) << 3) | ((r >> 20) & 7u);
  if (em > 0x7Eu) em = 0x7Eu;
  return (unsigned char)(s | em);
}

// OCP e4m3 decode, byte SEL of a dword (compile-time constant)
template <int SEL>
__device__ inline float fp8tof(unsigned v) {
#ifdef HAS_CVTFP8
  return __builtin_amdgcn_cvt_f32_fp8(v, SEL);
#else
  unsigned b = (v >> (SEL * 8)) & 0xffu;
  unsigned em = b & 0x7fu;
  float n = __uint_as_float((em << 20) + 0x3C000000u);
  float dn = (float)em * 0.001953125f;
  float r = (em < 8u) ? dn : n;
  return (b & 0x80u) ? -r : r;
#endif
}

__device__ inline void gload16(const void* g, void* l) {
  __builtin_amdgcn_global_load_lds((const __attribute__((address_space(1))) void*)g,
                                   (__attribute__((address_space(3))) void*)l, 16, 0, 0);
}

// ---------------- CSR build (rank-based: one atomic pass) ----------------

__global__ void hist_kernel(const int* __restrict__ dst, int* __restrict__ deg,
                            int* __restrict__ rank) {
  int i = blockIdx.x * blockDim.x + threadIdx.x;
  int stride = gridDim.x * blockDim.x;
  for (; i < Ee; i += stride) rank[i] = atomicAdd(&deg[dst[i]], 1);
}

__global__ __launch_bounds__(1024) void scan1_kernel(const int* __restrict__ deg,
                                                     int* __restrict__ off,
                                                     int* __restrict__ bsum) {
  __shared__ int wsum[16];
  int tid = threadIdx.x, lane = tid & 63, w = tid >> 6;
  int i = blockIdx.x * 1024 + tid;
  int v = (i < Nn) ? deg[i] : 0;
  int x = v;
#pragma unroll
  for (int o = 1; o < 64; o <<= 1) {
    int t = __shfl_up(x, o);
    if (lane >= o) x += t;
  }
  if (lane == 63) wsum[w] = x;
  __syncthreads();
  if (w == 0 && lane < 16) {
    int y = wsum[lane];
#pragma unroll
    for (int o = 1; o < 16; o <<= 1) {
      int t = __shfl_up(y, o);
      if (lane >= o) y += t;
    }
    wsum[lane] = y;
  }
  __syncthreads();
  int incl = x + (w ? wsum[w - 1] : 0);
  if (i < Nn) off[i] = incl - v;
  if (tid == 1023) bsum[blockIdx.x] = incl;
}

__global__ void scan2_kernel(const int* __restrict__ bsum, int* __restrict__ boff,
                             int* __restrict__ offN) {
  int lane = threadIdx.x;
  int v = (lane < SCANB) ? bsum[lane] : 0;
  int x = v;
#pragma unroll
  for (int o = 1; o < 64; o <<= 1) {
    int t = __shfl_up(x, o);
    if (lane >= o) x += t;
  }
  if (lane < SCANB) boff[lane] = x - v;
  if (lane == 63) *offN = x;
}

__global__ void scan3_kernel(int* __restrict__ off, const int* __restrict__ boff) {
  int i = blockIdx.x * 256 + threadIdx.x;
  if (i < Nn) off[i] += boff[i >> 10];
}

__global__ void scatter_kernel(const int* __restrict__ src, const int* __restrict__ dst,
                               const int* __restrict__ off, const int* __restrict__ rank,
                               int* __restrict__ ssrc) {
  int i = blockIdx.x * blockDim.x + threadIdx.x;
  int stride = gridDim.x * blockDim.x;
  for (; i < Ee; i += stride) {
    ssrc[off[dst[i]] + rank[i]] = src[i];
  }
}

// ---------------- conversions ----------------

__global__ void round_kernel(const float* __restrict__ in, unsigned short* __restrict__ out,
                             int M, int K) {
  const int kg4 = K >> 2;
  int i = blockIdx.x * blockDim.x + threadIdx.x;
  const int total = M * kg4;
  const int stride = gridDim.x * blockDim.x;
  for (; i < total; i += stride) {
    const int row = i / kg4, kg = i - row * kg4;
    const float4 v = *(const float4*)(in + (size_t)row * K + kg * 4);
    ushort4 h;
    h.x = f2bf(v.x); h.y = f2bf(v.y); h.z = f2bf(v.z); h.w = f2bf(v.w);
    *(ushort4*)(out + (size_t)row * K + kg * 4) = h;
  }
}

// 4x W [K][256] fp32 -> B [1024][K] bf16 hi-only, transposed; row n = z*256+c
__global__ void convw_kernel(const float* __restrict__ W0, const float* __restrict__ W1,
                             const float* __restrict__ W2, const float* __restrict__ W3,
                             unsigned short* __restrict__ B, int K) {
  int i = blockIdx.x * blockDim.x + threadIdx.x;
  const int total = 1024 * K;
  const int stride = gridDim.x * blockDim.x;
  for (; i < total; i += stride) {
    const int n = i & 1023;
    const int k = i >> 10;
    const int z = n >> 8, c = n & 255;
    const float* W = z == 0 ? W0 : z == 1 ? W1 : z == 2 ? W2 : W3;
    B[(size_t)n * K + k] = f2bf(W[(size_t)k * Dd + c]);
  }
}

// ---------------- 1-term bf16 MFMA GEMM (128x128 tile) with XOR-swizzled LDS epilogue ----
// C = A_bf16 @ B_hi + bias.  A [M][K] bf16, B [1024][K] bf16.
// z=(i2&7)>>1: 0 -> q fp16 [M][256]; 1 -> K fp8 in kv[row*512 + c];
// 2 -> V fp8 in kv[row*512 + 256 + c]; 3 -> s fp16 [M][256].

__global__ __launch_bounds__(256, 6)
void gemm_mfma(const unsigned short* __restrict__ A2, int M, int K,
               const unsigned short* __restrict__ B,
               const float* __restrict__ b0, const float* __restrict__ b1,
               const float* __restrict__ b2, const float* __restrict__ b3,
               _Float16* __restrict__ qout, unsigned char* __restrict__ kvout,
               _Float16* __restrict__ sout) {
  __shared__ __align__(16) char smem[32768];
  unsigned short* As = (unsigned short*)smem;
  unsigned short* Bs = (unsigned short*)(smem + 16384);
  const int tid = threadIdx.x;
  const int lane = tid & 63, w = tid >> 6;
  const int wr = w >> 1, wc = w & 1;
  const int p = blockIdx.x;
  const int xcd = p & 7;
  const int i2 = p >> 3;
  const int bm = (xcd * 49 + (i2 >> 3)) * 128;
  const int zblk = (i2 & 7) >> 1;
  const int colbase = (i2 & 1) * 128;          // block's 128 cols within its z
  const int lda = K, ldb = K;
  const int nsteps = K >> 6;
  const int srow = lane >> 3, sslot = lane & 7;
  const int fr = lane & 15, fq = lane >> 4;

  f32x4 acc[4][4] = {};

  for (int s = 0; s < nsteps; ++s) {
    const int kk = s << 6;
    __syncthreads();
#pragma unroll
    for (int h = 0; h < 4; ++h) {
      const int q = h * 4 + w;
      const int r = q * 8 + srow;
      const int g = sslot ^ (r & 7);
      int ga = bm + r; if (ga > M - 1) ga = M - 1;
      gload16(A2 + (size_t)ga * lda + kk + g * 8, (char*)As + q * 1024);
      const int gb = (zblk * 256 + colbase) + r;   // B row = z*256 + c
      gload16(B + (size_t)gb * ldb + kk + g * 8, (char*)Bs + q * 1024);
    }
    __syncthreads();
    short8 av[2][4], bv[2][4];
#pragma unroll
    for (int kh = 0; kh < 2; ++kh)
#pragma unroll
      for (int i = 0; i < 4; ++i) {
        const int ra = wr * 64 + i * 16 + fr;
        av[kh][i] = *(const short8*)((const char*)As + ra * 128 + (((kh * 4 + fq) ^ (ra & 7)) << 4));
        const int rb = wc * 64 + i * 16 + fr;
        bv[kh][i] = *(const short8*)((const char*)Bs + rb * 128 + (((kh * 4 + fq) ^ (rb & 7)) << 4));
      }
#pragma unroll
    for (int kh = 0; kh < 2; ++kh)
#pragma unroll
      for (int mi = 0; mi < 4; ++mi)
#pragma unroll
        for (int ni = 0; ni < 4; ++ni)
          acc[mi][ni] = __builtin_amdgcn_mfma_f32_16x16x32_bf16(
              __builtin_bit_cast(bf16x8, av[kh][mi]),
              __builtin_bit_cast(bf16x8, bv[kh][ni]), acc[mi][ni], 0, 0, 0);
  }

  // ---- epilogue: fragments -> LDS (row stride 256B, byte XOR ^((row&7)<<4)) ----
  const float* bp = zblk == 0 ? b0 : zblk == 1 ? b1 : zblk == 2 ? b2 : b3;
  __syncthreads();   // K-loop LDS reads done before overwrite
  if (zblk == 1 || zblk == 2) {
    unsigned char* S8 = (unsigned char*)smem;
#pragma unroll
    for (int mi = 0; mi < 4; ++mi)
#pragma unroll
      for (int ni = 0; ni < 4; ++ni) {
        const int col = wc * 64 + ni * 16 + fr;
        const float bias = bp[colbase + col];
#pragma unroll
        for (int j = 0; j < 4; ++j) {
          const int row = wr * 64 + mi * 16 + fq * 4 + j;
          S8[row * 256 + (col ^ ((row & 7) << 4))] = f2fp8(acc[mi][ni][j] + bias);
        }
      }
  } else {
#pragma unroll
    for (int mi = 0; mi < 4; ++mi)
#pragma unroll
      for (int ni = 0; ni < 4; ++ni) {
        const int col = wc * 64 + ni * 16 + fr;
        const float bias = bp[colbase + col];
#pragma unroll
        for (int j = 0; j < 4; ++j) {
          const int row = wr * 64 + mi * 16 + fq * 4 + j;
          *(_Float16*)(smem + row * 256 + ((col * 2) ^ ((row & 7) << 4))) =
              (_Float16)(acc[mi][ni][j] + bias);
        }
      }
  }
  __syncthreads();

  // ---- flush: coalesced 16B stores; fp8 64B/thread-half, fp16 128B/thread-half ----
  const int row = tid >> 1, half = tid & 1;
  const int grow = bm + row;
  if (grow < M) {
    const int sh = (row & 7) << 4;
    if (zblk == 1 || zblk == 2) {
      uint4* dstp = (uint4*)(kvout + (size_t)grow * 512 + (zblk == 2 ? 256 : 0) +
                             colbase + half * 64);
#pragma unroll
      for (int k = 0; k < 4; ++k)
        dstp[k] = *(const uint4*)(smem + row * 256 + ((half * 64 + k * 16) ^ sh));
    } else {
      char* dbase = zblk == 0 ? (char*)qout + (size_t)grow * 512 + colbase * 2
                              : (char*)sout + (size_t)grow * 512 + colbase * 2;
      uint4* dstp = (uint4*)(dbase + half * 128);
#pragma unroll
      for (int k = 0; k < 8; ++k)
        dstp[k] = *(const uint4*)(smem + row * 256 + ((half * 128 + k * 16) ^ sh));
    }
  }
}

// ---------------- per-node attention (one wave per dst node, online softmax) ----------------
// q: fp16 [Nn][256]; kv row 512B: K fp8 [0,256), V fp8 [256,512); s fp16 [Nn][256].

__global__ __launch_bounds__(256)
void attn_kernel(const _Float16* __restrict__ qbuf, const unsigned char* __restrict__ kvb,
                 const _Float16* __restrict__ sbuf, const int* __restrict__ off,
                 const int* __restrict__ ssrc, unsigned short* __restrict__ hbout) {
  int gw = (int)((blockIdx.x * 256 + threadIdx.x) >> 6);
  if (gw >= Nn) return;
  int lane = threadIdx.x & 63;

  const uint2 qv = *(const uint2*)(qbuf + (size_t)gw * Dd + lane * 4);
  const half2v q01 = __builtin_bit_cast(half2v, qv.x);
  const half2v q23 = __builtin_bit_cast(half2v, qv.y);
  const float qx = (float)q01[0], qy = (float)q01[1];
  const float qz = (float)q23[0], qw = (float)q23[1];
  int e0 = off[gw], e1 = off[gw + 1];
  const float scale = 0.08838834764831845f;

  float m = -3.4e38f, d = 0.f;
  float ax = 0.f, ay = 0.f, az = 0.f, aw = 0.f;

  for (int e = e0; e < e1; e += 8) {
    int sx[8];
#pragma unroll
    for (int t = 0; t < 8; ++t) {
      const int ee = e + t;
      sx[t] = ssrc[ee < e1 ? ee : e1 - 1];
    }
    unsigned kw[8], vw[8];
#pragma unroll
    for (int t = 0; t < 8; ++t) {
      const unsigned char* row = kvb + (size_t)sx[t] * 512;
      kw[t] = *(const unsigned*)(row + lane * 4);
      vw[t] = *(const unsigned*)(row + 256 + lane * 4);
    }
    float p[8];
#pragma unroll
    for (int t = 0; t < 8; ++t) {
      float pp = qx * fp8tof<0>(kw[t]);
      pp = fmaf(qy, fp8tof<1>(kw[t]), pp);
      pp = fmaf(qz, fp8tof<2>(kw[t]), pp);
      pp = fmaf(qw, fp8tof<3>(kw[t]), pp);
      p[t] = pp;
    }
#pragma unroll
    for (int o = 16; o >= 1; o >>= 1)
#pragma unroll
      for (int t = 0; t < 8; ++t) p[t] += __shfl_xor(p[t], o);
    float sc[8];
#pragma unroll
    for (int t = 0; t < 8; ++t)
      sc[t] = (e + t < e1) ? p[t] * scale : -3.0e38f;
    float mx = m;
#pragma unroll
    for (int t = 0; t < 8; ++t) mx = fmaxf(mx, sc[t]);
    const float f = __expf(m - mx);
    float wsum = 0.f, vx = 0.f, vy = 0.f, vz = 0.f, vww = 0.f;
#pragma unroll
    for (int t = 0; t < 8; ++t) {
      const float wt = __expf(sc[t] - mx);
      wsum += wt;
      vx = fmaf(wt, fp8tof<0>(vw[t]), vx);
      vy = fmaf(wt, fp8tof<1>(vw[t]), vy);
      vz = fmaf(wt, fp8tof<2>(vw[t]), vz);
      vww = fmaf(wt, fp8tof<3>(vw[t]), vww);
    }
    d = d * f + wsum;
    ax = ax * f + vx;
    ay = ay * f + vy;
    az = az * f + vz;
    aw = aw * f + vww;
    m = mx;
  }

  float inv = 1.f / (d + 1e-16f);
  const uint2 sv = *(const uint2*)(sbuf + (size_t)gw * Dd + lane * 4);
  const half2v s01 = __builtin_bit_cast(half2v, sv.x);
  const half2v s23 = __builtin_bit_cast(half2v, sv.y);
  ushort4 hh;
  hh.x = f2bf(fmaxf(fmaf(ax, inv, (float)s01[0]), 0.f));
  hh.y = f2bf(fmaxf(fmaf(ay, inv, (float)s01[1]), 0.f));
  hh.z = f2bf(fmaxf(fmaf(az, inv, (float)s23[0]), 0.f));
  hh.w = f2bf(fmaxf(fmaf(aw, inv, (float)s23[1]), 0.f));
  *(ushort4*)(hbout + (size_t)gw * Dd + lane * 4) = hh;
}

// ---------------- pooling (bf16 input) + fc ----------------

__global__ __launch_bounds__(256)
void pool_kernel(const unsigned short* __restrict__ h, const int* __restrict__ batch,
                 float* __restrict__ pooled) {
  int c = threadIdx.x;
  int n0 = blockIdx.x * 128;
  int n1 = min(n0 + 128, Nn);
  int curg = batch[n0];
  float mx = 0.f;
  for (int n = n0; n < n1; ++n) {
    int g = batch[n];
    if (g != curg) {
      atomicMax((int*)(pooled + curg * Dd + c), __float_as_int(mx));
      mx = 0.f;
      curg = g;
    }
    mx = fmaxf(mx, bf2f(h[(size_t)n * Dd + c]));
  }
  atomicMax((int*)(pooled + curg * Dd + c), __float_as_int(mx));
}

__global__ __launch_bounds__(512)
void fc_kernel(const float* __restrict__ pooled,
               const float* __restrict__ wf1, const float* __restrict__ bf1,
               const float* __restrict__ wf2, const float* __restrict__ bf2,
               float* __restrict__ outp) {
  __shared__ float t[Gg][64];
  int tid = threadIdx.x;
  int g = tid >> 6, j = tid & 63;
  float acc = bf1[j];
  for (int c = 0; c < Dd; ++c) acc = fmaf(pooled[g * Dd + c], wf1[c * 64 + j], acc);
  t[g][j] = acc;
  __syncthreads();
  if (tid < Gg * 4) {
    int gg = tid >> 2, cc = tid & 3;
    float a2 = bf2[cc];
    for (int j2 = 0; j2 < 64; ++j2) a2 = fmaf(t[gg][j2], wf2[j2 * 4 + cc], a2);
    outp[gg * 4 + cc] = a2;
  }
}

// ---------------- host ----------------

extern "C" void kernel_launch(void* const* d_in, const int* in_sizes, int n_in,
                              void* d_out, int out_size, void* d_ws, size_t ws_size,
                              hipStream_t stream) {
  const float* x   = (const float*)d_in[0];
  const int* ei    = (const int*)d_in[1];
  const int* srcE  = ei;
  const int* dstE  = ei + Ee;
  const int* batch = (const int*)d_in[2];
  const float* wq1 = (const float*)d_in[3];  const float* bq1 = (const float*)d_in[4];
  const float* wk1 = (const float*)d_in[5];  const float* bk1 = (const float*)d_in[6];
  const float* wv1 = (const float*)d_in[7];  const float* bv1 = (const float*)d_in[8];
  const float* ws1 = (const float*)d_in[9];  const float* bs1 = (const float*)d_in[10];
  const float* wq2 = (const float*)d_in[11]; const float* bq2 = (const float*)d_in[12];
  const float* wk2 = (const float*)d_in[13]; const float* bk2 = (const float*)d_in[14];
  const float* wv2 = (const float*)d_in[15]; const float* bv2 = (const float*)d_in[16];
  const float* ws2 = (const float*)d_in[17]; const float* bs2 = (const float*)d_in[18];
  const float* wf1 = (const float*)d_in[19]; const float* bf1 = (const float*)d_in[20];
  const float* wf2 = (const float*)d_in[21]; const float* bf2 = (const float*)d_in[22];
  float* outp = (float*)d_out;
  char* ws = (char*)d_ws;

  auto al256 = [](size_t v) { return (v + 255) & ~(size_t)255; };
  size_t o_deg  = 0;
  size_t o_pool = o_deg + (size_t)Nn * 4;
  size_t zbytes = o_pool + (size_t)Gg * Dd * 4;
  size_t o_off  = al256(zbytes);
  size_t o_ssrc = al256(o_off + (size_t)(Nn + 1) * 4);
  size_t o_rank = al256(o_ssrc + (size_t)Ee * 4);
  size_t o_q    = al256(o_rank + (size_t)Ee * 4);                 // fp16 [Nn][256]
  size_t o_kv   = al256(o_q + (size_t)Nn * Dd * 2);               // 512B rows [Nn]
  size_t o_s    = al256(o_kv + (size_t)Nn * 512);                 // fp16 [Nn][256]
  size_t o_b1   = al256(o_s + (size_t)Nn * Dd * 2);               // bf16 [1024][512]
  size_t o_b2   = al256(o_b1 + (size_t)1024 * Ff * 2);            // bf16 [1024][256]
  size_t o_a    = al256(o_b2 + (size_t)1024 * Dd * 2);            // bf16 [Nn][512] x / h overlay
  size_t o_bsum = al256(o_a + (size_t)Nn * Ff * 2);
  size_t o_boff = al256(o_bsum + (size_t)SCANB * 4);
  size_t total  = o_boff + (size_t)SCANB * 4;
  if (ws_size < total) {
    fprintf(stderr, "kernel_launch: ws too small: %zu < %zu\n", ws_size, total);
    return;
  }

  int*   deg    = (int*)(ws + o_deg);
  float* pooled = (float*)(ws + o_pool);
  int*   off    = (int*)(ws + o_off);
  int*   ssrc   = (int*)(ws + o_ssrc);
  int*   rank   = (int*)(ws + o_rank);
  _Float16* qb  = (_Float16*)(ws + o_q);
  unsigned char* kvb = (unsigned char*)(ws + o_kv);
  _Float16* sb  = (_Float16*)(ws + o_s);
  unsigned short* b1 = (unsigned short*)(ws + o_b1);
  unsigned short* b2 = (unsigned short*)(ws + o_b2);
  unsigned short* a2  = (unsigned short*)(ws + o_a);    // [Nn][512] bf16 (x)
  unsigned short* hb  = (unsigned short*)(ws + o_a);    // [Nn][256] bf16 h (overlays a2)
  int* bsum     = (int*)(ws + o_bsum);
  int* boff     = (int*)(ws + o_boff);

  (void)hipMemsetAsync(ws, 0, zbytes, stream);
  hist_kernel<<<1024, 256, 0, stream>>>(dstE, deg, rank);
  scan1_kernel<<<SCANB, 1024, 0, stream>>>(deg, off, bsum);
  scan2_kernel<<<1, 64, 0, stream>>>(bsum, boff, off + Nn);
  scan3_kernel<<<(Nn + 255) / 256, 256, 0, stream>>>(off, boff);
  scatter_kernel<<<1024, 256, 0, stream>>>(srcE, dstE, off, rank, ssrc);

  convw_kernel<<<1024, 256, 0, stream>>>(wq1, wk1, wv1, ws1, b1, Ff);
  convw_kernel<<<1024, 256, 0, stream>>>(wq2, wk2, wv2, ws2, b2, Dd);
  round_kernel<<<4096, 256, 0, stream>>>(x, a2, Nn, Ff);

  gemm_mfma<<<3136, 256, 0, stream>>>(a2, Nn, Ff, b1, bq1, bk1, bv1, bs1, qb, kvb, sb);
  attn_kernel<<<(Nn + 3) / 4, 256, 0, stream>>>(qb, kvb, sb, off, ssrc, hb);
  gemm_mfma<<<3136, 256, 0, stream>>>(hb, Nn, Dd, b2, bq2, bk2, bv2, bs2, qb, kvb, sb);
  attn_kernel<<<(Nn + 3) / 4, 256, 0, stream>>>(qb, kvb, sb, off, ssrc, hb);

  pool_kernel<<<(Nn + 127) / 128, 256, 0, stream>>>(hb, batch, pooled);
  fc_kernel<<<1, 512, 0, stream>>>(pooled, wf1, bf1, wf2, bf2, outp);
}